// Round 8
// baseline (439.869 us; speedup 1.0000x reference)
//
#include <hip/hip_runtime.h>
#include <hip/hip_bf16.h>

using bf16x8 = __attribute__((ext_vector_type(8))) __bf16;
using f32x4  = __attribute__((ext_vector_type(4))) float;

constexpr int T_SEQ = 4096;
constexpr int HID_C = 2048;
constexpr int NH    = 16;
constexpr int QKV_N = 6144;

__device__ __forceinline__ float head_slope(int h) {
    // slope[h] = -2^{-(h+1)/2} * (1 - 1/31 + 1e-5)
    return -exp2f(-0.5f * (float)(h + 1)) * 0.967751935483871f;
}

__device__ __forceinline__ ushort f2bfu(float f) {
    __hip_bfloat16 h = __float2bfloat16(f);
    return *(ushort*)&h;
}
__device__ __forceinline__ float bfu2f(ushort u) {
    union { unsigned int i; float f; } x; x.i = ((unsigned int)u) << 16; return x.f;
}

// async global -> LDS, 16 bytes per lane; LDS dest = wave-uniform base + lane*16
__device__ __forceinline__ void async16(const ushort* g, ushort* l) {
    __builtin_amdgcn_global_load_lds((const __attribute__((address_space(1))) void*)g,
                                     (__attribute__((address_space(3))) void*)l, 16, 0, 0);
}

template<int N> __device__ __forceinline__ void waitcnt_vm() {
    if constexpr (N == 0)      asm volatile("s_waitcnt vmcnt(0)" ::: "memory");
    else if constexpr (N == 2) asm volatile("s_waitcnt vmcnt(2)" ::: "memory");
    else if constexpr (N == 4) asm volatile("s_waitcnt vmcnt(4)" ::: "memory");
    else if constexpr (N == 6) asm volatile("s_waitcnt vmcnt(6)" ::: "memory");
}

// ============ merged preprocessing: cvt_bf16 + 3x transpose_cvt + rope_tab in ONE launch ============
__device__ __forceinline__ void cvt_body(const float* __restrict__ src, ushort* __restrict__ dst,
                                         int bid, int tid) {
    int i = (bid * 256 + tid) * 8;
    float4 a = *(const float4*)(src + i);
    float4 b = *(const float4*)(src + i + 4);
    ushort4 ua = {f2bfu(a.x), f2bfu(a.y), f2bfu(a.z), f2bfu(a.w)};
    ushort4 ub = {f2bfu(b.x), f2bfu(b.y), f2bfu(b.z), f2bfu(b.w)};
    *(ushort4*)(dst + i) = ua;
    *(ushort4*)(dst + i + 4) = ub;
}

__device__ __forceinline__ void transpose_body(const float* __restrict__ src,
                                               ushort* __restrict__ dst,
                                               int R, int C, int bx, int by, int t,
                                               ushort (*tile)[68]) {
    int tr = by * 64, tc = bx * 64;
    int r0 = t >> 4;
    int c4 = (t & 15) << 2;
#pragma unroll
    for (int p = 0; p < 4; ++p) {
        int row = r0 + p * 16;
        float4 v = *(const float4*)&src[(size_t)(tr + row) * C + tc + c4];
        tile[row][c4 + 0] = f2bfu(v.x);
        tile[row][c4 + 1] = f2bfu(v.y);
        tile[row][c4 + 2] = f2bfu(v.z);
        tile[row][c4 + 3] = f2bfu(v.w);
    }
    __syncthreads();
#pragma unroll
    for (int p = 0; p < 4; ++p) {
        int orow = r0 + p * 16;
        ushort4 u;
        u.x = tile[c4 + 0][orow];
        u.y = tile[c4 + 1][orow];
        u.z = tile[c4 + 2][orow];
        u.w = tile[c4 + 3][orow];
        *(ushort4*)&dst[(size_t)(tc + orow) * R + tr + c4] = u;
    }
}

// grid: [0,4096) cvt | [4096,7168) w_qkv T | [7168,8192) w_g T | [8192,9216) w_dense T | [9216,9728) rope
__global__ __launch_bounds__(256) void prep_all(const float* __restrict__ hidden,
                                                ushort* __restrict__ hid_b,
                                                const float* __restrict__ w_qkv,
                                                ushort* __restrict__ wqkv_t,
                                                const float* __restrict__ w_g,
                                                ushort* __restrict__ wg_t,
                                                const float* __restrict__ w_dense,
                                                ushort* __restrict__ wd_t,
                                                const int* __restrict__ positions,
                                                float2* __restrict__ ropet) {
    __shared__ ushort tile[64][68];
    int b = blockIdx.x, t = threadIdx.x;
    if (b < 4096) {
        cvt_body(hidden, hid_b, b, t);
    } else if (b < 7168) {
        int bb = b - 4096;                       // 96 x 32 tiles
        transpose_body(w_qkv, wqkv_t, HID_C, QKV_N, bb % 96, bb / 96, t, tile);
    } else if (b < 8192) {
        int bb = b - 7168;                       // 32 x 32
        transpose_body(w_g, wg_t, HID_C, HID_C, bb % 32, bb / 32, t, tile);
    } else if (b < 9216) {
        int bb = b - 8192;                       // 32 x 32
        transpose_body(w_dense, wd_t, HID_C, HID_C, bb % 32, bb / 32, t, tile);
    } else {
        int i = (b - 9216) * 256 + t;            // i < T*32
        int tt = i >> 5, fi = i & 31;
        float inv = expf((float)fi * -0.2878231366f);   // ln(10000)/32
        float freq = (float)positions[tt] * inv;
        float sn, cs;
        sincosf(freq, &sn, &cs);
        ropet[i] = make_float2(cs, sn);
    }
}

// ============== 128x128 flat-K-tile core: 4 waves, 64 KiB LDS -> 2 blocks/CU ==============
// Mechanism (m114): INDEPENDENT co-resident blocks de-phase naturally — one block's read
// burst/drain overlaps another's MFMA phase. Barrier-synced waves within ONE block cannot
// (all leave the barrier together -> read burst gates every wave's MFMA; measured serial
// LDS+MFMA = 5081 cyc/tile on the 1-block/CU 256x256 config).
// LDS layout: A0|A1|B0|B1, each 128x64 bf16 = 16 KiB -> 64 KiB total (sh[32768] ushorts).
__device__ __forceinline__ void gemm4_core(const ushort* __restrict__ Ag,
                                           const ushort* __restrict__ Bg,
                                           int K, int bm, int bn,
                                           ushort* sh, f32x4 (&acc)[4][4]) {
    const int tid  = threadIdx.x;
    const int lane = tid & 63;
    const int wave = tid >> 6;             // 4 waves: 2M x 2N
    const int lane15 = lane & 15, quad = lane >> 4;
    const int wm = wave >> 1, wn = wave & 1;
    const int swz = lane15 & 7;

    ushort* const ldsA0 = sh;              // [128][64]
    ushort* const ldsA1 = sh + 8192;
    ushort* const ldsB0 = sh + 16384;
    ushort* const ldsB1 = sh + 24576;

    const int srow = lane >> 3;
    const int scol = ((lane & 7) ^ srow) << 3;
    const ushort* gA = Ag + (size_t)(bm + srow) * K + scol;
    const ushort* gB = Bg + (size_t)(bn + srow) * K + scol;
    const int ro = wave * 32;              // each wave stages 4x 8-row chunks (128 rows / 4 waves)
    const int NT = K >> 6;

#define STG(L, g, k0) do { \
    _Pragma("unroll") for (int q = 0; q < 4; ++q) \
        async16((g) + (size_t)(ro + q * 8) * K + (k0), (L) + (ro + q * 8) * 64); } while (0)

    STG(ldsA0, gA, 0);
    STG(ldsB0, gB, 0);
    waitcnt_vm<0>();
    asm volatile("s_barrier" ::: "memory");

    for (int t = 0; t < NT; ++t) {
        const ushort* LA = (t & 1) ? ldsA1 : ldsA0;
        const ushort* LB = (t & 1) ? ldsB1 : ldsB0;
        ushort* LAn = (t & 1) ? ldsA0 : ldsA1;
        ushort* LBn = (t & 1) ? ldsB0 : ldsB1;
        bf16x8 bfr[4][2];
#pragma unroll
        for (int j = 0; j < 4; ++j)
#pragma unroll
            for (int ks = 0; ks < 2; ++ks)
                bfr[j][ks] = *(const bf16x8*)&LB[(wn * 64 + j * 16 + lane15) * 64 + (((ks * 4 + quad) ^ swz) << 3)];
        bf16x8 af[4][2];
#pragma unroll
        for (int i = 0; i < 4; ++i)
#pragma unroll
            for (int ks = 0; ks < 2; ++ks)
                af[i][ks] = *(const bf16x8*)&LA[(wm * 64 + i * 16 + lane15) * 64 + (((ks * 4 + quad) ^ swz) << 3)];
        if (t + 1 < NT) {
            STG(LAn, gA, (t + 1) << 6);
            STG(LBn, gB, (t + 1) << 6);
        }
        __builtin_amdgcn_s_setprio(1);
#pragma unroll
        for (int i = 0; i < 4; ++i)
#pragma unroll
            for (int j = 0; j < 4; ++j)
#pragma unroll
                for (int ks = 0; ks < 2; ++ks)
                    acc[i][j] = __builtin_amdgcn_mfma_f32_16x16x32_bf16(af[i][ks], bfr[j][ks], acc[i][j], 0, 0, 0);
        __builtin_amdgcn_s_setprio(0);
        waitcnt_vm<0>();
        asm volatile("s_barrier" ::: "memory");
    }
#undef STG
}

// ---- fused qkv+gate GEMM: Bcat = [wqkv_t ; wg_t] (8192 x K). cols<6144 -> qkv, else sigmoid -> gate ----
// 128x128 tile, 256 thr, 64 KiB LDS -> 2 blocks/CU. Grid 2048 = 32m x 64n tiles.
// XCD swizzle: XCD x owns n-strip [x*8, x*8+8) (B-strip 4.2MB ~ L2); n-fastest, m outer.
__global__ __launch_bounds__(256, 2) void gemm_fused(const ushort* __restrict__ A,
                                                     const ushort* __restrict__ Bcat,
                                                     ushort* __restrict__ qkv,
                                                     ushort* __restrict__ gate, int K) {
    __shared__ ushort sh[32768];           // 64 KiB (A dbuf 32K + B dbuf 32K)
    int bid = blockIdx.x;
    int x = bid & 7, w = bid >> 3;         // XCD id, within-XCD order (0..255)
    int bn = (x * 8 + (w & 7)) * 128;
    int bm = (w >> 3) * 128;
    f32x4 acc[4][4] = {};
    gemm4_core(A, Bcat, K, bm, bn, sh, acc);

    int lane = threadIdx.x & 63, wave = threadIdx.x >> 6;
    int lane15 = lane & 15, quad = lane >> 4;
    int wm = wave >> 1, wn = wave & 1;
    bool isg = bn >= QKV_N;
    ushort* outp = isg ? gate : qkv;
    int ncol = isg ? HID_C : QKV_N;
    int cb = (isg ? bn - QKV_N : bn) + wn * 64;
    int rb = bm + wm * 64;
#pragma unroll
    for (int i = 0; i < 4; ++i)
#pragma unroll
        for (int j = 0; j < 4; ++j) {
            int col = cb + j * 16 + lane15;
#pragma unroll
            for (int r = 0; r < 4; ++r) {
                float v = acc[i][j][r];
                if (isg) v = 1.0f / (1.0f + __expf(-v));
                outp[(size_t)(rb + i * 16 + quad * 4 + r) * ncol + col] = f2bfu(v);
            }
        }
}

// ---- dense GEMM: fp32 out. BM=128 x BN=128, 256 thr, 64 KiB LDS (512 blocks, 2 blocks/CU) ----
__global__ __launch_bounds__(256, 2) void gemm_dense(const ushort* __restrict__ A,
                                                     const ushort* __restrict__ Bt,
                                                     float* __restrict__ Cout, int N, int K) {
    __shared__ ushort sh[32768];           // 64 KiB
    // GM=32 x GN=16 tiles; each XCD owns an 8m x 8n region (n-fastest inside)
    int bid = blockIdx.x;
    int x = bid & 7, w = bid >> 3;
    int rm = x >> 1, rn = x & 1;           // 4 x 2 regions
    int wm_i = w >> 3, wn_i = w & 7;       // 8 x 8 blocks inside region
    int bm = (rm * 8 + wm_i) * 128;
    int bn = (rn * 8 + wn_i) * 128;
    f32x4 acc[4][4] = {};
    gemm4_core(A, Bt, K, bm, bn, sh, acc);

    int lane = threadIdx.x & 63, wave = threadIdx.x >> 6;
    int lane15 = lane & 15, quad = lane >> 4;
    int wm = wave >> 1, wn = wave & 1;
    int cb = bn + wn * 64;
    int rb = bm + wm * 64;
#pragma unroll
    for (int i = 0; i < 4; ++i)
#pragma unroll
        for (int j = 0; j < 4; ++j) {
            int col = cb + j * 16 + lane15;
#pragma unroll
            for (int r = 0; r < 4; ++r)
                Cout[(size_t)(rb + i * 16 + quad * 4 + r) * N + col] = acc[i][j][r];
        }
}

// ---- fused q/k RMSNorm + RoPE (+q scale) and k/v transpose.  y: kind = y>>4 (0=q,1=k,2=v), h = y&15 ----
__global__ __launch_bounds__(256) void qk_rope_T(ushort* __restrict__ qkv,
                                                 const float2* __restrict__ tab,
                                                 const float* __restrict__ qw,
                                                 const float* __restrict__ kw,
                                                 ushort* __restrict__ kT,
                                                 ushort* __restrict__ vT) {
    __shared__ ushort tile[64][132];
    int bt = blockIdx.x;
    int kind = blockIdx.y >> 4, h = blockIdx.y & 15;
    int tid = threadIdx.x;
    int row = tid >> 2, c = tid & 3, d0 = c * 32;
    int t = bt * 64 + row;
    ushort* base = qkv + (size_t)t * QKV_N + kind * 2048 + h * 128 + d0;
    bf16x8 pk[4];
#pragma unroll
    for (int p = 0; p < 4; ++p) pk[p] = *(const bf16x8*)(base + p * 8);
    if (kind < 2) {
        float x[32];
        float ss = 0.f;
#pragma unroll
        for (int p = 0; p < 4; ++p)
#pragma unroll
            for (int i = 0; i < 8; ++i) {
                x[p * 8 + i] = (float)pk[p][i];
                ss += x[p * 8 + i] * x[p * 8 + i];
            }
        ss += __shfl_xor(ss, 1);
        ss += __shfl_xor(ss, 2);
        float rr = rsqrtf(ss * (1.0f / 128.0f) + 1e-6f);
        const float* w = (kind == 0) ? qw : kw;
#pragma unroll
        for (int i = 0; i < 32; ++i) x[i] *= rr * w[d0 + i];
        // rope on d<64: c=0 holds x1 (d 0..31), c=1 holds x2 (d 32..63); partner via xor 1
#pragma unroll
        for (int i = 0; i < 32; ++i) {
            float p = __shfl_xor(x[i], 1);
            if (c < 2) {
                float2 rt = tab[t * 32 + i];
                x[i] = (c == 0) ? (x[i] * rt.x - p * rt.y) : (x[i] * rt.x + p * rt.y);
            }
        }
        float sc = (kind == 0) ? 0.08838834764831845f : 1.0f;   // 128^-0.5 on q
#pragma unroll
        for (int p = 0; p < 4; ++p)
#pragma unroll
            for (int i = 0; i < 8; ++i) pk[p][i] = (__bf16)(x[p * 8 + i] * sc);
#pragma unroll
        for (int p = 0; p < 4; ++p) *(bf16x8*)(base + p * 8) = pk[p];
    }
    if (kind >= 1) {
        // transpose 64t x 128d -> out[d][t]
#pragma unroll
        for (int p = 0; p < 4; ++p) {
            ushort4* s = (ushort4*)&pk[p];
            *(ushort4*)&tile[row][d0 + p * 8]     = s[0];
            *(ushort4*)&tile[row][d0 + p * 8 + 4] = s[1];
        }
        __syncthreads();
        ushort* outT = ((kind == 1) ? kT : vT) + (size_t)(h * 128) * T_SEQ + bt * 64;
        int d = tid >> 1, half = tid & 1;
#pragma unroll
        for (int tt = 0; tt < 8; ++tt) {
            int tl = half * 32 + tt * 4;
            ushort4 u;
            u.x = tile[tl + 0][d];
            u.y = tile[tl + 1][d];
            u.z = tile[tl + 2][d];
            u.w = tile[tl + 3][d];
            *(ushort4*)&outT[(size_t)d * T_SEQ + tl] = u;
        }
    }
}

// ------- per-chunk partial state (transposed): PT[c,h][v][d] = sum_j lam^(127-j) v_j[v] k_j[d] -------
__global__ __launch_bounds__(256) void chunk_partial(const ushort* __restrict__ kT,
                                                     const ushort* __restrict__ vT,
                                                     float* __restrict__ PT) {
    int c = blockIdx.x, h = blockIdx.y;
    float slope = head_slope(h);
    float lam_inv = __expf(-slope);
    int tid = threadIdx.x, lane = tid & 63, wave = tid >> 6;
    int lane15 = lane & 15, quad = lane >> 4;
    int wv = (wave & 1) * 64, wd = (wave >> 1) * 64;
    const ushort* vbase = vT + (size_t)h * 128 * T_SEQ + c * 128;
    const ushort* kbase = kT + (size_t)h * 128 * T_SEQ + c * 128;
    f32x4 acc[4][4] = {};
#pragma unroll
    for (int j0 = 0; j0 < 128; j0 += 32) {
        float w8[8];
        w8[0] = __expf(slope * (float)(127 - (j0 + quad * 8)));
#pragma unroll
        for (int kk = 1; kk < 8; ++kk) w8[kk] = w8[kk - 1] * lam_inv;
        bf16x8 afr[4], bfr[4];
#pragma unroll
        for (int i = 0; i < 4; ++i) {
            bf16x8 v = *(const bf16x8*)&vbase[(size_t)(wv + i * 16 + lane15) * T_SEQ + j0 + quad * 8];
#pragma unroll
            for (int kk = 0; kk < 8; ++kk) afr[i][kk] = (__bf16)((float)v[kk] * w8[kk]);
        }
#pragma unroll
        for (int j = 0; j < 4; ++j)
            bfr[j] = *(const bf16x8*)&kbase[(size_t)(wd + j * 16 + lane15) * T_SEQ + j0 + quad * 8];
#pragma unroll
        for (int i = 0; i < 4; ++i)
#pragma unroll
            for (int j = 0; j < 4; ++j)
                acc[i][j] = __builtin_amdgcn_mfma_f32_16x16x32_bf16(afr[i], bfr[j], acc[i][j], 0, 0, 0);
    }
    float* out = PT + ((size_t)c * 16 + h) * 16384;
#pragma unroll
    for (int i = 0; i < 4; ++i)
#pragma unroll
        for (int j = 0; j < 4; ++j)
#pragma unroll
            for (int r = 0; r < 4; ++r)
                out[(size_t)(wv + i * 16 + quad * 4 + r) * 128 + wd + j * 16 + lane15] = acc[i][j][r];
}

// ------- sequential scan over 32 chunks: PT -> Spb (bf16 prefix states) + Sfin -------
__global__ __launch_bounds__(128) void scan_states(const float* __restrict__ PT,
                                                   const float* __restrict__ S0,
                                                   ushort* __restrict__ Spb,
                                                   float* __restrict__ Sfin) {
    int hv = blockIdx.x;              // h*128 + v
    int d = threadIdx.x;              // k-dim
    int h = hv >> 7, v = hv & 127;
    float lamC = __expf(head_slope(h) * 128.0f);
    float s = S0[(size_t)h * 16384 + d * 128 + v];
#pragma unroll
    for (int c = 0; c < 32; ++c) {
        size_t idx = ((size_t)c * 2048 + hv) * 128 + d;
        Spb[idx] = f2bfu(s);          // state BEFORE chunk c, layout [c][h][v][d]
        s = s * lamC + PT[idx];
    }
    Sfin[(size_t)h * 16384 + d * 128 + v] = s;
}

// ------- per-chunk output: QK^T (masked/decayed) * V + lam^(t+1) * Q * S_prev -------
__global__ __launch_bounds__(256) void chunk_out(const ushort* __restrict__ qkv,
                                                 const ushort* __restrict__ vT,
                                                 const ushort* __restrict__ Spb,
                                                 ushort* __restrict__ o) {
    int c = blockIdx.x, h = blockIdx.y;
    float slope = head_slope(h);
    __shared__ ushort Ps[128 * 136];   // padded: row stride 272B -> conflict-free b128
    int tid = threadIdx.x, lane = tid & 63, wave = tid >> 6;
    int lane15 = lane & 15, quad = lane >> 4;
    int t0 = c * 128;
    int tt0 = wave, tt1 = 7 - wave;    // owned t-tiles (balanced triangular split)
    const ushort* qbase = qkv + (size_t)t0 * QKV_N + h * 128;
    const ushort* kbase = qbase + 2048;

    bf16x8 qf0[4], qf1[4];
#pragma unroll
    for (int ds = 0; ds < 4; ++ds) {
        qf0[ds] = *(const bf16x8*)&qbase[(size_t)(tt0 * 16 + lane15) * QKV_N + ds * 32 + quad * 8];
        qf1[ds] = *(const bf16x8*)&qbase[(size_t)(tt1 * 16 + lane15) * QKV_N + ds * 32 + quad * 8];
    }
    // ---- phase 1: scores ----
    f32x4 s0a[4] = {};
    f32x4 s1a[8] = {};
#pragma unroll
    for (int st = 0; st < 8; ++st) {
        if (st <= tt1) {
            bf16x8 kf[4];
#pragma unroll
            for (int ds = 0; ds < 4; ++ds)
                kf[ds] = *(const bf16x8*)&kbase[(size_t)(st * 16 + lane15) * QKV_N + ds * 32 + quad * 8];
#pragma unroll
            for (int ds = 0; ds < 4; ++ds)
                s1a[st] = __builtin_amdgcn_mfma_f32_16x16x32_bf16(qf1[ds], kf[ds], s1a[st], 0, 0, 0);
            if (st <= tt0) {
#pragma unroll
                for (int ds = 0; ds < 4; ++ds)
                    s0a[st] = __builtin_amdgcn_mfma_f32_16x16x32_bf16(qf0[ds], kf[ds], s0a[st], 0, 0, 0);
            }
        }
    }
    // ---- park masked/decayed scores (zero strip pads odd 16-blocks to 32) ----
    int stmax0 = tt0 + ((tt0 & 1) ? 0 : 1);
    int stmax1 = tt1 + ((tt1 & 1) ? 0 : 1);
#pragma unroll
    for (int st = 0; st < 8; ++st) {
        if (st <= stmax1) {
#pragma unroll
            for (int r = 0; r < 4; ++r) {
                int t = tt1 * 16 + quad * 4 + r;
                int s = st * 16 + lane15;
                float val = 0.f;
                if (st <= tt1) val = (s <= t) ? s1a[st][r] * __expf(slope * (float)(t - s)) : 0.f;
                Ps[t * 136 + s] = f2bfu(val);
            }
        }
    }
#pragma unroll
    for (int st = 0; st < 5; ++st) {
        if (st <= stmax0) {
#pragma unroll
            for (int r = 0; r < 4; ++r) {
                int t = tt0 * 16 + quad * 4 + r;
                int s = st * 16 + lane15;
                float val = 0.f;
                if (st <= tt0) val = (s <= t) ? s0a[st][r] * __expf(slope * (float)(t - s)) : 0.f;
                Ps[t * 136 + s] = f2bfu(val);
            }
        }
    }
    __syncthreads();
    // ---- phase 2: O = P*V + diag(lam^(t+1)) Q*S_prev ----
    f32x4 oa0[8] = {};
    f32x4 oa1[8] = {};
    float lam0 = __expf(slope * (float)(tt0 * 16 + lane15 + 1));
    float lam1 = __expf(slope * (float)(tt1 * 16 + lane15 + 1));
    bf16x8 qs0[4], qs1[4];
#pragma unroll
    for (int ds = 0; ds < 4; ++ds)
#pragma unroll
        for (int kk = 0; kk < 8; ++kk) {
            qs0[ds][kk] = (__bf16)((float)qf0[ds][kk] * lam0);
            qs1[ds][kk] = (__bf16)((float)qf1[ds][kk] * lam1);
        }
    const ushort* spb = Spb + ((size_t)c * 2048 + h * 128) * 128;
#pragma unroll
    for (int vt = 0; vt < 8; ++vt)
#pragma unroll
        for (int ds = 0; ds < 4; ++ds) {
            bf16x8 bfrag = *(const bf16x8*)&spb[(vt * 16 + lane15) * 128 + ds * 32 + quad * 8];
            oa0[vt] = __builtin_amdgcn_mfma_f32_16x16x32_bf16(qs0[ds], bfrag, oa0[vt], 0, 0, 0);
            oa1[vt] = __builtin_amdgcn_mfma_f32_16x16x32_bf16(qs1[ds], bfrag, oa1[vt], 0, 0, 0);
        }
    const ushort* vbase = vT + (size_t)h * 128 * T_SEQ + t0;
    int ns0 = (tt0 + 2) >> 1, ns1 = (tt1 + 2) >> 1;
#pragma unroll
    for (int s32 = 0; s32 < 4; ++s32) {
        if (s32 < ns1) {
            bf16x8 af = *(const bf16x8*)&Ps[(tt1 * 16 + lane15) * 136 + s32 * 32 + quad * 8];
#pragma unroll
            for (int vt = 0; vt < 8; ++vt) {
                bf16x8 bfrag = *(const bf16x8*)&vbase[(size_t)(vt * 16 + lane15) * T_SEQ + s32 * 32 + quad * 8];
                oa1[vt] = __builtin_amdgcn_mfma_f32_16x16x32_bf16(af, bfrag, oa1[vt], 0, 0, 0);
            }
        }
    }
#pragma unroll
    for (int s32 = 0; s32 < 2; ++s32) {
        if (s32 < ns0) {
            bf16x8 af = *(const bf16x8*)&Ps[(tt0 * 16 + lane15) * 136 + s32 * 32 + quad * 8];
#pragma unroll
            for (int vt = 0; vt < 8; ++vt) {
                bf16x8 bfrag = *(const bf16x8*)&vbase[(size_t)(vt * 16 + lane15) * T_SEQ + s32 * 32 + quad * 8];
                oa0[vt] = __builtin_amdgcn_mfma_f32_16x16x32_bf16(af, bfrag, oa0[vt], 0, 0, 0);
            }
        }
    }
    // ---- epilogue (bf16) ----
#pragma unroll
    for (int vt = 0; vt < 8; ++vt)
#pragma unroll
        for (int r = 0; r < 4; ++r) {
            o[(size_t)(t0 + tt0 * 16 + quad * 4 + r) * 2048 + h * 128 + vt * 16 + lane15] = f2bfu(oa0[vt][r]);
            o[(size_t)(t0 + tt1 * 16 + quad * 4 + r) * 2048 + h * 128 + vt * 16 + lane15] = f2bfu(oa1[vt][r]);
        }
}

// ---------------- group RMS-norm * g_norm_w * sigmoid-gate -> bf16 ----------------
__global__ __launch_bounds__(256) void gnorm_gate(const ushort* __restrict__ o,
                                                  const ushort* __restrict__ gate,
                                                  const float* __restrict__ gw,
                                                  ushort* __restrict__ gg) {
    int t = blockIdx.x;
    int tid = threadIdx.x;
    const ushort* op = o + (size_t)t * 2048 + tid * 8;
    bf16x8 xv = *(const bf16x8*)op;
    float x[8];
    float ss = 0.0f;
#pragma unroll
    for (int i = 0; i < 8; ++i) { x[i] = (float)xv[i]; ss += x[i] * x[i]; }
#pragma unroll
    for (int off = 16; off > 0; off >>= 1) ss += __shfl_xor(ss, off);  // 32-thread group = 256 elems
    float r = rsqrtf(ss * (1.0f / 256.0f) + 1e-6f);
    const ushort* gp = gate + (size_t)t * 2048;
#pragma unroll
    for (int i = 0; i < 8; ++i) {
        int j = tid * 8 + i;
        float val = x[i] * r * gw[j] * bfu2f(gp[j]);
        gg[(size_t)t * 2048 + j] = f2bfu(val);
    }
}

extern "C" void kernel_launch(void* const* d_in, const int* in_sizes, int n_in,
                              void* d_out, int out_size, void* d_ws, size_t ws_size,
                              hipStream_t stream) {
    const int* positions   = (const int*)d_in[0];
    const float* hidden    = (const float*)d_in[1];
    const float* S0        = (const float*)d_in[2];
    const float* w_qkv     = (const float*)d_in[3];
    const float* w_g       = (const float*)d_in[4];
    const float* w_dense   = (const float*)d_in[5];
    const float* qw        = (const float*)d_in[6];
    const float* kw        = (const float*)d_in[7];
    const float* gw        = (const float*)d_in[8];

    char* ws = (char*)d_ws;
    ushort* qkv     = (ushort*)ws;                    // bf16 T x 6144            [0, 50331648)
    ushort* wqkv_t  = (ushort*)(ws + 50331648);       // bf16 6144 x 2048 (25.2M) — Bcat rows 0..6143
    ushort* wg_t    = (ushort*)(ws + 75497472);       // bf16 2048 x 2048 (8.4M)  — Bcat rows 6144..8191
    float2* ropet   = (float2*)(ws + 159383552);      // 1 MB — separate region (prep writes all at once)
    float*  PT      = (float*)(ws + 50331648);        // fp32 32x16x128x128 (33.6M) — aliases wqkv_t/wg_t (dead)
    ushort* wd_t    = (ushort*)(ws + 83886080);       // bf16 2048 x 2048 (8.4M)
    ushort* gatebuf = (ushort*)(ws + 92274688);       // bf16 T x 2048 (16.8M)
    ushort* hid_b   = (ushort*)(ws + 109051904);      // bf16 T x 2048 (16.8M)
    ushort* Spb     = (ushort*)(ws + 109051904);      // bf16 32x16x128x128 (16.8M) — aliases hid_b (dead)
    ushort* kT      = (ushort*)(ws + 125829120);      // bf16 16x128x4096 (16.8M)
    ushort* vT      = (ushort*)(ws + 142606336);      // bf16 16x128x4096 (16.8M)
    ushort* gg      = (ushort*)ws;                    // aliases qkv (dead by gnorm time)  total 160,432,128

    float* out  = (float*)d_out;
    float* Sfin = out + (size_t)T_SEQ * HID_C;
    ushort* obuf = (ushort*)d_out;                    // out-region doubles as bf16 attn scratch

    // one launch: cvt + 3 transposes + rope table (all independent preprocessing)
    prep_all<<<9728, 256, 0, stream>>>(hidden, hid_b, w_qkv, wqkv_t, w_g, wg_t,
                                       w_dense, wd_t, positions, ropet);

    // 128x128 tiles: (8192/128)*(4096/128) = 64*32 = 2048 blocks of 256 thr, 2 blocks/CU
    gemm_fused<<<dim3(2048), 256, 0, stream>>>(hid_b, wqkv_t, qkv, gatebuf, HID_C);

    qk_rope_T<<<dim3(T_SEQ / 64, 48), 256, 0, stream>>>(qkv, ropet, qw, kw, kT, vT);

    chunk_partial<<<dim3(32, 16), 256, 0, stream>>>(kT, vT, PT);
    scan_states<<<2048, 128, 0, stream>>>(PT, S0, Spb, Sfin);
    chunk_out<<<dim3(32, 16), 256, 0, stream>>>(qkv, vT, Spb, obuf);
    gnorm_gate<<<T_SEQ, 256, 0, stream>>>(obuf, gatebuf, gw, gg);

    // 128x128 tiles: (4096/128)*(2048/128) = 32*16 = 512 blocks of 256 thr, 2 blocks/CU
    gemm_dense<<<dim3(512), 256, 0, stream>>>(gg, wd_t, out, HID_C, HID_C);
}

// Round 9
// 429.077 us; speedup vs baseline: 1.0252x; 1.0252x over previous
//
#include <hip/hip_runtime.h>
#include <hip/hip_bf16.h>

using bf16x8 = __attribute__((ext_vector_type(8))) __bf16;
using f32x4  = __attribute__((ext_vector_type(4))) float;

constexpr int T_SEQ = 4096;
constexpr int HID_C = 2048;
constexpr int NH    = 16;
constexpr int QKV_N = 6144;

__device__ __forceinline__ float head_slope(int h) {
    // slope[h] = -2^{-(h+1)/2} * (1 - 1/31 + 1e-5)
    return -exp2f(-0.5f * (float)(h + 1)) * 0.967751935483871f;
}

__device__ __forceinline__ ushort f2bfu(float f) {
    __hip_bfloat16 h = __float2bfloat16(f);
    return *(ushort*)&h;
}
__device__ __forceinline__ float bfu2f(ushort u) {
    union { unsigned int i; float f; } x; x.i = ((unsigned int)u) << 16; return x.f;
}

// async global -> LDS, 16 bytes per lane; LDS dest = wave-uniform base + lane*16
__device__ __forceinline__ void async16(const ushort* g, ushort* l) {
    __builtin_amdgcn_global_load_lds((const __attribute__((address_space(1))) void*)g,
                                     (__attribute__((address_space(3))) void*)l, 16, 0, 0);
}

template<int N> __device__ __forceinline__ void waitcnt_vm() {
    if constexpr (N == 0)      asm volatile("s_waitcnt vmcnt(0)" ::: "memory");
    else if constexpr (N == 2) asm volatile("s_waitcnt vmcnt(2)" ::: "memory");
    else if constexpr (N == 4) asm volatile("s_waitcnt vmcnt(4)" ::: "memory");
    else if constexpr (N == 6) asm volatile("s_waitcnt vmcnt(6)" ::: "memory");
}

// ============ merged preprocessing: cvt_bf16 + 3x transpose_cvt + rope_tab in ONE launch ============
__device__ __forceinline__ void cvt_body(const float* __restrict__ src, ushort* __restrict__ dst,
                                         int bid, int tid) {
    int i = (bid * 256 + tid) * 8;
    float4 a = *(const float4*)(src + i);
    float4 b = *(const float4*)(src + i + 4);
    ushort4 ua = {f2bfu(a.x), f2bfu(a.y), f2bfu(a.z), f2bfu(a.w)};
    ushort4 ub = {f2bfu(b.x), f2bfu(b.y), f2bfu(b.z), f2bfu(b.w)};
    *(ushort4*)(dst + i) = ua;
    *(ushort4*)(dst + i + 4) = ub;
}

__device__ __forceinline__ void transpose_body(const float* __restrict__ src,
                                               ushort* __restrict__ dst,
                                               int R, int C, int bx, int by, int t,
                                               ushort (*tile)[68]) {
    int tr = by * 64, tc = bx * 64;
    int r0 = t >> 4;
    int c4 = (t & 15) << 2;
#pragma unroll
    for (int p = 0; p < 4; ++p) {
        int row = r0 + p * 16;
        float4 v = *(const float4*)&src[(size_t)(tr + row) * C + tc + c4];
        tile[row][c4 + 0] = f2bfu(v.x);
        tile[row][c4 + 1] = f2bfu(v.y);
        tile[row][c4 + 2] = f2bfu(v.z);
        tile[row][c4 + 3] = f2bfu(v.w);
    }
    __syncthreads();
#pragma unroll
    for (int p = 0; p < 4; ++p) {
        int orow = r0 + p * 16;
        ushort4 u;
        u.x = tile[c4 + 0][orow];
        u.y = tile[c4 + 1][orow];
        u.z = tile[c4 + 2][orow];
        u.w = tile[c4 + 3][orow];
        *(ushort4*)&dst[(size_t)(tc + orow) * R + tr + c4] = u;
    }
}

// grid: [0,4096) cvt | [4096,7168) w_qkv T | [7168,8192) w_g T | [8192,9216) w_dense T | [9216,9728) rope
__global__ __launch_bounds__(256) void prep_all(const float* __restrict__ hidden,
                                                ushort* __restrict__ hid_b,
                                                const float* __restrict__ w_qkv,
                                                ushort* __restrict__ wqkv_t,
                                                const float* __restrict__ w_g,
                                                ushort* __restrict__ wg_t,
                                                const float* __restrict__ w_dense,
                                                ushort* __restrict__ wd_t,
                                                const int* __restrict__ positions,
                                                float2* __restrict__ ropet) {
    __shared__ ushort tile[64][68];
    int b = blockIdx.x, t = threadIdx.x;
    if (b < 4096) {
        cvt_body(hidden, hid_b, b, t);
    } else if (b < 7168) {
        int bb = b - 4096;                       // 96 x 32 tiles
        transpose_body(w_qkv, wqkv_t, HID_C, QKV_N, bb % 96, bb / 96, t, tile);
    } else if (b < 8192) {
        int bb = b - 7168;                       // 32 x 32
        transpose_body(w_g, wg_t, HID_C, HID_C, bb % 32, bb / 32, t, tile);
    } else if (b < 9216) {
        int bb = b - 8192;                       // 32 x 32
        transpose_body(w_dense, wd_t, HID_C, HID_C, bb % 32, bb / 32, t, tile);
    } else {
        int i = (b - 9216) * 256 + t;            // i < T*32
        int tt = i >> 5, fi = i & 31;
        float inv = expf((float)fi * -0.2878231366f);   // ln(10000)/32
        float freq = (float)positions[tt] * inv;
        float sn, cs;
        sincosf(freq, &sn, &cs);
        ropet[i] = make_float2(cs, sn);
    }
}

// ============== 256x256 flat-K-tile MFMA GEMM core (BK=64, 8 waves, dbuf LDS) ==============
// R3-proven schedule (best of 6 measured variants: flat 135.5 > 8-phase 147 > SGB 143/169 >
// 128sq 2blk/CU 141.5): per K-tile {all ds_reads (compiler-counted lgkm waits) ; stage t+1 ;
// MFMA ; vmcnt(0) (cheap: issued ~2500cyc earlier) ; 1 barrier}.
template<int MI, int BN>
__device__ __forceinline__ void gemm8_core(const ushort* __restrict__ Ag,
                                           const ushort* __restrict__ Bg,
                                           int K, int bm, int bn,
                                           ushort* sh, f32x4 (&acc)[MI][4]) {
    constexpr int WM = 16 / MI;          // waves along M: 2 or 4
    constexpr int WN = 8 / WM;           // waves along N: 4 or 2
    constexpr int SB = BN / 128;         // async16 per wave per B-half: 2 or 1
    constexpr int AH = (MI >= 8) ? 2 : 1;// A-read halves (VGPR pressure relief)
    constexpr int MH = MI / AH;

    const int tid  = threadIdx.x;
    const int lane = tid & 63;
    const int wave = tid >> 6;
    const int lane15 = lane & 15, quad = lane >> 4;
    const int wm = wave / WN, wn = wave % WN;
    const int swz = lane15 & 7;

    ushort* const ldsA0 = sh;              // [256][64] bf16, rows swizzled: phys grp p of row r = logical p^(r&7)
    ushort* const ldsA1 = sh + 16384;
    ushort* const ldsB0 = sh + 32768;      // [BN][64]
    ushort* const ldsB1 = sh + 32768 + BN * 64;

    // staging: lane l covers row (l>>3) of an 8-row chunk, physical 16B group (l&7),
    // so it must READ logical group (l&7)^(l>>3)  (involution: same xor on the read side)
    const int srow = lane >> 3;
    const int scol = ((lane & 7) ^ srow) << 3;
    const ushort* gA = Ag + (size_t)(bm + srow) * K + scol;
    const ushort* gB = Bg + (size_t)(bn + srow) * K + scol;
    const int ro  = wave * 16;             // A: each wave stages 2x 8-row chunks per half-tile
    const int roB = wave * 8 * SB;         // B: SB 8-row chunks per half-tile
    const int NT = K >> 6;

#define STAGE_A(L, k0) do { \
    _Pragma("unroll") for (int h = 0; h < 2; ++h) \
    _Pragma("unroll") for (int q = 0; q < 2; ++q) \
        async16(gA + (size_t)((h) * 128 + ro + q * 8) * K + (k0), (L) + ((h) * 128 + ro + q * 8) * 64); } while (0)
#define STAGE_B(L, k0) do { \
    _Pragma("unroll") for (int h = 0; h < 2; ++h) \
    _Pragma("unroll") for (int q = 0; q < SB; ++q) \
        async16(gB + (size_t)((h) * (BN / 2) + roB + q * 8) * K + (k0), (L) + ((h) * (BN / 2) + roB + q * 8) * 64); } while (0)

    // prologue: tile0 -> buf0
    STAGE_A(ldsA0, 0);
    STAGE_B(ldsB0, 0);
    waitcnt_vm<0>();
    asm volatile("s_barrier" ::: "memory");

    for (int t = 0; t < NT; ++t) {
        const ushort* LA = (t & 1) ? ldsA1 : ldsA0;
        const ushort* LB = (t & 1) ? ldsB1 : ldsB0;
        ushort* LAn = (t & 1) ? ldsA0 : ldsA1;
        ushort* LBn = (t & 1) ? ldsB0 : ldsB1;
        // ---- all B-frags + first A-half (compiler inserts counted lgkm waits) ----
        bf16x8 bfr[4][2];
#pragma unroll
        for (int j = 0; j < 4; ++j)
#pragma unroll
            for (int ks = 0; ks < 2; ++ks)
                bfr[j][ks] = *(const bf16x8*)&LB[(wn * 64 + j * 16 + lane15) * 64 + (((ks * 4 + quad) ^ swz) << 3)];
        bf16x8 af0[MH][2];
#pragma unroll
        for (int i = 0; i < MH; ++i)
#pragma unroll
            for (int ks = 0; ks < 2; ++ks)
                af0[i][ks] = *(const bf16x8*)&LA[(wm * (MI * 16) + i * 16 + lane15) * 64 + (((ks * 4 + quad) ^ swz) << 3)];
        // ---- stage tile t+1 into the other buffers (WAR-safe: last read before this tile's barrier) ----
        if (t + 1 < NT) {
            STAGE_A(LAn, (t + 1) << 6);
            STAGE_B(LBn, (t + 1) << 6);
        }
        __builtin_amdgcn_s_setprio(1);
#pragma unroll
        for (int i = 0; i < MH; ++i)
#pragma unroll
            for (int j = 0; j < 4; ++j)
#pragma unroll
                for (int ks = 0; ks < 2; ++ks)
                    acc[i][j] = __builtin_amdgcn_mfma_f32_16x16x32_bf16(af0[i][ks], bfr[j][ks], acc[i][j], 0, 0, 0);
        __builtin_amdgcn_s_setprio(0);
        if constexpr (AH == 2) {
            // ---- second A-half: reads overlap first MFMA cluster ----
            bf16x8 af1[MH][2];
#pragma unroll
            for (int i = 0; i < MH; ++i)
#pragma unroll
                for (int ks = 0; ks < 2; ++ks)
                    af1[i][ks] = *(const bf16x8*)&LA[(wm * (MI * 16) + (MH + i) * 16 + lane15) * 64 + (((ks * 4 + quad) ^ swz) << 3)];
            __builtin_amdgcn_s_setprio(1);
#pragma unroll
            for (int i = 0; i < MH; ++i)
#pragma unroll
                for (int j = 0; j < 4; ++j)
#pragma unroll
                    for (int ks = 0; ks < 2; ++ks)
                        acc[MH + i][j] = __builtin_amdgcn_mfma_f32_16x16x32_bf16(af1[i][ks], bfr[j][ks], acc[MH + i][j], 0, 0, 0);
            __builtin_amdgcn_s_setprio(0);
        }
        // t+1 staging landed long ago (issued ~2500cyc back); drain + handoff
        waitcnt_vm<0>();
        asm volatile("s_barrier" ::: "memory");
    }
#undef STAGE_A
#undef STAGE_B
}

// ============== 128x128 flat-K-tile core: 4 waves, 64 KiB LDS (for the dense GEMM) ==============
__device__ __forceinline__ void gemm4_core(const ushort* __restrict__ Ag,
                                           const ushort* __restrict__ Bg,
                                           int K, int bm, int bn,
                                           ushort* sh, f32x4 (&acc)[4][4]) {
    const int tid  = threadIdx.x;
    const int lane = tid & 63;
    const int wave = tid >> 6;             // 4 waves: 2M x 2N
    const int lane15 = lane & 15, quad = lane >> 4;
    const int wm = wave >> 1, wn = wave & 1;
    const int swz = lane15 & 7;

    ushort* const ldsA0 = sh;              // [128][64]
    ushort* const ldsA1 = sh + 8192;
    ushort* const ldsB0 = sh + 16384;
    ushort* const ldsB1 = sh + 24576;

    const int srow = lane >> 3;
    const int scol = ((lane & 7) ^ srow) << 3;
    const ushort* gA = Ag + (size_t)(bm + srow) * K + scol;
    const ushort* gB = Bg + (size_t)(bn + srow) * K + scol;
    const int ro = wave * 32;              // each wave stages 4x 8-row chunks (128 rows / 4 waves)
    const int NT = K >> 6;

#define STG(L, g, k0) do { \
    _Pragma("unroll") for (int q = 0; q < 4; ++q) \
        async16((g) + (size_t)(ro + q * 8) * K + (k0), (L) + (ro + q * 8) * 64); } while (0)

    STG(ldsA0, gA, 0);
    STG(ldsB0, gB, 0);
    waitcnt_vm<0>();
    asm volatile("s_barrier" ::: "memory");

    for (int t = 0; t < NT; ++t) {
        const ushort* LA = (t & 1) ? ldsA1 : ldsA0;
        const ushort* LB = (t & 1) ? ldsB1 : ldsB0;
        ushort* LAn = (t & 1) ? ldsA0 : ldsA1;
        ushort* LBn = (t & 1) ? ldsB0 : ldsB1;
        bf16x8 bfr[4][2];
#pragma unroll
        for (int j = 0; j < 4; ++j)
#pragma unroll
            for (int ks = 0; ks < 2; ++ks)
                bfr[j][ks] = *(const bf16x8*)&LB[(wn * 64 + j * 16 + lane15) * 64 + (((ks * 4 + quad) ^ swz) << 3)];
        bf16x8 af[4][2];
#pragma unroll
        for (int i = 0; i < 4; ++i)
#pragma unroll
            for (int ks = 0; ks < 2; ++ks)
                af[i][ks] = *(const bf16x8*)&LA[(wm * 64 + i * 16 + lane15) * 64 + (((ks * 4 + quad) ^ swz) << 3)];
        if (t + 1 < NT) {
            STG(LAn, gA, (t + 1) << 6);
            STG(LBn, gB, (t + 1) << 6);
        }
        __builtin_amdgcn_s_setprio(1);
#pragma unroll
        for (int i = 0; i < 4; ++i)
#pragma unroll
            for (int j = 0; j < 4; ++j)
#pragma unroll
                for (int ks = 0; ks < 2; ++ks)
                    acc[i][j] = __builtin_amdgcn_mfma_f32_16x16x32_bf16(af[i][ks], bfr[j][ks], acc[i][j], 0, 0, 0);
        __builtin_amdgcn_s_setprio(0);
        waitcnt_vm<0>();
        asm volatile("s_barrier" ::: "memory");
    }
#undef STG
}

// ---- fused qkv+gate GEMM: Bcat = [wqkv_t ; wg_t] (8192 x K). cols<6144 -> qkv, else sigmoid -> gate ----
__global__ __launch_bounds__(512, 2) void gemm_fused(const ushort* __restrict__ A,
                                                     const ushort* __restrict__ Bcat,
                                                     ushort* __restrict__ qkv,
                                                     ushort* __restrict__ gate, int K) {
    __shared__ ushort sh[65536];           // 128 KiB: A dbuf 64K + B dbuf 64K
    // 2D-chunked XCD swizzle: GM=16 x GN=32 tiles; each XCD owns an 8m x 8n region
    // (n-fastest inside) -> concurrent per-XCD working set = 4 A-tiles + 8 B-tiles.
    int bid = blockIdx.x;
    int x = bid & 7, w = bid >> 3;         // XCD id, within-XCD order
    int rm = x >> 2, rn = x & 3;           // region coords: 2 x 4 regions
    int wm_i = w >> 3, wn_i = w & 7;       // 8 x 8 blocks inside region
    int bm = (rm * 8 + wm_i) * 256;
    int bn = (rn * 8 + wn_i) * 256;
    f32x4 acc[8][4] = {};
    gemm8_core<8, 256>(A, Bcat, K, bm, bn, sh, acc);

    int lane = threadIdx.x & 63, wave = threadIdx.x >> 6;
    int lane15 = lane & 15, quad = lane >> 4;
    int wm = wave >> 2, wn = wave & 3;
    bool isg = bn >= QKV_N;
    ushort* outp = isg ? gate : qkv;
    int ncol = isg ? HID_C : QKV_N;
    int cb = (isg ? bn - QKV_N : bn) + wn * 64;
    int rb = bm + wm * 128;
#pragma unroll
    for (int i = 0; i < 8; ++i)
#pragma unroll
        for (int j = 0; j < 4; ++j) {
            int col = cb + j * 16 + lane15;
#pragma unroll
            for (int r = 0; r < 4; ++r) {
                float v = acc[i][j][r];
                if (isg) v = 1.0f / (1.0f + __expf(-v));
                outp[(size_t)(rb + i * 16 + quad * 4 + r) * ncol + col] = f2bfu(v);
            }
        }
}

// ---- dense GEMM: fp32 out. BM=128 x BN=128, 256 thr, 64 KiB LDS (512 blocks, 2 blocks/CU) ----
__global__ __launch_bounds__(256, 2) void gemm_dense(const ushort* __restrict__ A,
                                                     const ushort* __restrict__ Bt,
                                                     float* __restrict__ Cout, int N, int K) {
    __shared__ ushort sh[32768];           // 64 KiB
    // GM=32 x GN=16 tiles; each XCD owns an 8m x 8n region (n-fastest inside)
    int bid = blockIdx.x;
    int x = bid & 7, w = bid >> 3;
    int rm = x >> 1, rn = x & 1;           // 4 x 2 regions
    int wm_i = w >> 3, wn_i = w & 7;       // 8 x 8 blocks inside region
    int bm = (rm * 8 + wm_i) * 128;
    int bn = (rn * 8 + wn_i) * 128;
    f32x4 acc[4][4] = {};
    gemm4_core(A, Bt, K, bm, bn, sh, acc);

    int lane = threadIdx.x & 63, wave = threadIdx.x >> 6;
    int lane15 = lane & 15, quad = lane >> 4;
    int wm = wave >> 1, wn = wave & 1;
    int cb = bn + wn * 64;
    int rb = bm + wm * 64;
#pragma unroll
    for (int i = 0; i < 4; ++i)
#pragma unroll
        for (int j = 0; j < 4; ++j) {
            int col = cb + j * 16 + lane15;
#pragma unroll
            for (int r = 0; r < 4; ++r)
                Cout[(size_t)(rb + i * 16 + quad * 4 + r) * N + col] = acc[i][j][r];
        }
}

// ---- fused q/k RMSNorm + RoPE (+q scale) and k/v transpose.  y: kind = y>>4 (0=q,1=k,2=v), h = y&15 ----
// kT/vT layout is CHUNK-TILED: [h][c=t/128][128 d][128 t_in_chunk]  (contiguous 32KB slab per
// (h,c) -> chunk_partial/chunk_out read full 64B lines instead of 16B granules at 8KB stride)
__global__ __launch_bounds__(256) void qk_rope_T(ushort* __restrict__ qkv,
                                                 const float2* __restrict__ tab,
                                                 const float* __restrict__ qw,
                                                 const float* __restrict__ kw,
                                                 ushort* __restrict__ kT,
                                                 ushort* __restrict__ vT) {
    __shared__ ushort tile[64][132];
    int bt = blockIdx.x;
    int kind = blockIdx.y >> 4, h = blockIdx.y & 15;
    int tid = threadIdx.x;
    int row = tid >> 2, c = tid & 3, d0 = c * 32;
    int t = bt * 64 + row;
    ushort* base = qkv + (size_t)t * QKV_N + kind * 2048 + h * 128 + d0;
    bf16x8 pk[4];
#pragma unroll
    for (int p = 0; p < 4; ++p) pk[p] = *(const bf16x8*)(base + p * 8);
    if (kind < 2) {
        float x[32];
        float ss = 0.f;
#pragma unroll
        for (int p = 0; p < 4; ++p)
#pragma unroll
            for (int i = 0; i < 8; ++i) {
                x[p * 8 + i] = (float)pk[p][i];
                ss += x[p * 8 + i] * x[p * 8 + i];
            }
        ss += __shfl_xor(ss, 1);
        ss += __shfl_xor(ss, 2);
        float rr = rsqrtf(ss * (1.0f / 128.0f) + 1e-6f);
        const float* w = (kind == 0) ? qw : kw;
#pragma unroll
        for (int i = 0; i < 32; ++i) x[i] *= rr * w[d0 + i];
        // rope on d<64: c=0 holds x1 (d 0..31), c=1 holds x2 (d 32..63); partner via xor 1
#pragma unroll
        for (int i = 0; i < 32; ++i) {
            float p = __shfl_xor(x[i], 1);
            if (c < 2) {
                float2 rt = tab[t * 32 + i];
                x[i] = (c == 0) ? (x[i] * rt.x - p * rt.y) : (x[i] * rt.x + p * rt.y);
            }
        }
        float sc = (kind == 0) ? 0.08838834764831845f : 1.0f;   // 128^-0.5 on q
#pragma unroll
        for (int p = 0; p < 4; ++p)
#pragma unroll
            for (int i = 0; i < 8; ++i) pk[p][i] = (__bf16)(x[p * 8 + i] * sc);
#pragma unroll
        for (int p = 0; p < 4; ++p) *(bf16x8*)(base + p * 8) = pk[p];
    }
    if (kind >= 1) {
        // transpose 64t x 128d -> chunk-tiled out[h][bt>>1][d][ (bt&1)*64 + t ]
#pragma unroll
        for (int p = 0; p < 4; ++p) {
            ushort4* s = (ushort4*)&pk[p];
            *(ushort4*)&tile[row][d0 + p * 8]     = s[0];
            *(ushort4*)&tile[row][d0 + p * 8 + 4] = s[1];
        }
        __syncthreads();
        ushort* outT = ((kind == 1) ? kT : vT)
                     + ((size_t)(h * 32 + (bt >> 1)) * 128) * 128 + (bt & 1) * 64;
        int d = tid >> 1, half = tid & 1;
#pragma unroll
        for (int tt = 0; tt < 8; ++tt) {
            int tl = half * 32 + tt * 4;
            ushort4 u;
            u.x = tile[tl + 0][d];
            u.y = tile[tl + 1][d];
            u.z = tile[tl + 2][d];
            u.w = tile[tl + 3][d];
            *(ushort4*)&outT[(size_t)d * 128 + tl] = u;
        }
    }
}

// ------- per-chunk partial state (transposed): PT[c,h][v][d] = sum_j lam^(127-j) v_j[v] k_j[d] -------
__global__ __launch_bounds__(256) void chunk_partial(const ushort* __restrict__ kT,
                                                     const ushort* __restrict__ vT,
                                                     float* __restrict__ PT) {
    int c = blockIdx.x, h = blockIdx.y;
    float slope = head_slope(h);
    float lam_inv = __expf(-slope);
    int tid = threadIdx.x, lane = tid & 63, wave = tid >> 6;
    int lane15 = lane & 15, quad = lane >> 4;
    int wv = (wave & 1) * 64, wd = (wave >> 1) * 64;
    // chunk-tiled layout: slab (h,c) is contiguous [128 d][128 t]
    const ushort* vbase = vT + ((size_t)(h * 32 + c) * 128) * 128;
    const ushort* kbase = kT + ((size_t)(h * 32 + c) * 128) * 128;
    f32x4 acc[4][4] = {};
#pragma unroll
    for (int j0 = 0; j0 < 128; j0 += 32) {
        float w8[8];
        w8[0] = __expf(slope * (float)(127 - (j0 + quad * 8)));
#pragma unroll
        for (int kk = 1; kk < 8; ++kk) w8[kk] = w8[kk - 1] * lam_inv;
        bf16x8 afr[4], bfr[4];
#pragma unroll
        for (int i = 0; i < 4; ++i) {
            bf16x8 v = *(const bf16x8*)&vbase[(size_t)(wv + i * 16 + lane15) * 128 + j0 + quad * 8];
#pragma unroll
            for (int kk = 0; kk < 8; ++kk) afr[i][kk] = (__bf16)((float)v[kk] * w8[kk]);
        }
#pragma unroll
        for (int j = 0; j < 4; ++j)
            bfr[j] = *(const bf16x8*)&kbase[(size_t)(wd + j * 16 + lane15) * 128 + j0 + quad * 8];
#pragma unroll
        for (int i = 0; i < 4; ++i)
#pragma unroll
            for (int j = 0; j < 4; ++j)
                acc[i][j] = __builtin_amdgcn_mfma_f32_16x16x32_bf16(afr[i], bfr[j], acc[i][j], 0, 0, 0);
    }
    float* out = PT + ((size_t)c * 16 + h) * 16384;
#pragma unroll
    for (int i = 0; i < 4; ++i)
#pragma unroll
        for (int j = 0; j < 4; ++j)
#pragma unroll
            for (int r = 0; r < 4; ++r)
                out[(size_t)(wv + i * 16 + quad * 4 + r) * 128 + wd + j * 16 + lane15] = acc[i][j][r];
}

// ------- sequential scan over 32 chunks: PT -> Spb (bf16 prefix states) + Sfin -------
__global__ __launch_bounds__(128) void scan_states(const float* __restrict__ PT,
                                                   const float* __restrict__ S0,
                                                   ushort* __restrict__ Spb,
                                                   float* __restrict__ Sfin) {
    int hv = blockIdx.x;              // h*128 + v
    int d = threadIdx.x;              // k-dim
    int h = hv >> 7, v = hv & 127;
    float lamC = __expf(head_slope(h) * 128.0f);
    float s = S0[(size_t)h * 16384 + d * 128 + v];
#pragma unroll
    for (int c = 0; c < 32; ++c) {
        size_t idx = ((size_t)c * 2048 + hv) * 128 + d;
        Spb[idx] = f2bfu(s);          // state BEFORE chunk c, layout [c][h][v][d]
        s = s * lamC + PT[idx];
    }
    Sfin[(size_t)h * 16384 + d * 128 + v] = s;
}

// ------- per-chunk output: QK^T (masked/decayed) * V + lam^(t+1) * Q * S_prev -------
__global__ __launch_bounds__(256) void chunk_out(const ushort* __restrict__ qkv,
                                                 const ushort* __restrict__ vT,
                                                 const ushort* __restrict__ Spb,
                                                 ushort* __restrict__ o) {
    int c = blockIdx.x, h = blockIdx.y;
    float slope = head_slope(h);
    __shared__ ushort Ps[128 * 136];   // padded: row stride 272B -> conflict-free b128
    int tid = threadIdx.x, lane = tid & 63, wave = tid >> 6;
    int lane15 = lane & 15, quad = lane >> 4;
    int t0 = c * 128;
    int tt0 = wave, tt1 = 7 - wave;    // owned t-tiles (balanced triangular split)
    const ushort* qbase = qkv + (size_t)t0 * QKV_N + h * 128;
    const ushort* kbase = qbase + 2048;

    bf16x8 qf0[4], qf1[4];
#pragma unroll
    for (int ds = 0; ds < 4; ++ds) {
        qf0[ds] = *(const bf16x8*)&qbase[(size_t)(tt0 * 16 + lane15) * QKV_N + ds * 32 + quad * 8];
        qf1[ds] = *(const bf16x8*)&qbase[(size_t)(tt1 * 16 + lane15) * QKV_N + ds * 32 + quad * 8];
    }
    // ---- phase 1: scores ----
    f32x4 s0a[4] = {};
    f32x4 s1a[8] = {};
#pragma unroll
    for (int st = 0; st < 8; ++st) {
        if (st <= tt1) {
            bf16x8 kf[4];
#pragma unroll
            for (int ds = 0; ds < 4; ++ds)
                kf[ds] = *(const bf16x8*)&kbase[(size_t)(st * 16 + lane15) * QKV_N + ds * 32 + quad * 8];
#pragma unroll
            for (int ds = 0; ds < 4; ++ds)
                s1a[st] = __builtin_amdgcn_mfma_f32_16x16x32_bf16(qf1[ds], kf[ds], s1a[st], 0, 0, 0);
            if (st <= tt0) {
#pragma unroll
                for (int ds = 0; ds < 4; ++ds)
                    s0a[st] = __builtin_amdgcn_mfma_f32_16x16x32_bf16(qf0[ds], kf[ds], s0a[st], 0, 0, 0);
            }
        }
    }
    // ---- park masked/decayed scores (zero strip pads odd 16-blocks to 32) ----
    int stmax0 = tt0 + ((tt0 & 1) ? 0 : 1);
    int stmax1 = tt1 + ((tt1 & 1) ? 0 : 1);
#pragma unroll
    for (int st = 0; st < 8; ++st) {
        if (st <= stmax1) {
#pragma unroll
            for (int r = 0; r < 4; ++r) {
                int t = tt1 * 16 + quad * 4 + r;
                int s = st * 16 + lane15;
                float val = 0.f;
                if (st <= tt1) val = (s <= t) ? s1a[st][r] * __expf(slope * (float)(t - s)) : 0.f;
                Ps[t * 136 + s] = f2bfu(val);
            }
        }
    }
#pragma unroll
    for (int st = 0; st < 5; ++st) {
        if (st <= stmax0) {
#pragma unroll
            for (int r = 0; r < 4; ++r) {
                int t = tt0 * 16 + quad * 4 + r;
                int s = st * 16 + lane15;
                float val = 0.f;
                if (st <= tt0) val = (s <= t) ? s0a[st][r] * __expf(slope * (float)(t - s)) : 0.f;
                Ps[t * 136 + s] = f2bfu(val);
            }
        }
    }
    __syncthreads();
    // ---- phase 2: O = P*V + diag(lam^(t+1)) Q*S_prev ----
    f32x4 oa0[8] = {};
    f32x4 oa1[8] = {};
    float lam0 = __expf(slope * (float)(tt0 * 16 + lane15 + 1));
    float lam1 = __expf(slope * (float)(tt1 * 16 + lane15 + 1));
    bf16x8 qs0[4], qs1[4];
#pragma unroll
    for (int ds = 0; ds < 4; ++ds)
#pragma unroll
        for (int kk = 0; kk < 8; ++kk) {
            qs0[ds][kk] = (__bf16)((float)qf0[ds][kk] * lam0);
            qs1[ds][kk] = (__bf16)((float)qf1[ds][kk] * lam1);
        }
    const ushort* spb = Spb + ((size_t)c * 2048 + h * 128) * 128;
#pragma unroll
    for (int vt = 0; vt < 8; ++vt)
#pragma unroll
        for (int ds = 0; ds < 4; ++ds) {
            bf16x8 bfrag = *(const bf16x8*)&spb[(vt * 16 + lane15) * 128 + ds * 32 + quad * 8];
            oa0[vt] = __builtin_amdgcn_mfma_f32_16x16x32_bf16(qs0[ds], bfrag, oa0[vt], 0, 0, 0);
            oa1[vt] = __builtin_amdgcn_mfma_f32_16x16x32_bf16(qs1[ds], bfrag, oa1[vt], 0, 0, 0);
        }
    // chunk-tiled layout: slab (h,c) contiguous [128 d][128 t]
    const ushort* vbase = vT + ((size_t)(h * 32 + c) * 128) * 128;
    int ns0 = (tt0 + 2) >> 1, ns1 = (tt1 + 2) >> 1;
#pragma unroll
    for (int s32 = 0; s32 < 4; ++s32) {
        if (s32 < ns1) {
            bf16x8 af = *(const bf16x8*)&Ps[(tt1 * 16 + lane15) * 136 + s32 * 32 + quad * 8];
#pragma unroll
            for (int vt = 0; vt < 8; ++vt) {
                bf16x8 bfrag = *(const bf16x8*)&vbase[(size_t)(vt * 16 + lane15) * 128 + s32 * 32 + quad * 8];
                oa1[vt] = __builtin_amdgcn_mfma_f32_16x16x32_bf16(af, bfrag, oa1[vt], 0, 0, 0);
            }
        }
    }
#pragma unroll
    for (int s32 = 0; s32 < 2; ++s32) {
        if (s32 < ns0) {
            bf16x8 af = *(const bf16x8*)&Ps[(tt0 * 16 + lane15) * 136 + s32 * 32 + quad * 8];
#pragma unroll
            for (int vt = 0; vt < 8; ++vt) {
                bf16x8 bfrag = *(const bf16x8*)&vbase[(size_t)(vt * 16 + lane15) * 128 + s32 * 32 + quad * 8];
                oa0[vt] = __builtin_amdgcn_mfma_f32_16x16x32_bf16(af, bfrag, oa0[vt], 0, 0, 0);
            }
        }
    }
    // ---- epilogue (bf16) ----
#pragma unroll
    for (int vt = 0; vt < 8; ++vt)
#pragma unroll
        for (int r = 0; r < 4; ++r) {
            o[(size_t)(t0 + tt0 * 16 + quad * 4 + r) * 2048 + h * 128 + vt * 16 + lane15] = f2bfu(oa0[vt][r]);
            o[(size_t)(t0 + tt1 * 16 + quad * 4 + r) * 2048 + h * 128 + vt * 16 + lane15] = f2bfu(oa1[vt][r]);
        }
}

// ---------------- group RMS-norm * g_norm_w * sigmoid-gate -> bf16 ----------------
__global__ __launch_bounds__(256) void gnorm_gate(const ushort* __restrict__ o,
                                                  const ushort* __restrict__ gate,
                                                  const float* __restrict__ gw,
                                                  ushort* __restrict__ gg) {
    int t = blockIdx.x;
    int tid = threadIdx.x;
    const ushort* op = o + (size_t)t * 2048 + tid * 8;
    bf16x8 xv = *(const bf16x8*)op;
    float x[8];
    float ss = 0.0f;
#pragma unroll
    for (int i = 0; i < 8; ++i) { x[i] = (float)xv[i]; ss += x[i] * x[i]; }
#pragma unroll
    for (int off = 16; off > 0; off >>= 1) ss += __shfl_xor(ss, off);  // 32-thread group = 256 elems
    float r = rsqrtf(ss * (1.0f / 256.0f) + 1e-6f);
    const ushort* gp = gate + (size_t)t * 2048;
#pragma unroll
    for (int i = 0; i < 8; ++i) {
        int j = tid * 8 + i;
        float val = x[i] * r * gw[j] * bfu2f(gp[j]);
        gg[(size_t)t * 2048 + j] = f2bfu(val);
    }
}

extern "C" void kernel_launch(void* const* d_in, const int* in_sizes, int n_in,
                              void* d_out, int out_size, void* d_ws, size_t ws_size,
                              hipStream_t stream) {
    const int* positions   = (const int*)d_in[0];
    const float* hidden    = (const float*)d_in[1];
    const float* S0        = (const float*)d_in[2];
    const float* w_qkv     = (const float*)d_in[3];
    const float* w_g       = (const float*)d_in[4];
    const float* w_dense   = (const float*)d_in[5];
    const float* qw        = (const float*)d_in[6];
    const float* kw        = (const float*)d_in[7];
    const float* gw        = (const float*)d_in[8];

    char* ws = (char*)d_ws;
    ushort* qkv     = (ushort*)ws;                    // bf16 T x 6144            [0, 50331648)
    ushort* wqkv_t  = (ushort*)(ws + 50331648);       // bf16 6144 x 2048 (25.2M) — Bcat rows 0..6143
    ushort* wg_t    = (ushort*)(ws + 75497472);       // bf16 2048 x 2048 (8.4M)  — Bcat rows 6144..8191
    float2* ropet   = (float2*)(ws + 159383552);      // 1 MB — separate region (prep writes all at once)
    float*  PT      = (float*)(ws + 50331648);        // fp32 32x16x128x128 (33.6M) — aliases wqkv_t/wg_t (dead)
    ushort* wd_t    = (ushort*)(ws + 83886080);       // bf16 2048 x 2048 (8.4M)
    ushort* gatebuf = (ushort*)(ws + 92274688);       // bf16 T x 2048 (16.8M)
    ushort* hid_b   = (ushort*)(ws + 109051904);      // bf16 T x 2048 (16.8M)
    ushort* Spb     = (ushort*)(ws + 109051904);      // bf16 32x16x128x128 (16.8M) — aliases hid_b (dead)
    ushort* kT      = (ushort*)(ws + 125829120);      // bf16 [16][32][128][128] (16.8M) chunk-tiled
    ushort* vT      = (ushort*)(ws + 142606336);      // bf16 [16][32][128][128] (16.8M) chunk-tiled
    ushort* gg      = (ushort*)ws;                    // aliases qkv (dead by gnorm time)  total 160,432,128

    float* out  = (float*)d_out;
    float* Sfin = out + (size_t)T_SEQ * HID_C;
    ushort* obuf = (ushort*)d_out;                    // out-region doubles as bf16 attn scratch

    // one launch: cvt + 3 transposes + rope table (all independent preprocessing)
    prep_all<<<9728, 256, 0, stream>>>(hidden, hid_b, w_qkv, wqkv_t, w_g, wg_t,
                                       w_dense, wd_t, positions, ropet);

    // 256x256 tiles: (8192/256)*(4096/256) = 32*16 = 512 blocks of 512 threads
    gemm_fused<<<dim3(512), 512, 0, stream>>>(hid_b, wqkv_t, qkv, gatebuf, HID_C);

    qk_rope_T<<<dim3(T_SEQ / 64, 48), 256, 0, stream>>>(qkv, ropet, qw, kw, kT, vT);

    chunk_partial<<<dim3(32, 16), 256, 0, stream>>>(kT, vT, PT);
    scan_states<<<2048, 128, 0, stream>>>(PT, S0, Spb, Sfin);
    chunk_out<<<dim3(32, 16), 256, 0, stream>>>(qkv, vT, Spb, obuf);
    gnorm_gate<<<T_SEQ, 256, 0, stream>>>(obuf, gatebuf, gw, gg);

    // 128x128 tiles: (4096/128)*(2048/128) = 32*16 = 512 blocks of 256 thr, 2 blocks/CU
    gemm_dense<<<dim3(512), 256, 0, stream>>>(gg, wd_t, out, HID_C, HID_C);
}

// Round 10
// 419.956 us; speedup vs baseline: 1.0474x; 1.0217x over previous
//
#include <hip/hip_runtime.h>
#include <hip/hip_bf16.h>

using bf16x8 = __attribute__((ext_vector_type(8))) __bf16;
using f32x4  = __attribute__((ext_vector_type(4))) float;

constexpr int T_SEQ = 4096;
constexpr int HID_C = 2048;
constexpr int NH    = 16;
constexpr int QKV_N = 6144;

__device__ __forceinline__ float head_slope(int h) {
    // slope[h] = -2^{-(h+1)/2} * (1 - 1/31 + 1e-5)
    return -exp2f(-0.5f * (float)(h + 1)) * 0.967751935483871f;
}

__device__ __forceinline__ ushort f2bfu(float f) {
    __hip_bfloat16 h = __float2bfloat16(f);
    return *(ushort*)&h;
}
__device__ __forceinline__ float bfu2f(ushort u) {
    union { unsigned int i; float f; } x; x.i = ((unsigned int)u) << 16; return x.f;
}

// async global -> LDS, 16 bytes per lane; LDS dest = wave-uniform base + lane*16
__device__ __forceinline__ void async16(const ushort* g, ushort* l) {
    __builtin_amdgcn_global_load_lds((const __attribute__((address_space(1))) void*)g,
                                     (__attribute__((address_space(3))) void*)l, 16, 0, 0);
}

template<int N> __device__ __forceinline__ void waitcnt_vm() {
    if constexpr (N == 0)      asm volatile("s_waitcnt vmcnt(0)" ::: "memory");
    else if constexpr (N == 2) asm volatile("s_waitcnt vmcnt(2)" ::: "memory");
    else if constexpr (N == 4) asm volatile("s_waitcnt vmcnt(4)" ::: "memory");
    else if constexpr (N == 6) asm volatile("s_waitcnt vmcnt(6)" ::: "memory");
}

// ============ merged preprocessing: cvt_bf16 + 3x transpose_cvt + rope_tab in ONE launch ============
__device__ __forceinline__ void cvt_body(const float* __restrict__ src, ushort* __restrict__ dst,
                                         int bid, int tid) {
    int i = (bid * 256 + tid) * 8;
    float4 a = *(const float4*)(src + i);
    float4 b = *(const float4*)(src + i + 4);
    ushort4 ua = {f2bfu(a.x), f2bfu(a.y), f2bfu(a.z), f2bfu(a.w)};
    ushort4 ub = {f2bfu(b.x), f2bfu(b.y), f2bfu(b.z), f2bfu(b.w)};
    *(ushort4*)(dst + i) = ua;
    *(ushort4*)(dst + i + 4) = ub;
}

__device__ __forceinline__ void transpose_body(const float* __restrict__ src,
                                               ushort* __restrict__ dst,
                                               int R, int C, int bx, int by, int t,
                                               ushort (*tile)[68]) {
    int tr = by * 64, tc = bx * 64;
    int r0 = t >> 4;
    int c4 = (t & 15) << 2;
#pragma unroll
    for (int p = 0; p < 4; ++p) {
        int row = r0 + p * 16;
        float4 v = *(const float4*)&src[(size_t)(tr + row) * C + tc + c4];
        tile[row][c4 + 0] = f2bfu(v.x);
        tile[row][c4 + 1] = f2bfu(v.y);
        tile[row][c4 + 2] = f2bfu(v.z);
        tile[row][c4 + 3] = f2bfu(v.w);
    }
    __syncthreads();
#pragma unroll
    for (int p = 0; p < 4; ++p) {
        int orow = r0 + p * 16;
        ushort4 u;
        u.x = tile[c4 + 0][orow];
        u.y = tile[c4 + 1][orow];
        u.z = tile[c4 + 2][orow];
        u.w = tile[c4 + 3][orow];
        *(ushort4*)&dst[(size_t)(tc + orow) * R + tr + c4] = u;
    }
}

// grid: [0,4096) cvt | [4096,7168) w_qkv T | [7168,8192) w_g T | [8192,9216) w_dense T | [9216,9728) rope
__global__ __launch_bounds__(256) void prep_all(const float* __restrict__ hidden,
                                                ushort* __restrict__ hid_b,
                                                const float* __restrict__ w_qkv,
                                                ushort* __restrict__ wqkv_t,
                                                const float* __restrict__ w_g,
                                                ushort* __restrict__ wg_t,
                                                const float* __restrict__ w_dense,
                                                ushort* __restrict__ wd_t,
                                                const int* __restrict__ positions,
                                                float2* __restrict__ ropet) {
    __shared__ ushort tile[64][68];
    int b = blockIdx.x, t = threadIdx.x;
    if (b < 4096) {
        cvt_body(hidden, hid_b, b, t);
    } else if (b < 7168) {
        int bb = b - 4096;                       // 96 x 32 tiles
        transpose_body(w_qkv, wqkv_t, HID_C, QKV_N, bb % 96, bb / 96, t, tile);
    } else if (b < 8192) {
        int bb = b - 7168;                       // 32 x 32
        transpose_body(w_g, wg_t, HID_C, HID_C, bb % 32, bb / 32, t, tile);
    } else if (b < 9216) {
        int bb = b - 8192;                       // 32 x 32
        transpose_body(w_dense, wd_t, HID_C, HID_C, bb % 32, bb / 32, t, tile);
    } else {
        int i = (b - 9216) * 256 + t;            // i < T*32
        int tt = i >> 5, fi = i & 31;
        float inv = expf((float)fi * -0.2878231366f);   // ln(10000)/32
        float freq = (float)positions[tt] * inv;
        float sn, cs;
        sincosf(freq, &sn, &cs);
        ropet[i] = make_float2(cs, sn);
    }
}

// ============== 256x256 flat-K-tile MFMA GEMM core (BK=64, 8 waves, dbuf LDS) ==============
// R3-proven schedule (best of 6 measured variants): per K-tile {all ds_reads (compiler-counted
// lgkm waits) ; stage t+1 ; MFMA ; vmcnt(0) (cheap: issued ~2500cyc earlier) ; 1 barrier}.
template<int MI, int BN>
__device__ __forceinline__ void gemm8_core(const ushort* __restrict__ Ag,
                                           const ushort* __restrict__ Bg,
                                           int K, int bm, int bn,
                                           ushort* sh, f32x4 (&acc)[MI][4]) {
    constexpr int WM = 16 / MI;          // waves along M: 2 or 4
    constexpr int WN = 8 / WM;           // waves along N: 4 or 2
    constexpr int SB = BN / 128;         // async16 per wave per B-half: 2 or 1
    constexpr int AH = (MI >= 8) ? 2 : 1;// A-read halves (VGPR pressure relief)
    constexpr int MH = MI / AH;

    const int tid  = threadIdx.x;
    const int lane = tid & 63;
    const int wave = tid >> 6;
    const int lane15 = lane & 15, quad = lane >> 4;
    const int wm = wave / WN, wn = wave % WN;
    const int swz = lane15 & 7;

    ushort* const ldsA0 = sh;              // [256][64] bf16, rows swizzled: phys grp p of row r = logical p^(r&7)
    ushort* const ldsA1 = sh + 16384;
    ushort* const ldsB0 = sh + 32768;      // [BN][64]
    ushort* const ldsB1 = sh + 32768 + BN * 64;

    // staging: lane l covers row (l>>3) of an 8-row chunk, physical 16B group (l&7),
    // so it must READ logical group (l&7)^(l>>3)  (involution: same xor on the read side)
    const int srow = lane >> 3;
    const int scol = ((lane & 7) ^ srow) << 3;
    const ushort* gA = Ag + (size_t)(bm + srow) * K + scol;
    const ushort* gB = Bg + (size_t)(bn + srow) * K + scol;
    const int ro  = wave * 16;             // A: each wave stages 2x 8-row chunks per half-tile
    const int roB = wave * 8 * SB;         // B: SB 8-row chunks per half-tile
    const int NT = K >> 6;

#define STAGE_A(L, k0) do { \
    _Pragma("unroll") for (int h = 0; h < 2; ++h) \
    _Pragma("unroll") for (int q = 0; q < 2; ++q) \
        async16(gA + (size_t)((h) * 128 + ro + q * 8) * K + (k0), (L) + ((h) * 128 + ro + q * 8) * 64); } while (0)
#define STAGE_B(L, k0) do { \
    _Pragma("unroll") for (int h = 0; h < 2; ++h) \
    _Pragma("unroll") for (int q = 0; q < SB; ++q) \
        async16(gB + (size_t)((h) * (BN / 2) + roB + q * 8) * K + (k0), (L) + ((h) * (BN / 2) + roB + q * 8) * 64); } while (0)

    // prologue: tile0 -> buf0
    STAGE_A(ldsA0, 0);
    STAGE_B(ldsB0, 0);
    waitcnt_vm<0>();
    asm volatile("s_barrier" ::: "memory");

    for (int t = 0; t < NT; ++t) {
        const ushort* LA = (t & 1) ? ldsA1 : ldsA0;
        const ushort* LB = (t & 1) ? ldsB1 : ldsB0;
        ushort* LAn = (t & 1) ? ldsA0 : ldsA1;
        ushort* LBn = (t & 1) ? ldsB0 : ldsB1;
        // ---- all B-frags + first A-half (compiler inserts counted lgkm waits) ----
        bf16x8 bfr[4][2];
#pragma unroll
        for (int j = 0; j < 4; ++j)
#pragma unroll
            for (int ks = 0; ks < 2; ++ks)
                bfr[j][ks] = *(const bf16x8*)&LB[(wn * 64 + j * 16 + lane15) * 64 + (((ks * 4 + quad) ^ swz) << 3)];
        bf16x8 af0[MH][2];
#pragma unroll
        for (int i = 0; i < MH; ++i)
#pragma unroll
            for (int ks = 0; ks < 2; ++ks)
                af0[i][ks] = *(const bf16x8*)&LA[(wm * (MI * 16) + i * 16 + lane15) * 64 + (((ks * 4 + quad) ^ swz) << 3)];
        // ---- stage tile t+1 into the other buffers (WAR-safe: last read before this tile's barrier) ----
        if (t + 1 < NT) {
            STAGE_A(LAn, (t + 1) << 6);
            STAGE_B(LBn, (t + 1) << 6);
        }
        __builtin_amdgcn_s_setprio(1);
#pragma unroll
        for (int i = 0; i < MH; ++i)
#pragma unroll
            for (int j = 0; j < 4; ++j)
#pragma unroll
                for (int ks = 0; ks < 2; ++ks)
                    acc[i][j] = __builtin_amdgcn_mfma_f32_16x16x32_bf16(af0[i][ks], bfr[j][ks], acc[i][j], 0, 0, 0);
        __builtin_amdgcn_s_setprio(0);
        if constexpr (AH == 2) {
            // ---- second A-half: reads overlap first MFMA cluster ----
            bf16x8 af1[MH][2];
#pragma unroll
            for (int i = 0; i < MH; ++i)
#pragma unroll
                for (int ks = 0; ks < 2; ++ks)
                    af1[i][ks] = *(const bf16x8*)&LA[(wm * (MI * 16) + (MH + i) * 16 + lane15) * 64 + (((ks * 4 + quad) ^ swz) << 3)];
            __builtin_amdgcn_s_setprio(1);
#pragma unroll
            for (int i = 0; i < MH; ++i)
#pragma unroll
                for (int j = 0; j < 4; ++j)
#pragma unroll
                    for (int ks = 0; ks < 2; ++ks)
                        acc[MH + i][j] = __builtin_amdgcn_mfma_f32_16x16x32_bf16(af1[i][ks], bfr[j][ks], acc[MH + i][j], 0, 0, 0);
            __builtin_amdgcn_s_setprio(0);
        }
        // t+1 staging landed long ago (issued ~2500cyc back); drain + handoff
        waitcnt_vm<0>();
        asm volatile("s_barrier" ::: "memory");
    }
#undef STAGE_A
#undef STAGE_B
}

// ============== 128x128 flat-K-tile core: 4 waves, 64 KiB LDS (for the dense GEMM) ==============
__device__ __forceinline__ void gemm4_core(const ushort* __restrict__ Ag,
                                           const ushort* __restrict__ Bg,
                                           int K, int bm, int bn,
                                           ushort* sh, f32x4 (&acc)[4][4]) {
    const int tid  = threadIdx.x;
    const int lane = tid & 63;
    const int wave = tid >> 6;             // 4 waves: 2M x 2N
    const int lane15 = lane & 15, quad = lane >> 4;
    const int wm = wave >> 1, wn = wave & 1;
    const int swz = lane15 & 7;

    ushort* const ldsA0 = sh;              // [128][64]
    ushort* const ldsA1 = sh + 8192;
    ushort* const ldsB0 = sh + 16384;
    ushort* const ldsB1 = sh + 24576;

    const int srow = lane >> 3;
    const int scol = ((lane & 7) ^ srow) << 3;
    const ushort* gA = Ag + (size_t)(bm + srow) * K + scol;
    const ushort* gB = Bg + (size_t)(bn + srow) * K + scol;
    const int ro = wave * 32;              // each wave stages 4x 8-row chunks (128 rows / 4 waves)
    const int NT = K >> 6;

#define STG(L, g, k0) do { \
    _Pragma("unroll") for (int q = 0; q < 4; ++q) \
        async16((g) + (size_t)(ro + q * 8) * K + (k0), (L) + (ro + q * 8) * 64); } while (0)

    STG(ldsA0, gA, 0);
    STG(ldsB0, gB, 0);
    waitcnt_vm<0>();
    asm volatile("s_barrier" ::: "memory");

    for (int t = 0; t < NT; ++t) {
        const ushort* LA = (t & 1) ? ldsA1 : ldsA0;
        const ushort* LB = (t & 1) ? ldsB1 : ldsB0;
        ushort* LAn = (t & 1) ? ldsA0 : ldsA1;
        ushort* LBn = (t & 1) ? ldsB0 : ldsB1;
        bf16x8 bfr[4][2];
#pragma unroll
        for (int j = 0; j < 4; ++j)
#pragma unroll
            for (int ks = 0; ks < 2; ++ks)
                bfr[j][ks] = *(const bf16x8*)&LB[(wn * 64 + j * 16 + lane15) * 64 + (((ks * 4 + quad) ^ swz) << 3)];
        bf16x8 af[4][2];
#pragma unroll
        for (int i = 0; i < 4; ++i)
#pragma unroll
            for (int ks = 0; ks < 2; ++ks)
                af[i][ks] = *(const bf16x8*)&LA[(wm * 64 + i * 16 + lane15) * 64 + (((ks * 4 + quad) ^ swz) << 3)];
        if (t + 1 < NT) {
            STG(LAn, gA, (t + 1) << 6);
            STG(LBn, gB, (t + 1) << 6);
        }
        __builtin_amdgcn_s_setprio(1);
#pragma unroll
        for (int i = 0; i < 4; ++i)
#pragma unroll
            for (int j = 0; j < 4; ++j)
#pragma unroll
                for (int ks = 0; ks < 2; ++ks)
                    acc[i][j] = __builtin_amdgcn_mfma_f32_16x16x32_bf16(af[i][ks], bfr[j][ks], acc[i][j], 0, 0, 0);
        __builtin_amdgcn_s_setprio(0);
        waitcnt_vm<0>();
        asm volatile("s_barrier" ::: "memory");
    }
#undef STG
}

// ---- fused qkv+gate GEMM: Bcat = [wqkv_t ; wg_t] (8192 x K). cols<6144 -> qkv, else sigmoid -> gate ----
// V tiles (4096 <= bn < 6144) skip the row-major write and transpose directly into chunk-tiled vT.
__global__ __launch_bounds__(512, 2) void gemm_fused(const ushort* __restrict__ A,
                                                     const ushort* __restrict__ Bcat,
                                                     ushort* __restrict__ qkv,
                                                     ushort* __restrict__ gate,
                                                     ushort* __restrict__ vT, int K) {
    __shared__ ushort sh[65536];           // 128 KiB: A dbuf 64K + B dbuf 64K (reused by V-transpose)
    // 2D-chunked XCD swizzle: GM=16 x GN=32 tiles; each XCD owns an 8m x 8n region
    // (n-fastest inside) -> concurrent per-XCD working set = 4 A-tiles + 8 B-tiles.
    int bid = blockIdx.x;
    int x = bid & 7, w = bid >> 3;         // XCD id, within-XCD order
    int rm = x >> 2, rn = x & 3;           // region coords: 2 x 4 regions
    int wm_i = w >> 3, wn_i = w & 7;       // 8 x 8 blocks inside region
    int bm = (rm * 8 + wm_i) * 256;
    int bn = (rn * 8 + wn_i) * 256;
    f32x4 acc[8][4] = {};
    gemm8_core<8, 256>(A, Bcat, K, bm, bn, sh, acc);

    int lane = threadIdx.x & 63, wave = threadIdx.x >> 6;
    int lane15 = lane & 15, quad = lane >> 4;
    int wm = wave >> 2, wn = wave & 3;

    if (bn >= 4096 && bn < QKV_N) {
        // ---- V tile: transpose 256x256 into vT chunk-tiled slabs [h][c][128 d][128 t] ----
        constexpr int S = 132;             // padded t-stride: 8B-aligned rows, 2-way-free reads
        ushort* L = sh;                    // 2 quadrants [hq][128 d][S t] = 67.6 KiB (loop done)
        int h0 = (bn - 4096) >> 7;         // even head index of col 0
        int c0 = bm >> 7;                  // chunk index of row 0 (even)
        int hq = wn >> 1;                  // this wave's head within the tile
        int dl = (wn & 1) * 64;            // this wave's d-offset within the head
#pragma unroll
        for (int cq = 0; cq < 2; ++cq) {
            if (wm == cq) {                // waves holding rows cq*128..+127 write their quadrant
#pragma unroll
                for (int i = 0; i < 8; ++i)
#pragma unroll
                    for (int j = 0; j < 4; ++j) {
                        int d_local = dl + j * 16 + lane15;
#pragma unroll
                        for (int r = 0; r < 4; ++r) {
                            int t_local = i * 16 + quad * 4 + r;
                            L[hq * 128 * S + d_local * S + t_local] = f2bfu(acc[i][j][r]);
                        }
                    }
            }
            __syncthreads();
            // all 512 threads stream both quadrants out (coalesced ushort4)
#pragma unroll
            for (int p = 0; p < 16; ++p) {
                int lin = (p * 512 + threadIdx.x) * 4;   // ushort index in 2-slab space
                int hq2 = lin >> 14;
                int wi = lin & 16383;
                int d = wi >> 7, t4 = wi & 127;
                const ushort* lp = &L[hq2 * 128 * S + d * S + t4];
                ushort4 u = { lp[0], lp[1], lp[2], lp[3] };
                *(ushort4*)&vT[((size_t)((h0 + hq2) * 32 + c0 + cq) * 128 + d) * 128 + t4] = u;
            }
            __syncthreads();
        }
        return;
    }

    bool isg = bn >= QKV_N;
    ushort* outp = isg ? gate : qkv;
    int ncol = isg ? HID_C : QKV_N;
    int cb = (isg ? bn - QKV_N : bn) + wn * 64;
    int rb = bm + wm * 128;
#pragma unroll
    for (int i = 0; i < 8; ++i)
#pragma unroll
        for (int j = 0; j < 4; ++j) {
            int col = cb + j * 16 + lane15;
#pragma unroll
            for (int r = 0; r < 4; ++r) {
                float v = acc[i][j][r];
                if (isg) v = 1.0f / (1.0f + __expf(-v));
                outp[(size_t)(rb + i * 16 + quad * 4 + r) * ncol + col] = f2bfu(v);
            }
        }
}

// ---- dense GEMM: fp32 out. BM=128 x BN=128, 256 thr, 64 KiB LDS (512 blocks, 2 blocks/CU) ----
__global__ __launch_bounds__(256, 2) void gemm_dense(const ushort* __restrict__ A,
                                                     const ushort* __restrict__ Bt,
                                                     float* __restrict__ Cout, int N, int K) {
    __shared__ ushort sh[32768];           // 64 KiB
    // GM=32 x GN=16 tiles; each XCD owns an 8m x 8n region (n-fastest inside)
    int bid = blockIdx.x;
    int x = bid & 7, w = bid >> 3;
    int rm = x >> 1, rn = x & 1;           // 4 x 2 regions
    int wm_i = w >> 3, wn_i = w & 7;       // 8 x 8 blocks inside region
    int bm = (rm * 8 + wm_i) * 128;
    int bn = (rn * 8 + wn_i) * 128;
    f32x4 acc[4][4] = {};
    gemm4_core(A, Bt, K, bm, bn, sh, acc);

    int lane = threadIdx.x & 63, wave = threadIdx.x >> 6;
    int lane15 = lane & 15, quad = lane >> 4;
    int wm = wave >> 1, wn = wave & 1;
    int cb = bn + wn * 64;
    int rb = bm + wm * 64;
#pragma unroll
    for (int i = 0; i < 4; ++i)
#pragma unroll
        for (int j = 0; j < 4; ++j) {
            int col = cb + j * 16 + lane15;
#pragma unroll
            for (int r = 0; r < 4; ++r)
                Cout[(size_t)(rb + i * 16 + quad * 4 + r) * N + col] = acc[i][j][r];
        }
}

// ---- fused q/k RMSNorm + RoPE (+q scale); k additionally transposed to chunk-tiled kT ----
// grid y in [0,32): kind = y>>4 (0=q, 1=k), h = y&15.  (v handled in gemm_fused epilogue)
__global__ __launch_bounds__(256) void qk_rope_T(ushort* __restrict__ qkv,
                                                 const float2* __restrict__ tab,
                                                 const float* __restrict__ qw,
                                                 const float* __restrict__ kw,
                                                 ushort* __restrict__ kT) {
    __shared__ ushort tile[64][132];
    int bt = blockIdx.x;
    int kind = blockIdx.y >> 4, h = blockIdx.y & 15;
    int tid = threadIdx.x;
    int row = tid >> 2, c = tid & 3, d0 = c * 32;
    int t = bt * 64 + row;
    ushort* base = qkv + (size_t)t * QKV_N + kind * 2048 + h * 128 + d0;
    bf16x8 pk[4];
#pragma unroll
    for (int p = 0; p < 4; ++p) pk[p] = *(const bf16x8*)(base + p * 8);
    {
        float x[32];
        float ss = 0.f;
#pragma unroll
        for (int p = 0; p < 4; ++p)
#pragma unroll
            for (int i = 0; i < 8; ++i) {
                x[p * 8 + i] = (float)pk[p][i];
                ss += x[p * 8 + i] * x[p * 8 + i];
            }
        ss += __shfl_xor(ss, 1);
        ss += __shfl_xor(ss, 2);
        float rr = rsqrtf(ss * (1.0f / 128.0f) + 1e-6f);
        const float* w = (kind == 0) ? qw : kw;
#pragma unroll
        for (int i = 0; i < 32; ++i) x[i] *= rr * w[d0 + i];
        // rope on d<64: c=0 holds x1 (d 0..31), c=1 holds x2 (d 32..63); partner via xor 1
#pragma unroll
        for (int i = 0; i < 32; ++i) {
            float p = __shfl_xor(x[i], 1);
            if (c < 2) {
                float2 rt = tab[t * 32 + i];
                x[i] = (c == 0) ? (x[i] * rt.x - p * rt.y) : (x[i] * rt.x + p * rt.y);
            }
        }
        float sc = (kind == 0) ? 0.08838834764831845f : 1.0f;   // 128^-0.5 on q
#pragma unroll
        for (int p = 0; p < 4; ++p)
#pragma unroll
            for (int i = 0; i < 8; ++i) pk[p][i] = (__bf16)(x[p * 8 + i] * sc);
#pragma unroll
        for (int p = 0; p < 4; ++p) *(bf16x8*)(base + p * 8) = pk[p];
    }
    if (kind == 1) {
        // transpose 64t x 128d -> chunk-tiled kT[h][bt>>1][d][(bt&1)*64 + t]
#pragma unroll
        for (int p = 0; p < 4; ++p) {
            ushort4* s = (ushort4*)&pk[p];
            *(ushort4*)&tile[row][d0 + p * 8]     = s[0];
            *(ushort4*)&tile[row][d0 + p * 8 + 4] = s[1];
        }
        __syncthreads();
        ushort* outT = kT + ((size_t)(h * 32 + (bt >> 1)) * 128) * 128 + (bt & 1) * 64;
        int d = tid >> 1, half = tid & 1;
#pragma unroll
        for (int tt = 0; tt < 8; ++tt) {
            int tl = half * 32 + tt * 4;
            ushort4 u;
            u.x = tile[tl + 0][d];
            u.y = tile[tl + 1][d];
            u.z = tile[tl + 2][d];
            u.w = tile[tl + 3][d];
            *(ushort4*)&outT[(size_t)d * 128 + tl] = u;
        }
    }
}

// ------- per-chunk partial state (transposed, bf16): PT[c,h][v][d] = sum_j lam^(127-j) v_j[v] k_j[d] -------
__global__ __launch_bounds__(256) void chunk_partial(const ushort* __restrict__ kT,
                                                     const ushort* __restrict__ vT,
                                                     ushort* __restrict__ PT) {
    int c = blockIdx.x, h = blockIdx.y;
    float slope = head_slope(h);
    float lam_inv = __expf(-slope);
    int tid = threadIdx.x, lane = tid & 63, wave = tid >> 6;
    int lane15 = lane & 15, quad = lane >> 4;
    int wv = (wave & 1) * 64, wd = (wave >> 1) * 64;
    // chunk-tiled layout: slab (h,c) is contiguous [128 d][128 t]
    const ushort* vbase = vT + ((size_t)(h * 32 + c) * 128) * 128;
    const ushort* kbase = kT + ((size_t)(h * 32 + c) * 128) * 128;
    f32x4 acc[4][4] = {};
#pragma unroll
    for (int j0 = 0; j0 < 128; j0 += 32) {
        float w8[8];
        w8[0] = __expf(slope * (float)(127 - (j0 + quad * 8)));
#pragma unroll
        for (int kk = 1; kk < 8; ++kk) w8[kk] = w8[kk - 1] * lam_inv;
        bf16x8 afr[4], bfr[4];
#pragma unroll
        for (int i = 0; i < 4; ++i) {
            bf16x8 v = *(const bf16x8*)&vbase[(size_t)(wv + i * 16 + lane15) * 128 + j0 + quad * 8];
#pragma unroll
            for (int kk = 0; kk < 8; ++kk) afr[i][kk] = (__bf16)((float)v[kk] * w8[kk]);
        }
#pragma unroll
        for (int j = 0; j < 4; ++j)
            bfr[j] = *(const bf16x8*)&kbase[(size_t)(wd + j * 16 + lane15) * 128 + j0 + quad * 8];
#pragma unroll
        for (int i = 0; i < 4; ++i)
#pragma unroll
            for (int j = 0; j < 4; ++j)
                acc[i][j] = __builtin_amdgcn_mfma_f32_16x16x32_bf16(afr[i], bfr[j], acc[i][j], 0, 0, 0);
    }
    ushort* out = PT + ((size_t)c * 16 + h) * 16384;
#pragma unroll
    for (int i = 0; i < 4; ++i)
#pragma unroll
        for (int j = 0; j < 4; ++j)
#pragma unroll
            for (int r = 0; r < 4; ++r)
                out[(size_t)(wv + i * 16 + quad * 4 + r) * 128 + wd + j * 16 + lane15] = f2bfu(acc[i][j][r]);
}

// ------- sequential scan over 32 chunks: PT (bf16) -> Spb (bf16 prefix states) + Sfin -------
__global__ __launch_bounds__(128) void scan_states(const ushort* __restrict__ PT,
                                                   const float* __restrict__ S0,
                                                   ushort* __restrict__ Spb,
                                                   float* __restrict__ Sfin) {
    int hv = blockIdx.x;              // h*128 + v
    int d = threadIdx.x;              // k-dim
    int h = hv >> 7, v = hv & 127;
    float lamC = __expf(head_slope(h) * 128.0f);
    float s = S0[(size_t)h * 16384 + d * 128 + v];
#pragma unroll
    for (int c = 0; c < 32; ++c) {
        size_t idx = ((size_t)c * 2048 + hv) * 128 + d;
        Spb[idx] = f2bfu(s);          // state BEFORE chunk c, layout [c][h][v][d]
        s = s * lamC + bfu2f(PT[idx]);
    }
    Sfin[(size_t)h * 16384 + d * 128 + v] = s;
}

// ------- per-chunk output: QK^T (masked/decayed) * V + lam^(t+1) * Q * S_prev -------
__global__ __launch_bounds__(256) void chunk_out(const ushort* __restrict__ qkv,
                                                 const ushort* __restrict__ vT,
                                                 const ushort* __restrict__ Spb,
                                                 ushort* __restrict__ o) {
    int c = blockIdx.x, h = blockIdx.y;
    float slope = head_slope(h);
    __shared__ ushort Ps[128 * 136];   // padded: row stride 272B -> conflict-free b128
    int tid = threadIdx.x, lane = tid & 63, wave = tid >> 6;
    int lane15 = lane & 15, quad = lane >> 4;
    int t0 = c * 128;
    int tt0 = wave, tt1 = 7 - wave;    // owned t-tiles (balanced triangular split)
    const ushort* qbase = qkv + (size_t)t0 * QKV_N + h * 128;
    const ushort* kbase = qbase + 2048;

    bf16x8 qf0[4], qf1[4];
#pragma unroll
    for (int ds = 0; ds < 4; ++ds) {
        qf0[ds] = *(const bf16x8*)&qbase[(size_t)(tt0 * 16 + lane15) * QKV_N + ds * 32 + quad * 8];
        qf1[ds] = *(const bf16x8*)&qbase[(size_t)(tt1 * 16 + lane15) * QKV_N + ds * 32 + quad * 8];
    }
    // ---- phase 1: scores ----
    f32x4 s0a[4] = {};
    f32x4 s1a[8] = {};
#pragma unroll
    for (int st = 0; st < 8; ++st) {
        if (st <= tt1) {
            bf16x8 kf[4];
#pragma unroll
            for (int ds = 0; ds < 4; ++ds)
                kf[ds] = *(const bf16x8*)&kbase[(size_t)(st * 16 + lane15) * QKV_N + ds * 32 + quad * 8];
#pragma unroll
            for (int ds = 0; ds < 4; ++ds)
                s1a[st] = __builtin_amdgcn_mfma_f32_16x16x32_bf16(qf1[ds], kf[ds], s1a[st], 0, 0, 0);
            if (st <= tt0) {
#pragma unroll
                for (int ds = 0; ds < 4; ++ds)
                    s0a[st] = __builtin_amdgcn_mfma_f32_16x16x32_bf16(qf0[ds], kf[ds], s0a[st], 0, 0, 0);
            }
        }
    }
    // ---- park masked/decayed scores (zero strip pads odd 16-blocks to 32) ----
    int stmax0 = tt0 + ((tt0 & 1) ? 0 : 1);
    int stmax1 = tt1 + ((tt1 & 1) ? 0 : 1);
#pragma unroll
    for (int st = 0; st < 8; ++st) {
        if (st <= stmax1) {
#pragma unroll
            for (int r = 0; r < 4; ++r) {
                int t = tt1 * 16 + quad * 4 + r;
                int s = st * 16 + lane15;
                float val = 0.f;
                if (st <= tt1) val = (s <= t) ? s1a[st][r] * __expf(slope * (float)(t - s)) : 0.f;
                Ps[t * 136 + s] = f2bfu(val);
            }
        }
    }
#pragma unroll
    for (int st = 0; st < 5; ++st) {
        if (st <= stmax0) {
#pragma unroll
            for (int r = 0; r < 4; ++r) {
                int t = tt0 * 16 + quad * 4 + r;
                int s = st * 16 + lane15;
                float val = 0.f;
                if (st <= tt0) val = (s <= t) ? s0a[st][r] * __expf(slope * (float)(t - s)) : 0.f;
                Ps[t * 136 + s] = f2bfu(val);
            }
        }
    }
    __syncthreads();
    // ---- phase 2: O = P*V + diag(lam^(t+1)) Q*S_prev ----
    f32x4 oa0[8] = {};
    f32x4 oa1[8] = {};
    float lam0 = __expf(slope * (float)(tt0 * 16 + lane15 + 1));
    float lam1 = __expf(slope * (float)(tt1 * 16 + lane15 + 1));
    bf16x8 qs0[4], qs1[4];
#pragma unroll
    for (int ds = 0; ds < 4; ++ds)
#pragma unroll
        for (int kk = 0; kk < 8; ++kk) {
            qs0[ds][kk] = (__bf16)((float)qf0[ds][kk] * lam0);
            qs1[ds][kk] = (__bf16)((float)qf1[ds][kk] * lam1);
        }
    const ushort* spb = Spb + ((size_t)c * 2048 + h * 128) * 128;
#pragma unroll
    for (int vt = 0; vt < 8; ++vt)
#pragma unroll
        for (int ds = 0; ds < 4; ++ds) {
            bf16x8 bfrag = *(const bf16x8*)&spb[(vt * 16 + lane15) * 128 + ds * 32 + quad * 8];
            oa0[vt] = __builtin_amdgcn_mfma_f32_16x16x32_bf16(qs0[ds], bfrag, oa0[vt], 0, 0, 0);
            oa1[vt] = __builtin_amdgcn_mfma_f32_16x16x32_bf16(qs1[ds], bfrag, oa1[vt], 0, 0, 0);
        }
    // chunk-tiled layout: slab (h,c) contiguous [128 d][128 t]
    const ushort* vbase = vT + ((size_t)(h * 32 + c) * 128) * 128;
    int ns0 = (tt0 + 2) >> 1, ns1 = (tt1 + 2) >> 1;
#pragma unroll
    for (int s32 = 0; s32 < 4; ++s32) {
        if (s32 < ns1) {
            bf16x8 af = *(const bf16x8*)&Ps[(tt1 * 16 + lane15) * 136 + s32 * 32 + quad * 8];
#pragma unroll
            for (int vt = 0; vt < 8; ++vt) {
                bf16x8 bfrag = *(const bf16x8*)&vbase[(size_t)(vt * 16 + lane15) * 128 + s32 * 32 + quad * 8];
                oa1[vt] = __builtin_amdgcn_mfma_f32_16x16x32_bf16(af, bfrag, oa1[vt], 0, 0, 0);
            }
        }
    }
#pragma unroll
    for (int s32 = 0; s32 < 2; ++s32) {
        if (s32 < ns0) {
            bf16x8 af = *(const bf16x8*)&Ps[(tt0 * 16 + lane15) * 136 + s32 * 32 + quad * 8];
#pragma unroll
            for (int vt = 0; vt < 8; ++vt) {
                bf16x8 bfrag = *(const bf16x8*)&vbase[(size_t)(vt * 16 + lane15) * 128 + s32 * 32 + quad * 8];
                oa0[vt] = __builtin_amdgcn_mfma_f32_16x16x32_bf16(af, bfrag, oa0[vt], 0, 0, 0);
            }
        }
    }
    // ---- epilogue (bf16) ----
#pragma unroll
    for (int vt = 0; vt < 8; ++vt)
#pragma unroll
        for (int r = 0; r < 4; ++r) {
            o[(size_t)(t0 + tt0 * 16 + quad * 4 + r) * 2048 + h * 128 + vt * 16 + lane15] = f2bfu(oa0[vt][r]);
            o[(size_t)(t0 + tt1 * 16 + quad * 4 + r) * 2048 + h * 128 + vt * 16 + lane15] = f2bfu(oa1[vt][r]);
        }
}

// ---------------- group RMS-norm * g_norm_w * sigmoid-gate -> bf16 ----------------
__global__ __launch_bounds__(256) void gnorm_gate(const ushort* __restrict__ o,
                                                  const ushort* __restrict__ gate,
                                                  const float* __restrict__ gw,
                                                  ushort* __restrict__ gg) {
    int t = blockIdx.x;
    int tid = threadIdx.x;
    const ushort* op = o + (size_t)t * 2048 + tid * 8;
    bf16x8 xv = *(const bf16x8*)op;
    float x[8];
    float ss = 0.0f;
#pragma unroll
    for (int i = 0; i < 8; ++i) { x[i] = (float)xv[i]; ss += x[i] * x[i]; }
#pragma unroll
    for (int off = 16; off > 0; off >>= 1) ss += __shfl_xor(ss, off);  // 32-thread group = 256 elems
    float r = rsqrtf(ss * (1.0f / 256.0f) + 1e-6f);
    const ushort* gp = gate + (size_t)t * 2048;
#pragma unroll
    for (int i = 0; i < 8; ++i) {
        int j = tid * 8 + i;
        float val = x[i] * r * gw[j] * bfu2f(gp[j]);
        gg[(size_t)t * 2048 + j] = f2bfu(val);
    }
}

extern "C" void kernel_launch(void* const* d_in, const int* in_sizes, int n_in,
                              void* d_out, int out_size, void* d_ws, size_t ws_size,
                              hipStream_t stream) {
    const int* positions   = (const int*)d_in[0];
    const float* hidden    = (const float*)d_in[1];
    const float* S0        = (const float*)d_in[2];
    const float* w_qkv     = (const float*)d_in[3];
    const float* w_g       = (const float*)d_in[4];
    const float* w_dense   = (const float*)d_in[5];
    const float* qw        = (const float*)d_in[6];
    const float* kw        = (const float*)d_in[7];
    const float* gw        = (const float*)d_in[8];

    char* ws = (char*)d_ws;
    ushort* qkv     = (ushort*)ws;                    // bf16 T x 6144            [0, 50331648)
    ushort* wqkv_t  = (ushort*)(ws + 50331648);       // bf16 6144 x 2048 (25.2M) — Bcat rows 0..6143
    ushort* wg_t    = (ushort*)(ws + 75497472);       // bf16 2048 x 2048 (8.4M)  — Bcat rows 6144..8191
    float2* ropet   = (float2*)(ws + 159383552);      // 1 MB — separate region (prep writes all at once)
    ushort* PT      = (ushort*)(ws + 50331648);       // bf16 32x16x128x128 (16.8M) — aliases wqkv_t (dead)
    ushort* wd_t    = (ushort*)(ws + 83886080);       // bf16 2048 x 2048 (8.4M)
    ushort* gatebuf = (ushort*)(ws + 92274688);       // bf16 T x 2048 (16.8M)
    ushort* hid_b   = (ushort*)(ws + 109051904);      // bf16 T x 2048 (16.8M)
    ushort* Spb     = (ushort*)(ws + 109051904);      // bf16 32x16x128x128 (16.8M) — aliases hid_b (dead)
    ushort* kT      = (ushort*)(ws + 125829120);      // bf16 [16][32][128][128] (16.8M) chunk-tiled
    ushort* vT      = (ushort*)(ws + 142606336);      // bf16 [16][32][128][128] (16.8M) chunk-tiled
    ushort* gg      = (ushort*)ws;                    // aliases qkv (dead by gnorm time)  total 160,432,128

    float* out  = (float*)d_out;
    float* Sfin = out + (size_t)T_SEQ * HID_C;
    ushort* obuf = (ushort*)d_out;                    // out-region doubles as bf16 attn scratch

    // one launch: cvt + 3 transposes + rope table (all independent preprocessing)
    prep_all<<<9728, 256, 0, stream>>>(hidden, hid_b, w_qkv, wqkv_t, w_g, wg_t,
                                       w_dense, wd_t, positions, ropet);

    // 256x256 tiles: (8192/256)*(4096/256) = 32*16 = 512 blocks of 512 threads
    // (v-tiles write transposed vT directly in-epilogue)
    gemm_fused<<<dim3(512), 512, 0, stream>>>(hid_b, wqkv_t, qkv, gatebuf, vT, HID_C);

    // q,k only (v handled above): grid y = 32
    qk_rope_T<<<dim3(T_SEQ / 64, 32), 256, 0, stream>>>(qkv, ropet, qw, kw, kT);

    chunk_partial<<<dim3(32, 16), 256, 0, stream>>>(kT, vT, PT);
    scan_states<<<2048, 128, 0, stream>>>(PT, S0, Spb, Sfin);
    chunk_out<<<dim3(32, 16), 256, 0, stream>>>(qkv, vT, Spb, obuf);
    gnorm_gate<<<T_SEQ, 256, 0, stream>>>(obuf, gatebuf, gw, gg);

    // 128x128 tiles: (4096/128)*(2048/128) = 32*16 = 512 blocks of 256 thr, 2 blocks/CU
    gemm_dense<<<dim3(512), 256, 0, stream>>>(gg, wd_t, out, HID_C, HID_C);
}

// Round 11
// 409.568 us; speedup vs baseline: 1.0740x; 1.0254x over previous
//
#include <hip/hip_runtime.h>
#include <hip/hip_bf16.h>

using bf16x8 = __attribute__((ext_vector_type(8))) __bf16;
using f32x4  = __attribute__((ext_vector_type(4))) float;

constexpr int T_SEQ = 4096;
constexpr int HID_C = 2048;
constexpr int NH    = 16;
constexpr int QKV_N = 6144;

__device__ __forceinline__ float head_slope(int h) {
    // slope[h] = -2^{-(h+1)/2} * (1 - 1/31 + 1e-5)
    return -exp2f(-0.5f * (float)(h + 1)) * 0.967751935483871f;
}

__device__ __forceinline__ ushort f2bfu(float f) {
    __hip_bfloat16 h = __float2bfloat16(f);
    return *(ushort*)&h;
}
__device__ __forceinline__ float bfu2f(ushort u) {
    union { unsigned int i; float f; } x; x.i = ((unsigned int)u) << 16; return x.f;
}

// async global -> LDS, 16 bytes per lane; LDS dest = wave-uniform base + lane*16
__device__ __forceinline__ void async16(const ushort* g, ushort* l) {
    __builtin_amdgcn_global_load_lds((const __attribute__((address_space(1))) void*)g,
                                     (__attribute__((address_space(3))) void*)l, 16, 0, 0);
}

template<int N> __device__ __forceinline__ void waitcnt_vm() {
    if constexpr (N == 0)      asm volatile("s_waitcnt vmcnt(0)" ::: "memory");
    else if constexpr (N == 2) asm volatile("s_waitcnt vmcnt(2)" ::: "memory");
    else if constexpr (N == 4) asm volatile("s_waitcnt vmcnt(4)" ::: "memory");
    else if constexpr (N == 6) asm volatile("s_waitcnt vmcnt(6)" ::: "memory");
}

// ============ merged preprocessing: cvt_bf16 + 3x transpose_cvt + rope_tab in ONE launch ============
__device__ __forceinline__ void cvt_body(const float* __restrict__ src, ushort* __restrict__ dst,
                                         int bid, int tid) {
    int i = (bid * 256 + tid) * 8;
    float4 a = *(const float4*)(src + i);
    float4 b = *(const float4*)(src + i + 4);
    ushort4 ua = {f2bfu(a.x), f2bfu(a.y), f2bfu(a.z), f2bfu(a.w)};
    ushort4 ub = {f2bfu(b.x), f2bfu(b.y), f2bfu(b.z), f2bfu(b.w)};
    *(ushort4*)(dst + i) = ua;
    *(ushort4*)(dst + i + 4) = ub;
}

__device__ __forceinline__ void transpose_body(const float* __restrict__ src,
                                               ushort* __restrict__ dst,
                                               int R, int C, int bx, int by, int t,
                                               ushort (*tile)[68]) {
    int tr = by * 64, tc = bx * 64;
    int r0 = t >> 4;
    int c4 = (t & 15) << 2;
#pragma unroll
    for (int p = 0; p < 4; ++p) {
        int row = r0 + p * 16;
        float4 v = *(const float4*)&src[(size_t)(tr + row) * C + tc + c4];
        tile[row][c4 + 0] = f2bfu(v.x);
        tile[row][c4 + 1] = f2bfu(v.y);
        tile[row][c4 + 2] = f2bfu(v.z);
        tile[row][c4 + 3] = f2bfu(v.w);
    }
    __syncthreads();
#pragma unroll
    for (int p = 0; p < 4; ++p) {
        int orow = r0 + p * 16;
        ushort4 u;
        u.x = tile[c4 + 0][orow];
        u.y = tile[c4 + 1][orow];
        u.z = tile[c4 + 2][orow];
        u.w = tile[c4 + 3][orow];
        *(ushort4*)&dst[(size_t)(tc + orow) * R + tr + c4] = u;
    }
}

// grid: [0,4096) cvt | [4096,7168) w_qkv T | [7168,8192) w_g T | [8192,9216) w_dense T | [9216,9728) rope
__global__ __launch_bounds__(256) void prep_all(const float* __restrict__ hidden,
                                                ushort* __restrict__ hid_b,
                                                const float* __restrict__ w_qkv,
                                                ushort* __restrict__ wqkv_t,
                                                const float* __restrict__ w_g,
                                                ushort* __restrict__ wg_t,
                                                const float* __restrict__ w_dense,
                                                ushort* __restrict__ wd_t,
                                                const int* __restrict__ positions,
                                                float2* __restrict__ ropet) {
    __shared__ ushort tile[64][68];
    int b = blockIdx.x, t = threadIdx.x;
    if (b < 4096) {
        cvt_body(hidden, hid_b, b, t);
    } else if (b < 7168) {
        int bb = b - 4096;                       // 96 x 32 tiles
        transpose_body(w_qkv, wqkv_t, HID_C, QKV_N, bb % 96, bb / 96, t, tile);
    } else if (b < 8192) {
        int bb = b - 7168;                       // 32 x 32
        transpose_body(w_g, wg_t, HID_C, HID_C, bb % 32, bb / 32, t, tile);
    } else if (b < 9216) {
        int bb = b - 8192;                       // 32 x 32
        transpose_body(w_dense, wd_t, HID_C, HID_C, bb % 32, bb / 32, t, tile);
    } else {
        int i = (b - 9216) * 256 + t;            // i < T*32
        int tt = i >> 5, fi = i & 31;
        float inv = expf((float)fi * -0.2878231366f);   // ln(10000)/32
        float freq = (float)positions[tt] * inv;
        float sn, cs;
        sincosf(freq, &sn, &cs);
        ropet[i] = make_float2(cs, sn);
    }
}

// ============== 256x256 flat-K-tile MFMA GEMM core (BK=64, 8 waves, dbuf LDS) ==============
// R3-proven schedule (best of 6 measured variants): per K-tile {all ds_reads (compiler-counted
// lgkm waits) ; stage t+1 ; MFMA ; vmcnt(0) (cheap: issued ~2500cyc earlier) ; 1 barrier}.
template<int MI, int BN>
__device__ __forceinline__ void gemm8_core(const ushort* __restrict__ Ag,
                                           const ushort* __restrict__ Bg,
                                           int K, int bm, int bn,
                                           ushort* sh, f32x4 (&acc)[MI][4]) {
    constexpr int WM = 16 / MI;          // waves along M: 2 or 4
    constexpr int WN = 8 / WM;           // waves along N: 4 or 2
    constexpr int SB = BN / 128;         // async16 per wave per B-half: 2 or 1
    constexpr int AH = (MI >= 8) ? 2 : 1;// A-read halves (VGPR pressure relief)
    constexpr int MH = MI / AH;

    const int tid  = threadIdx.x;
    const int lane = tid & 63;
    const int wave = tid >> 6;
    const int lane15 = lane & 15, quad = lane >> 4;
    const int wm = wave / WN, wn = wave % WN;
    const int swz = lane15 & 7;

    ushort* const ldsA0 = sh;              // [256][64] bf16, rows swizzled: phys grp p of row r = logical p^(r&7)
    ushort* const ldsA1 = sh + 16384;
    ushort* const ldsB0 = sh + 32768;      // [BN][64]
    ushort* const ldsB1 = sh + 32768 + BN * 64;

    // staging: lane l covers row (l>>3) of an 8-row chunk, physical 16B group (l&7),
    // so it must READ logical group (l&7)^(l>>3)  (involution: same xor on the read side)
    const int srow = lane >> 3;
    const int scol = ((lane & 7) ^ srow) << 3;
    const ushort* gA = Ag + (size_t)(bm + srow) * K + scol;
    const ushort* gB = Bg + (size_t)(bn + srow) * K + scol;
    const int ro  = wave * 16;             // A: each wave stages 2x 8-row chunks per half-tile
    const int roB = wave * 8 * SB;         // B: SB 8-row chunks per half-tile
    const int NT = K >> 6;

#define STAGE_A(L, k0) do { \
    _Pragma("unroll") for (int h = 0; h < 2; ++h) \
    _Pragma("unroll") for (int q = 0; q < 2; ++q) \
        async16(gA + (size_t)((h) * 128 + ro + q * 8) * K + (k0), (L) + ((h) * 128 + ro + q * 8) * 64); } while (0)
#define STAGE_B(L, k0) do { \
    _Pragma("unroll") for (int h = 0; h < 2; ++h) \
    _Pragma("unroll") for (int q = 0; q < SB; ++q) \
        async16(gB + (size_t)((h) * (BN / 2) + roB + q * 8) * K + (k0), (L) + ((h) * (BN / 2) + roB + q * 8) * 64); } while (0)

    // prologue: tile0 -> buf0
    STAGE_A(ldsA0, 0);
    STAGE_B(ldsB0, 0);
    waitcnt_vm<0>();
    asm volatile("s_barrier" ::: "memory");

    for (int t = 0; t < NT; ++t) {
        const ushort* LA = (t & 1) ? ldsA1 : ldsA0;
        const ushort* LB = (t & 1) ? ldsB1 : ldsB0;
        ushort* LAn = (t & 1) ? ldsA0 : ldsA1;
        ushort* LBn = (t & 1) ? ldsB0 : ldsB1;
        // ---- all B-frags + first A-half (compiler inserts counted lgkm waits) ----
        bf16x8 bfr[4][2];
#pragma unroll
        for (int j = 0; j < 4; ++j)
#pragma unroll
            for (int ks = 0; ks < 2; ++ks)
                bfr[j][ks] = *(const bf16x8*)&LB[(wn * 64 + j * 16 + lane15) * 64 + (((ks * 4 + quad) ^ swz) << 3)];
        bf16x8 af0[MH][2];
#pragma unroll
        for (int i = 0; i < MH; ++i)
#pragma unroll
            for (int ks = 0; ks < 2; ++ks)
                af0[i][ks] = *(const bf16x8*)&LA[(wm * (MI * 16) + i * 16 + lane15) * 64 + (((ks * 4 + quad) ^ swz) << 3)];
        // ---- stage tile t+1 into the other buffers (WAR-safe: last read before this tile's barrier) ----
        if (t + 1 < NT) {
            STAGE_A(LAn, (t + 1) << 6);
            STAGE_B(LBn, (t + 1) << 6);
        }
        __builtin_amdgcn_s_setprio(1);
#pragma unroll
        for (int i = 0; i < MH; ++i)
#pragma unroll
            for (int j = 0; j < 4; ++j)
#pragma unroll
                for (int ks = 0; ks < 2; ++ks)
                    acc[i][j] = __builtin_amdgcn_mfma_f32_16x16x32_bf16(af0[i][ks], bfr[j][ks], acc[i][j], 0, 0, 0);
        __builtin_amdgcn_s_setprio(0);
        if constexpr (AH == 2) {
            // ---- second A-half: reads overlap first MFMA cluster ----
            bf16x8 af1[MH][2];
#pragma unroll
            for (int i = 0; i < MH; ++i)
#pragma unroll
                for (int ks = 0; ks < 2; ++ks)
                    af1[i][ks] = *(const bf16x8*)&LA[(wm * (MI * 16) + (MH + i) * 16 + lane15) * 64 + (((ks * 4 + quad) ^ swz) << 3)];
            __builtin_amdgcn_s_setprio(1);
#pragma unroll
            for (int i = 0; i < MH; ++i)
#pragma unroll
                for (int j = 0; j < 4; ++j)
#pragma unroll
                    for (int ks = 0; ks < 2; ++ks)
                        acc[MH + i][j] = __builtin_amdgcn_mfma_f32_16x16x32_bf16(af1[i][ks], bfr[j][ks], acc[MH + i][j], 0, 0, 0);
            __builtin_amdgcn_s_setprio(0);
        }
        // t+1 staging landed long ago (issued ~2500cyc back); drain + handoff
        waitcnt_vm<0>();
        asm volatile("s_barrier" ::: "memory");
    }
#undef STAGE_A
#undef STAGE_B
}

// ============== 128x128 flat-K-tile core: 4 waves, 64 KiB LDS (for the dense GEMM) ==============
__device__ __forceinline__ void gemm4_core(const ushort* __restrict__ Ag,
                                           const ushort* __restrict__ Bg,
                                           int K, int bm, int bn,
                                           ushort* sh, f32x4 (&acc)[4][4]) {
    const int tid  = threadIdx.x;
    const int lane = tid & 63;
    const int wave = tid >> 6;             // 4 waves: 2M x 2N
    const int lane15 = lane & 15, quad = lane >> 4;
    const int wm = wave >> 1, wn = wave & 1;
    const int swz = lane15 & 7;

    ushort* const ldsA0 = sh;              // [128][64]
    ushort* const ldsA1 = sh + 8192;
    ushort* const ldsB0 = sh + 16384;
    ushort* const ldsB1 = sh + 24576;

    const int srow = lane >> 3;
    const int scol = ((lane & 7) ^ srow) << 3;
    const ushort* gA = Ag + (size_t)(bm + srow) * K + scol;
    const ushort* gB = Bg + (size_t)(bn + srow) * K + scol;
    const int ro = wave * 32;              // each wave stages 4x 8-row chunks (128 rows / 4 waves)
    const int NT = K >> 6;

#define STG(L, g, k0) do { \
    _Pragma("unroll") for (int q = 0; q < 4; ++q) \
        async16((g) + (size_t)(ro + q * 8) * K + (k0), (L) + (ro + q * 8) * 64); } while (0)

    STG(ldsA0, gA, 0);
    STG(ldsB0, gB, 0);
    waitcnt_vm<0>();
    asm volatile("s_barrier" ::: "memory");

    for (int t = 0; t < NT; ++t) {
        const ushort* LA = (t & 1) ? ldsA1 : ldsA0;
        const ushort* LB = (t & 1) ? ldsB1 : ldsB0;
        ushort* LAn = (t & 1) ? ldsA0 : ldsA1;
        ushort* LBn = (t & 1) ? ldsB0 : ldsB1;
        bf16x8 bfr[4][2];
#pragma unroll
        for (int j = 0; j < 4; ++j)
#pragma unroll
            for (int ks = 0; ks < 2; ++ks)
                bfr[j][ks] = *(const bf16x8*)&LB[(wn * 64 + j * 16 + lane15) * 64 + (((ks * 4 + quad) ^ swz) << 3)];
        bf16x8 af[4][2];
#pragma unroll
        for (int i = 0; i < 4; ++i)
#pragma unroll
            for (int ks = 0; ks < 2; ++ks)
                af[i][ks] = *(const bf16x8*)&LA[(wm * 64 + i * 16 + lane15) * 64 + (((ks * 4 + quad) ^ swz) << 3)];
        if (t + 1 < NT) {
            STG(LAn, gA, (t + 1) << 6);
            STG(LBn, gB, (t + 1) << 6);
        }
        __builtin_amdgcn_s_setprio(1);
#pragma unroll
        for (int i = 0; i < 4; ++i)
#pragma unroll
            for (int j = 0; j < 4; ++j)
#pragma unroll
                for (int ks = 0; ks < 2; ++ks)
                    acc[i][j] = __builtin_amdgcn_mfma_f32_16x16x32_bf16(af[i][ks], bfr[j][ks], acc[i][j], 0, 0, 0);
        __builtin_amdgcn_s_setprio(0);
        waitcnt_vm<0>();
        asm volatile("s_barrier" ::: "memory");
    }
#undef STG
}

// ---- fused qkv+gate GEMM + q/k RMSNorm+RoPE + k/v chunk-tiled transpose, all in-epilogue ----
// tiles: bn<2048 q | [2048,4096) k | [4096,6144) v | >=6144 gate.
// q: norm+rope+scale -> row-major qkv.  k: norm+rope -> row-major qkv AND chunk-tiled kT.
// v: chunk-tiled vT only.  gate: sigmoid -> gatebuf.
__global__ __launch_bounds__(512, 2) void gemm_fused(const ushort* __restrict__ A,
                                                     const ushort* __restrict__ Bcat,
                                                     ushort* __restrict__ qkv,
                                                     ushort* __restrict__ gate,
                                                     ushort* __restrict__ kT,
                                                     ushort* __restrict__ vT,
                                                     const float2* __restrict__ tab,
                                                     const float* __restrict__ qw,
                                                     const float* __restrict__ kw, int K) {
    __shared__ ushort sh[65536];           // 128 KiB: GEMM dbuf; epilogue reuses (post-final-barrier)
    // 2D-chunked XCD swizzle: GM=16 x GN=32 tiles; each XCD owns an 8m x 8n region
    // (n-fastest inside) -> concurrent per-XCD working set = 4 A-tiles + 8 B-tiles.
    int bid = blockIdx.x;
    int x = bid & 7, w = bid >> 3;         // XCD id, within-XCD order
    int rm = x >> 2, rn = x & 3;           // region coords: 2 x 4 regions
    int wm_i = w >> 3, wn_i = w & 7;       // 8 x 8 blocks inside region
    int bm = (rm * 8 + wm_i) * 256;
    int bn = (rn * 8 + wn_i) * 256;
    f32x4 acc[8][4] = {};
    gemm8_core<8, 256>(A, Bcat, K, bm, bn, sh, acc);

    int lane = threadIdx.x & 63, wave = threadIdx.x >> 6;
    int lane15 = lane & 15, quad = lane >> 4;
    int wm = wave >> 2, wn = wave & 3;
    constexpr int S = 132;                 // padded t-stride for transpose slabs

    if (bn < 4096) {
        // ================= q/k tile: RMSNorm + RoPE in-register =================
        bool isq = bn < 2048;
        const float* wnorm = isq ? qw : kw;
        int hq = wn >> 1, dl = (wn & 1) * 64;   // head-in-tile, d-offset within head
        int rowbase = bm + wm * 128;
        float w4[4];
#pragma unroll
        for (int j = 0; j < 4; ++j) w4[j] = wnorm[dl + j * 16 + lane15];
        float* ssb = (float*)&sh[63488];        // 4 KB at LDS tail (disjoint from slabs)
        // pass 1: per-row sum of squares (wave-local 64 cols) -> LDS
#pragma unroll
        for (int i = 0; i < 8; ++i)
#pragma unroll
            for (int r = 0; r < 4; ++r) {
                float s2 = 0.f;
#pragma unroll
                for (int j = 0; j < 4; ++j) { float xv = acc[i][j][r]; s2 += xv * xv; }
                s2 += __shfl_xor(s2, 1);
                s2 += __shfl_xor(s2, 2);
                s2 += __shfl_xor(s2, 4);
                s2 += __shfl_xor(s2, 8);
                if (lane15 == 0) ssb[wave * 128 + i * 16 + quad * 4 + r] = s2;
            }
        __syncthreads();
        // pass 2: combine wave-pair, normalize, rope, scale; write row-major
        float sc = isq ? 0.08838834764831845f : 1.0f;   // 128^-0.5 on q
#pragma unroll
        for (int i = 0; i < 8; ++i)
#pragma unroll
            for (int r = 0; r < 4; ++r) {
                int row = i * 16 + quad * 4 + r;
                float ssf = ssb[wave * 128 + row] + ssb[(wave ^ 1) * 128 + row];
                float rr = rsqrtf(ssf * (1.0f / 128.0f) + 1e-6f);
                float xx[4];
#pragma unroll
                for (int j = 0; j < 4; ++j) xx[j] = acc[i][j][r] * rr * w4[j];
                if (dl == 0) {
                    // rope: d<32 (j=0,1) pairs with d+32 (j=2,3); fi = j*16+lane15
                    int t = rowbase + row;
                    float2 rt0 = tab[t * 32 + lane15];
                    float2 rt1 = tab[t * 32 + 16 + lane15];
                    float a0 = xx[0], b0 = xx[2], a1 = xx[1], b1 = xx[3];
                    xx[0] = a0 * rt0.x - b0 * rt0.y;
                    xx[2] = b0 * rt0.x + a0 * rt0.y;
                    xx[1] = a1 * rt1.x - b1 * rt1.y;
                    xx[3] = b1 * rt1.x + a1 * rt1.y;
                }
#pragma unroll
                for (int j = 0; j < 4; ++j) acc[i][j][r] = xx[j] * sc;
            }
        // row-major write (q and k both consumed row-major by chunk_out)
#pragma unroll
        for (int i = 0; i < 8; ++i)
#pragma unroll
            for (int j = 0; j < 4; ++j) {
                int col = bn + wn * 64 + j * 16 + lane15;
#pragma unroll
                for (int r = 0; r < 4; ++r)
                    qkv[(size_t)(rowbase + i * 16 + quad * 4 + r) * QKV_N + col] = f2bfu(acc[i][j][r]);
            }
        if (!isq) {
            // ---- k: additionally transpose into chunk-tiled kT[h][c][128 d][128 t] ----
            ushort* L = sh;
            int h0 = (bn - 2048) >> 7;
            int c0 = bm >> 7;
            __syncthreads();               // ssb reads done before slab overwrite ordering
#pragma unroll
            for (int cq = 0; cq < 2; ++cq) {
                if (wm == cq) {
#pragma unroll
                    for (int i = 0; i < 8; ++i)
#pragma unroll
                        for (int j = 0; j < 4; ++j) {
                            int d_local = dl + j * 16 + lane15;
#pragma unroll
                            for (int r = 0; r < 4; ++r)
                                L[hq * 128 * S + d_local * S + i * 16 + quad * 4 + r] = f2bfu(acc[i][j][r]);
                        }
                }
                __syncthreads();
#pragma unroll
                for (int p = 0; p < 16; ++p) {
                    int lin = (p * 512 + threadIdx.x) * 4;
                    int hq2 = lin >> 14;
                    int wi = lin & 16383;
                    int d = wi >> 7, t4 = wi & 127;
                    const ushort* lp = &L[hq2 * 128 * S + d * S + t4];
                    ushort4 u = { lp[0], lp[1], lp[2], lp[3] };
                    *(ushort4*)&kT[((size_t)((h0 + hq2) * 32 + c0 + cq) * 128 + d) * 128 + t4] = u;
                }
                __syncthreads();
            }
        }
        return;
    }

    if (bn < QKV_N) {
        // ---- V tile: transpose 256x256 into vT chunk-tiled slabs [h][c][128 d][128 t] ----
        ushort* L = sh;
        int h0 = (bn - 4096) >> 7;
        int c0 = bm >> 7;
        int hq = wn >> 1;
        int dl = (wn & 1) * 64;
#pragma unroll
        for (int cq = 0; cq < 2; ++cq) {
            if (wm == cq) {
#pragma unroll
                for (int i = 0; i < 8; ++i)
#pragma unroll
                    for (int j = 0; j < 4; ++j) {
                        int d_local = dl + j * 16 + lane15;
#pragma unroll
                        for (int r = 0; r < 4; ++r)
                            L[hq * 128 * S + d_local * S + i * 16 + quad * 4 + r] = f2bfu(acc[i][j][r]);
                    }
            }
            __syncthreads();
#pragma unroll
            for (int p = 0; p < 16; ++p) {
                int lin = (p * 512 + threadIdx.x) * 4;
                int hq2 = lin >> 14;
                int wi = lin & 16383;
                int d = wi >> 7, t4 = wi & 127;
                const ushort* lp = &L[hq2 * 128 * S + d * S + t4];
                ushort4 u = { lp[0], lp[1], lp[2], lp[3] };
                *(ushort4*)&vT[((size_t)((h0 + hq2) * 32 + c0 + cq) * 128 + d) * 128 + t4] = u;
            }
            __syncthreads();
        }
        return;
    }

    // ---- gate tile: sigmoid -> gatebuf ----
    int cb = (bn - QKV_N) + wn * 64;
    int rb = bm + wm * 128;
#pragma unroll
    for (int i = 0; i < 8; ++i)
#pragma unroll
        for (int j = 0; j < 4; ++j) {
            int col = cb + j * 16 + lane15;
#pragma unroll
            for (int r = 0; r < 4; ++r) {
                float v = 1.0f / (1.0f + __expf(-acc[i][j][r]));
                gate[(size_t)(rb + i * 16 + quad * 4 + r) * HID_C + col] = f2bfu(v);
            }
        }
}

// ---- dense GEMM: fp32 out. BM=128 x BN=128, 256 thr, 64 KiB LDS (512 blocks, 2 blocks/CU) ----
__global__ __launch_bounds__(256, 2) void gemm_dense(const ushort* __restrict__ A,
                                                     const ushort* __restrict__ Bt,
                                                     float* __restrict__ Cout, int N, int K) {
    __shared__ ushort sh[32768];           // 64 KiB
    // GM=32 x GN=16 tiles; each XCD owns an 8m x 8n region (n-fastest inside)
    int bid = blockIdx.x;
    int x = bid & 7, w = bid >> 3;
    int rm = x >> 1, rn = x & 1;           // 4 x 2 regions
    int wm_i = w >> 3, wn_i = w & 7;       // 8 x 8 blocks inside region
    int bm = (rm * 8 + wm_i) * 128;
    int bn = (rn * 8 + wn_i) * 128;
    f32x4 acc[4][4] = {};
    gemm4_core(A, Bt, K, bm, bn, sh, acc);

    int lane = threadIdx.x & 63, wave = threadIdx.x >> 6;
    int lane15 = lane & 15, quad = lane >> 4;
    int wm = wave >> 1, wn = wave & 1;
    int cb = bn + wn * 64;
    int rb = bm + wm * 64;
#pragma unroll
    for (int i = 0; i < 4; ++i)
#pragma unroll
        for (int j = 0; j < 4; ++j) {
            int col = cb + j * 16 + lane15;
#pragma unroll
            for (int r = 0; r < 4; ++r)
                Cout[(size_t)(rb + i * 16 + quad * 4 + r) * N + col] = acc[i][j][r];
        }
}

// ------- per-chunk partial state (transposed, bf16): PT[c,h][v][d] = sum_j lam^(127-j) v_j[v] k_j[d] -------
__global__ __launch_bounds__(256) void chunk_partial(const ushort* __restrict__ kT,
                                                     const ushort* __restrict__ vT,
                                                     ushort* __restrict__ PT) {
    int c = blockIdx.x, h = blockIdx.y;
    float slope = head_slope(h);
    float lam_inv = __expf(-slope);
    int tid = threadIdx.x, lane = tid & 63, wave = tid >> 6;
    int lane15 = lane & 15, quad = lane >> 4;
    int wv = (wave & 1) * 64, wd = (wave >> 1) * 64;
    // chunk-tiled layout: slab (h,c) is contiguous [128 d][128 t]
    const ushort* vbase = vT + ((size_t)(h * 32 + c) * 128) * 128;
    const ushort* kbase = kT + ((size_t)(h * 32 + c) * 128) * 128;
    f32x4 acc[4][4] = {};
#pragma unroll
    for (int j0 = 0; j0 < 128; j0 += 32) {
        float w8[8];
        w8[0] = __expf(slope * (float)(127 - (j0 + quad * 8)));
#pragma unroll
        for (int kk = 1; kk < 8; ++kk) w8[kk] = w8[kk - 1] * lam_inv;
        bf16x8 afr[4], bfr[4];
#pragma unroll
        for (int i = 0; i < 4; ++i) {
            bf16x8 v = *(const bf16x8*)&vbase[(size_t)(wv + i * 16 + lane15) * 128 + j0 + quad * 8];
#pragma unroll
            for (int kk = 0; kk < 8; ++kk) afr[i][kk] = (__bf16)((float)v[kk] * w8[kk]);
        }
#pragma unroll
        for (int j = 0; j < 4; ++j)
            bfr[j] = *(const bf16x8*)&kbase[(size_t)(wd + j * 16 + lane15) * 128 + j0 + quad * 8];
#pragma unroll
        for (int i = 0; i < 4; ++i)
#pragma unroll
            for (int j = 0; j < 4; ++j)
                acc[i][j] = __builtin_amdgcn_mfma_f32_16x16x32_bf16(afr[i], bfr[j], acc[i][j], 0, 0, 0);
    }
    ushort* out = PT + ((size_t)c * 16 + h) * 16384;
#pragma unroll
    for (int i = 0; i < 4; ++i)
#pragma unroll
        for (int j = 0; j < 4; ++j)
#pragma unroll
            for (int r = 0; r < 4; ++r)
                out[(size_t)(wv + i * 16 + quad * 4 + r) * 128 + wd + j * 16 + lane15] = f2bfu(acc[i][j][r]);
}

// ------- sequential scan over 32 chunks: PT (bf16) -> Spb (bf16 prefix states) + Sfin -------
__global__ __launch_bounds__(128) void scan_states(const ushort* __restrict__ PT,
                                                   const float* __restrict__ S0,
                                                   ushort* __restrict__ Spb,
                                                   float* __restrict__ Sfin) {
    int hv = blockIdx.x;              // h*128 + v
    int d = threadIdx.x;              // k-dim
    int h = hv >> 7, v = hv & 127;
    float lamC = __expf(head_slope(h) * 128.0f);
    float s = S0[(size_t)h * 16384 + d * 128 + v];
#pragma unroll
    for (int c = 0; c < 32; ++c) {
        size_t idx = ((size_t)c * 2048 + hv) * 128 + d;
        Spb[idx] = f2bfu(s);          // state BEFORE chunk c, layout [c][h][v][d]
        s = s * lamC + bfu2f(PT[idx]);
    }
    Sfin[(size_t)h * 16384 + d * 128 + v] = s;
}

// ------- per-chunk output: QK^T (masked/decayed) * V + lam^(t+1) * Q * S_prev -------
__global__ __launch_bounds__(256) void chunk_out(const ushort* __restrict__ qkv,
                                                 const ushort* __restrict__ vT,
                                                 const ushort* __restrict__ Spb,
                                                 ushort* __restrict__ o) {
    int c = blockIdx.x, h = blockIdx.y;
    float slope = head_slope(h);
    __shared__ ushort Ps[128 * 136];   // padded: row stride 272B -> conflict-free b128
    int tid = threadIdx.x, lane = tid & 63, wave = tid >> 6;
    int lane15 = lane & 15, quad = lane >> 4;
    int t0 = c * 128;
    int tt0 = wave, tt1 = 7 - wave;    // owned t-tiles (balanced triangular split)
    const ushort* qbase = qkv + (size_t)t0 * QKV_N + h * 128;
    const ushort* kbase = qbase + 2048;

    bf16x8 qf0[4], qf1[4];
#pragma unroll
    for (int ds = 0; ds < 4; ++ds) {
        qf0[ds] = *(const bf16x8*)&qbase[(size_t)(tt0 * 16 + lane15) * QKV_N + ds * 32 + quad * 8];
        qf1[ds] = *(const bf16x8*)&qbase[(size_t)(tt1 * 16 + lane15) * QKV_N + ds * 32 + quad * 8];
    }
    // ---- phase 1: scores ----
    f32x4 s0a[4] = {};
    f32x4 s1a[8] = {};
#pragma unroll
    for (int st = 0; st < 8; ++st) {
        if (st <= tt1) {
            bf16x8 kf[4];
#pragma unroll
            for (int ds = 0; ds < 4; ++ds)
                kf[ds] = *(const bf16x8*)&kbase[(size_t)(st * 16 + lane15) * QKV_N + ds * 32 + quad * 8];
#pragma unroll
            for (int ds = 0; ds < 4; ++ds)
                s1a[st] = __builtin_amdgcn_mfma_f32_16x16x32_bf16(qf1[ds], kf[ds], s1a[st], 0, 0, 0);
            if (st <= tt0) {
#pragma unroll
                for (int ds = 0; ds < 4; ++ds)
                    s0a[st] = __builtin_amdgcn_mfma_f32_16x16x32_bf16(qf0[ds], kf[ds], s0a[st], 0, 0, 0);
            }
        }
    }
    // ---- park masked/decayed scores (zero strip pads odd 16-blocks to 32) ----
    int stmax0 = tt0 + ((tt0 & 1) ? 0 : 1);
    int stmax1 = tt1 + ((tt1 & 1) ? 0 : 1);
#pragma unroll
    for (int st = 0; st < 8; ++st) {
        if (st <= stmax1) {
#pragma unroll
            for (int r = 0; r < 4; ++r) {
                int t = tt1 * 16 + quad * 4 + r;
                int s = st * 16 + lane15;
                float val = 0.f;
                if (st <= tt1) val = (s <= t) ? s1a[st][r] * __expf(slope * (float)(t - s)) : 0.f;
                Ps[t * 136 + s] = f2bfu(val);
            }
        }
    }
#pragma unroll
    for (int st = 0; st < 5; ++st) {
        if (st <= stmax0) {
#pragma unroll
            for (int r = 0; r < 4; ++r) {
                int t = tt0 * 16 + quad * 4 + r;
                int s = st * 16 + lane15;
                float val = 0.f;
                if (st <= tt0) val = (s <= t) ? s0a[st][r] * __expf(slope * (float)(t - s)) : 0.f;
                Ps[t * 136 + s] = f2bfu(val);
            }
        }
    }
    __syncthreads();
    // ---- phase 2: O = P*V + diag(lam^(t+1)) Q*S_prev ----
    f32x4 oa0[8] = {};
    f32x4 oa1[8] = {};
    float lam0 = __expf(slope * (float)(tt0 * 16 + lane15 + 1));
    float lam1 = __expf(slope * (float)(tt1 * 16 + lane15 + 1));
    bf16x8 qs0[4], qs1[4];
#pragma unroll
    for (int ds = 0; ds < 4; ++ds)
#pragma unroll
        for (int kk = 0; kk < 8; ++kk) {
            qs0[ds][kk] = (__bf16)((float)qf0[ds][kk] * lam0);
            qs1[ds][kk] = (__bf16)((float)qf1[ds][kk] * lam1);
        }
    const ushort* spb = Spb + ((size_t)c * 2048 + h * 128) * 128;
#pragma unroll
    for (int vt = 0; vt < 8; ++vt)
#pragma unroll
        for (int ds = 0; ds < 4; ++ds) {
            bf16x8 bfrag = *(const bf16x8*)&spb[(vt * 16 + lane15) * 128 + ds * 32 + quad * 8];
            oa0[vt] = __builtin_amdgcn_mfma_f32_16x16x32_bf16(qs0[ds], bfrag, oa0[vt], 0, 0, 0);
            oa1[vt] = __builtin_amdgcn_mfma_f32_16x16x32_bf16(qs1[ds], bfrag, oa1[vt], 0, 0, 0);
        }
    // chunk-tiled layout: slab (h,c) contiguous [128 d][128 t]
    const ushort* vbase = vT + ((size_t)(h * 32 + c) * 128) * 128;
    int ns0 = (tt0 + 2) >> 1, ns1 = (tt1 + 2) >> 1;
#pragma unroll
    for (int s32 = 0; s32 < 4; ++s32) {
        if (s32 < ns1) {
            bf16x8 af = *(const bf16x8*)&Ps[(tt1 * 16 + lane15) * 136 + s32 * 32 + quad * 8];
#pragma unroll
            for (int vt = 0; vt < 8; ++vt) {
                bf16x8 bfrag = *(const bf16x8*)&vbase[(size_t)(vt * 16 + lane15) * 128 + s32 * 32 + quad * 8];
                oa1[vt] = __builtin_amdgcn_mfma_f32_16x16x32_bf16(af, bfrag, oa1[vt], 0, 0, 0);
            }
        }
    }
#pragma unroll
    for (int s32 = 0; s32 < 2; ++s32) {
        if (s32 < ns0) {
            bf16x8 af = *(const bf16x8*)&Ps[(tt0 * 16 + lane15) * 136 + s32 * 32 + quad * 8];
#pragma unroll
            for (int vt = 0; vt < 8; ++vt) {
                bf16x8 bfrag = *(const bf16x8*)&vbase[(size_t)(vt * 16 + lane15) * 128 + s32 * 32 + quad * 8];
                oa0[vt] = __builtin_amdgcn_mfma_f32_16x16x32_bf16(af, bfrag, oa0[vt], 0, 0, 0);
            }
        }
    }
    // ---- epilogue (bf16) ----
#pragma unroll
    for (int vt = 0; vt < 8; ++vt)
#pragma unroll
        for (int r = 0; r < 4; ++r) {
            o[(size_t)(t0 + tt0 * 16 + quad * 4 + r) * 2048 + h * 128 + vt * 16 + lane15] = f2bfu(oa0[vt][r]);
            o[(size_t)(t0 + tt1 * 16 + quad * 4 + r) * 2048 + h * 128 + vt * 16 + lane15] = f2bfu(oa1[vt][r]);
        }
}

// ---------------- group RMS-norm * g_norm_w * sigmoid-gate -> bf16 ----------------
__global__ __launch_bounds__(256) void gnorm_gate(const ushort* __restrict__ o,
                                                  const ushort* __restrict__ gate,
                                                  const float* __restrict__ gw,
                                                  ushort* __restrict__ gg) {
    int t = blockIdx.x;
    int tid = threadIdx.x;
    const ushort* op = o + (size_t)t * 2048 + tid * 8;
    bf16x8 xv = *(const bf16x8*)op;
    float x[8];
    float ss = 0.0f;
#pragma unroll
    for (int i = 0; i < 8; ++i) { x[i] = (float)xv[i]; ss += x[i] * x[i]; }
#pragma unroll
    for (int off = 16; off > 0; off >>= 1) ss += __shfl_xor(ss, off);  // 32-thread group = 256 elems
    float r = rsqrtf(ss * (1.0f / 256.0f) + 1e-6f);
    const ushort* gp = gate + (size_t)t * 2048;
#pragma unroll
    for (int i = 0; i < 8; ++i) {
        int j = tid * 8 + i;
        float val = x[i] * r * gw[j] * bfu2f(gp[j]);
        gg[(size_t)t * 2048 + j] = f2bfu(val);
    }
}

extern "C" void kernel_launch(void* const* d_in, const int* in_sizes, int n_in,
                              void* d_out, int out_size, void* d_ws, size_t ws_size,
                              hipStream_t stream) {
    const int* positions   = (const int*)d_in[0];
    const float* hidden    = (const float*)d_in[1];
    const float* S0        = (const float*)d_in[2];
    const float* w_qkv     = (const float*)d_in[3];
    const float* w_g       = (const float*)d_in[4];
    const float* w_dense   = (const float*)d_in[5];
    const float* qw        = (const float*)d_in[6];
    const float* kw        = (const float*)d_in[7];
    const float* gw        = (const float*)d_in[8];

    char* ws = (char*)d_ws;
    ushort* qkv     = (ushort*)ws;                    // bf16 T x 6144            [0, 50331648)
    ushort* wqkv_t  = (ushort*)(ws + 50331648);       // bf16 6144 x 2048 (25.2M) — Bcat rows 0..6143
    ushort* wg_t    = (ushort*)(ws + 75497472);       // bf16 2048 x 2048 (8.4M)  — Bcat rows 6144..8191
    float2* ropet   = (float2*)(ws + 159383552);      // 1 MB — separate region
    ushort* PT      = (ushort*)(ws + 50331648);       // bf16 32x16x128x128 (16.8M) — aliases wqkv_t (dead)
    ushort* wd_t    = (ushort*)(ws + 83886080);       // bf16 2048 x 2048 (8.4M)
    ushort* gatebuf = (ushort*)(ws + 92274688);       // bf16 T x 2048 (16.8M)
    ushort* hid_b   = (ushort*)(ws + 109051904);      // bf16 T x 2048 (16.8M)
    ushort* Spb     = (ushort*)(ws + 109051904);      // bf16 32x16x128x128 (16.8M) — aliases hid_b (dead)
    ushort* kT      = (ushort*)(ws + 125829120);      // bf16 [16][32][128][128] (16.8M) chunk-tiled
    ushort* vT      = (ushort*)(ws + 142606336);      // bf16 [16][32][128][128] (16.8M) chunk-tiled
    ushort* gg      = (ushort*)ws;                    // aliases qkv (dead by gnorm time)  total 160,432,128

    float* out  = (float*)d_out;
    float* Sfin = out + (size_t)T_SEQ * HID_C;
    ushort* obuf = (ushort*)d_out;                    // out-region doubles as bf16 attn scratch

    // one launch: cvt + 3 transposes + rope table (all independent preprocessing)
    prep_all<<<9728, 256, 0, stream>>>(hidden, hid_b, w_qkv, wqkv_t, w_g, wg_t,
                                       w_dense, wd_t, positions, ropet);

    // 256x256 tiles: 512 blocks of 512 threads.
    // epilogue does q/k RMSNorm+RoPE (q,k row-major; k also -> kT) and v -> vT; qk_rope_T is gone.
    gemm_fused<<<dim3(512), 512, 0, stream>>>(hid_b, wqkv_t, qkv, gatebuf, kT, vT,
                                              ropet, qw, kw, HID_C);

    chunk_partial<<<dim3(32, 16), 256, 0, stream>>>(kT, vT, PT);
    scan_states<<<2048, 128, 0, stream>>>(PT, S0, Spb, Sfin);
    chunk_out<<<dim3(32, 16), 256, 0, stream>>>(qkv, vT, Spb, obuf);
    gnorm_gate<<<T_SEQ, 256, 0, stream>>>(obuf, gatebuf, gw, gg);

    // 128x128 tiles: (4096/128)*(2048/128) = 32*16 = 512 blocks of 256 thr, 2 blocks/CU
    gemm_dense<<<dim3(512), 256, 0, stream>>>(gg, wd_t, out, HID_C, HID_C);
}

// Round 12
// 388.988 us; speedup vs baseline: 1.1308x; 1.0529x over previous
//
#include <hip/hip_runtime.h>
#include <hip/hip_bf16.h>

using bf16x8 = __attribute__((ext_vector_type(8))) __bf16;
using f32x4  = __attribute__((ext_vector_type(4))) float;

constexpr int T_SEQ = 4096;
constexpr int HID_C = 2048;
constexpr int NH    = 16;
constexpr int QKV_N = 6144;

__device__ __forceinline__ float head_slope(int h) {
    // slope[h] = -2^{-(h+1)/2} * (1 - 1/31 + 1e-5)
    return -exp2f(-0.5f * (float)(h + 1)) * 0.967751935483871f;
}

__device__ __forceinline__ ushort f2bfu(float f) {
    __hip_bfloat16 h = __float2bfloat16(f);
    return *(ushort*)&h;
}
__device__ __forceinline__ float bfu2f(ushort u) {
    union { unsigned int i; float f; } x; x.i = ((unsigned int)u) << 16; return x.f;
}

// async global -> LDS, 16 bytes per lane; LDS dest = wave-uniform base + lane*16
__device__ __forceinline__ void async16(const ushort* g, ushort* l) {
    __builtin_amdgcn_global_load_lds((const __attribute__((address_space(1))) void*)g,
                                     (__attribute__((address_space(3))) void*)l, 16, 0, 0);
}

template<int N> __device__ __forceinline__ void waitcnt_vm() {
    if constexpr (N == 0)      asm volatile("s_waitcnt vmcnt(0)" ::: "memory");
    else if constexpr (N == 2) asm volatile("s_waitcnt vmcnt(2)" ::: "memory");
    else if constexpr (N == 4) asm volatile("s_waitcnt vmcnt(4)" ::: "memory");
    else if constexpr (N == 6) asm volatile("s_waitcnt vmcnt(6)" ::: "memory");
}

// ============ merged preprocessing: cvt_bf16 + 3x transpose_cvt + rope_tab in ONE launch ============
__device__ __forceinline__ void cvt_body(const float* __restrict__ src, ushort* __restrict__ dst,
                                         int bid, int tid) {
    int i = (bid * 256 + tid) * 8;
    float4 a = *(const float4*)(src + i);
    float4 b = *(const float4*)(src + i + 4);
    ushort4 ua = {f2bfu(a.x), f2bfu(a.y), f2bfu(a.z), f2bfu(a.w)};
    ushort4 ub = {f2bfu(b.x), f2bfu(b.y), f2bfu(b.z), f2bfu(b.w)};
    *(ushort4*)(dst + i) = ua;
    *(ushort4*)(dst + i + 4) = ub;
}

__device__ __forceinline__ void transpose_body(const float* __restrict__ src,
                                               ushort* __restrict__ dst,
                                               int R, int C, int bx, int by, int t,
                                               ushort (*tile)[68]) {
    int tr = by * 64, tc = bx * 64;
    int r0 = t >> 4;
    int c4 = (t & 15) << 2;
#pragma unroll
    for (int p = 0; p < 4; ++p) {
        int row = r0 + p * 16;
        float4 v = *(const float4*)&src[(size_t)(tr + row) * C + tc + c4];
        tile[row][c4 + 0] = f2bfu(v.x);
        tile[row][c4 + 1] = f2bfu(v.y);
        tile[row][c4 + 2] = f2bfu(v.z);
        tile[row][c4 + 3] = f2bfu(v.w);
    }
    __syncthreads();
#pragma unroll
    for (int p = 0; p < 4; ++p) {
        int orow = r0 + p * 16;
        ushort4 u;
        u.x = tile[c4 + 0][orow];
        u.y = tile[c4 + 1][orow];
        u.z = tile[c4 + 2][orow];
        u.w = tile[c4 + 3][orow];
        *(ushort4*)&dst[(size_t)(tc + orow) * R + tr + c4] = u;
    }
}

// grid: [0,4096) cvt | [4096,7168) w_qkv T | [7168,8192) w_g T | [8192,9216) w_dense T | [9216,9728) rope
__global__ __launch_bounds__(256) void prep_all(const float* __restrict__ hidden,
                                                ushort* __restrict__ hid_b,
                                                const float* __restrict__ w_qkv,
                                                ushort* __restrict__ wqkv_t,
                                                const float* __restrict__ w_g,
                                                ushort* __restrict__ wg_t,
                                                const float* __restrict__ w_dense,
                                                ushort* __restrict__ wd_t,
                                                const int* __restrict__ positions,
                                                float2* __restrict__ ropet) {
    __shared__ ushort tile[64][68];
    int b = blockIdx.x, t = threadIdx.x;
    if (b < 4096) {
        cvt_body(hidden, hid_b, b, t);
    } else if (b < 7168) {
        int bb = b - 4096;                       // 96 x 32 tiles
        transpose_body(w_qkv, wqkv_t, HID_C, QKV_N, bb % 96, bb / 96, t, tile);
    } else if (b < 8192) {
        int bb = b - 7168;                       // 32 x 32
        transpose_body(w_g, wg_t, HID_C, HID_C, bb % 32, bb / 32, t, tile);
    } else if (b < 9216) {
        int bb = b - 8192;                       // 32 x 32
        transpose_body(w_dense, wd_t, HID_C, HID_C, bb % 32, bb / 32, t, tile);
    } else {
        int i = (b - 9216) * 256 + t;            // i < T*32
        int tt = i >> 5, fi = i & 31;
        float inv = expf((float)fi * -0.2878231366f);   // ln(10000)/32
        float freq = (float)positions[tt] * inv;
        float sn, cs;
        sincosf(freq, &sn, &cs);
        ropet[i] = make_float2(cs, sn);
    }
}

// ============== 256x256 flat-K-tile MFMA GEMM core, waves 4M x 2N (BK=64, 8 waves, dbuf LDS) ==============
// Per-wave output: 64 rows x 128 cols (ONE FULL HEAD of q/k/v) -> epilogue norm/rope is wave-local.
// Same flat schedule as the proven 2Mx4N core with A<->B fragment roles swapped:
// {A-frags(8) + B-half(8) reads ; stage t+1 ; 32 MFMA ; B-half-2(8) reads ; 32 MFMA ; vmcnt(0) ; barrier}.
__device__ __forceinline__ void gemm8w_core(const ushort* __restrict__ Ag,
                                            const ushort* __restrict__ Bg,
                                            int K, int bm, int bn,
                                            ushort* sh, f32x4 (&acc)[4][8]) {
    const int tid  = threadIdx.x;
    const int lane = tid & 63;
    const int wave = tid >> 6;
    const int lane15 = lane & 15, quad = lane >> 4;
    const int wm = wave >> 1, wn = wave & 1;   // 4M x 2N
    const int swz = lane15 & 7;

    ushort* const ldsA0 = sh;              // [256][64] bf16, rows swizzled: phys grp p of row r = logical p^(r&7)
    ushort* const ldsA1 = sh + 16384;
    ushort* const ldsB0 = sh + 32768;      // [256][64]
    ushort* const ldsB1 = sh + 49152;

    // staging: lane l covers row (l>>3) of an 8-row chunk, physical 16B group (l&7),
    // so it must READ logical group (l&7)^(l>>3)  (involution: same xor on the read side)
    const int srow = lane >> 3;
    const int scol = ((lane & 7) ^ srow) << 3;
    const ushort* gA = Ag + (size_t)(bm + srow) * K + scol;
    const ushort* gB = Bg + (size_t)(bn + srow) * K + scol;
    const int ro = wave * 16;              // each wave stages 2x 8-row chunks per half-tile
    const int NT = K >> 6;

#define STAGE8(L, g, k0) do { \
    _Pragma("unroll") for (int h = 0; h < 2; ++h) \
    _Pragma("unroll") for (int q = 0; q < 2; ++q) \
        async16((g) + (size_t)((h) * 128 + ro + q * 8) * K + (k0), (L) + ((h) * 128 + ro + q * 8) * 64); } while (0)

    // prologue: tile0 -> buf0
    STAGE8(ldsA0, gA, 0);
    STAGE8(ldsB0, gB, 0);
    waitcnt_vm<0>();
    asm volatile("s_barrier" ::: "memory");

    for (int t = 0; t < NT; ++t) {
        const ushort* LA = (t & 1) ? ldsA1 : ldsA0;
        const ushort* LB = (t & 1) ? ldsB1 : ldsB0;
        ushort* LAn = (t & 1) ? ldsA0 : ldsA1;
        ushort* LBn = (t & 1) ? ldsB0 : ldsB1;
        // ---- all A-frags + first B-half (compiler inserts counted lgkm waits) ----
        bf16x8 af[4][2];
#pragma unroll
        for (int i = 0; i < 4; ++i)
#pragma unroll
            for (int ks = 0; ks < 2; ++ks)
                af[i][ks] = *(const bf16x8*)&LA[(wm * 64 + i * 16 + lane15) * 64 + (((ks * 4 + quad) ^ swz) << 3)];
        bf16x8 bf0[4][2];
#pragma unroll
        for (int j = 0; j < 4; ++j)
#pragma unroll
            for (int ks = 0; ks < 2; ++ks)
                bf0[j][ks] = *(const bf16x8*)&LB[(wn * 128 + j * 16 + lane15) * 64 + (((ks * 4 + quad) ^ swz) << 3)];
        // ---- stage tile t+1 into the other buffers (WAR-safe) ----
        if (t + 1 < NT) {
            STAGE8(LAn, gA, (t + 1) << 6);
            STAGE8(LBn, gB, (t + 1) << 6);
        }
        __builtin_amdgcn_s_setprio(1);
#pragma unroll
        for (int i = 0; i < 4; ++i)
#pragma unroll
            for (int j = 0; j < 4; ++j)
#pragma unroll
                for (int ks = 0; ks < 2; ++ks)
                    acc[i][j] = __builtin_amdgcn_mfma_f32_16x16x32_bf16(af[i][ks], bf0[j][ks], acc[i][j], 0, 0, 0);
        __builtin_amdgcn_s_setprio(0);
        // ---- second B-half: reads overlap first MFMA cluster ----
        bf16x8 bf1[4][2];
#pragma unroll
        for (int j = 0; j < 4; ++j)
#pragma unroll
            for (int ks = 0; ks < 2; ++ks)
                bf1[j][ks] = *(const bf16x8*)&LB[(wn * 128 + (4 + j) * 16 + lane15) * 64 + (((ks * 4 + quad) ^ swz) << 3)];
        __builtin_amdgcn_s_setprio(1);
#pragma unroll
        for (int i = 0; i < 4; ++i)
#pragma unroll
            for (int j = 0; j < 4; ++j)
#pragma unroll
                for (int ks = 0; ks < 2; ++ks)
                    acc[i][4 + j] = __builtin_amdgcn_mfma_f32_16x16x32_bf16(af[i][ks], bf1[j][ks], acc[i][4 + j], 0, 0, 0);
        __builtin_amdgcn_s_setprio(0);
        // t+1 staging landed long ago (issued ~2500cyc back); drain + handoff
        waitcnt_vm<0>();
        asm volatile("s_barrier" ::: "memory");
    }
#undef STAGE8
}

// ============== 128x128 flat-K-tile core: 4 waves, 64 KiB LDS (for the dense GEMM) ==============
__device__ __forceinline__ void gemm4_core(const ushort* __restrict__ Ag,
                                           const ushort* __restrict__ Bg,
                                           int K, int bm, int bn,
                                           ushort* sh, f32x4 (&acc)[4][4]) {
    const int tid  = threadIdx.x;
    const int lane = tid & 63;
    const int wave = tid >> 6;             // 4 waves: 2M x 2N
    const int lane15 = lane & 15, quad = lane >> 4;
    const int wm = wave >> 1, wn = wave & 1;
    const int swz = lane15 & 7;

    ushort* const ldsA0 = sh;              // [128][64]
    ushort* const ldsA1 = sh + 8192;
    ushort* const ldsB0 = sh + 16384;
    ushort* const ldsB1 = sh + 24576;

    const int srow = lane >> 3;
    const int scol = ((lane & 7) ^ srow) << 3;
    const ushort* gA = Ag + (size_t)(bm + srow) * K + scol;
    const ushort* gB = Bg + (size_t)(bn + srow) * K + scol;
    const int ro = wave * 32;              // each wave stages 4x 8-row chunks (128 rows / 4 waves)
    const int NT = K >> 6;

#define STG(L, g, k0) do { \
    _Pragma("unroll") for (int q = 0; q < 4; ++q) \
        async16((g) + (size_t)(ro + q * 8) * K + (k0), (L) + (ro + q * 8) * 64); } while (0)

    STG(ldsA0, gA, 0);
    STG(ldsB0, gB, 0);
    waitcnt_vm<0>();
    asm volatile("s_barrier" ::: "memory");

    for (int t = 0; t < NT; ++t) {
        const ushort* LA = (t & 1) ? ldsA1 : ldsA0;
        const ushort* LB = (t & 1) ? ldsB1 : ldsB0;
        ushort* LAn = (t & 1) ? ldsA0 : ldsA1;
        ushort* LBn = (t & 1) ? ldsB0 : ldsB1;
        bf16x8 bfr[4][2];
#pragma unroll
        for (int j = 0; j < 4; ++j)
#pragma unroll
            for (int ks = 0; ks < 2; ++ks)
                bfr[j][ks] = *(const bf16x8*)&LB[(wn * 64 + j * 16 + lane15) * 64 + (((ks * 4 + quad) ^ swz) << 3)];
        bf16x8 af[4][2];
#pragma unroll
        for (int i = 0; i < 4; ++i)
#pragma unroll
            for (int ks = 0; ks < 2; ++ks)
                af[i][ks] = *(const bf16x8*)&LA[(wm * 64 + i * 16 + lane15) * 64 + (((ks * 4 + quad) ^ swz) << 3)];
        if (t + 1 < NT) {
            STG(LAn, gA, (t + 1) << 6);
            STG(LBn, gB, (t + 1) << 6);
        }
        __builtin_amdgcn_s_setprio(1);
#pragma unroll
        for (int i = 0; i < 4; ++i)
#pragma unroll
            for (int j = 0; j < 4; ++j)
#pragma unroll
                for (int ks = 0; ks < 2; ++ks)
                    acc[i][j] = __builtin_amdgcn_mfma_f32_16x16x32_bf16(af[i][ks], bfr[j][ks], acc[i][j], 0, 0, 0);
        __builtin_amdgcn_s_setprio(0);
        waitcnt_vm<0>();
        asm volatile("s_barrier" ::: "memory");
    }
#undef STG
}

// ---- fused qkv+gate GEMM + q/k RMSNorm+RoPE + k/v chunk-tiled transpose, all in-epilogue ----
// waves 4Mx2N: each wave owns 64 rows x 1 full head -> norm/rope wave-local (no LDS exchange).
// tiles: bn<2048 q | [2048,4096) k | [4096,6144) v | >=6144 gate.
__global__ __launch_bounds__(512, 2) void gemm_fused(const ushort* __restrict__ A,
                                                     const ushort* __restrict__ Bcat,
                                                     ushort* __restrict__ qkv,
                                                     ushort* __restrict__ gate,
                                                     ushort* __restrict__ kT,
                                                     ushort* __restrict__ vT,
                                                     const float2* __restrict__ tab,
                                                     const float* __restrict__ qw,
                                                     const float* __restrict__ kw, int K) {
    __shared__ ushort sh[65536];           // 128 KiB: GEMM dbuf; epilogue reuses (post-final-barrier)
    // 2D-chunked XCD swizzle: GM=16 x GN=32 tiles; each XCD owns an 8m x 8n region (n-fastest inside)
    int bid = blockIdx.x;
    int x = bid & 7, w = bid >> 3;
    int rm = x >> 2, rn = x & 3;
    int wm_i = w >> 3, wn_i = w & 7;
    int bm = (rm * 8 + wm_i) * 256;
    int bn = (rn * 8 + wn_i) * 256;
    f32x4 acc[4][8] = {};
    gemm8w_core(A, Bcat, K, bm, bn, sh, acc);

    int lane = threadIdx.x & 63, wave = threadIdx.x >> 6;
    int lane15 = lane & 15, quad = lane >> 4;
    int wm = wave >> 1, wn = wave & 1;     // 4M x 2N
    constexpr int S = 132;                 // padded t-stride for transpose slabs

    if (bn < 4096) {
        // ========== q/k tile: wave-local RMSNorm + RoPE ==========
        bool isq = bn < 2048;
        const float* wnorm = isq ? qw : kw;
        float w8a[8];
#pragma unroll
        for (int j = 0; j < 8; ++j) w8a[j] = wnorm[j * 16 + lane15];
        float sc = isq ? 0.08838834764831845f : 1.0f;   // 128^-0.5 on q
        int rowbase = bm + wm * 64;
#pragma unroll
        for (int i = 0; i < 4; ++i)
#pragma unroll
            for (int r = 0; r < 4; ++r) {
                float s2 = 0.f;
#pragma unroll
                for (int j = 0; j < 8; ++j) { float xv = acc[i][j][r]; s2 += xv * xv; }
                s2 += __shfl_xor(s2, 1);
                s2 += __shfl_xor(s2, 2);
                s2 += __shfl_xor(s2, 4);
                s2 += __shfl_xor(s2, 8);
                float rr = rsqrtf(s2 * (1.0f / 128.0f) + 1e-6f);
                float xx[8];
#pragma unroll
                for (int j = 0; j < 8; ++j) xx[j] = acc[i][j][r] * rr * w8a[j];
                // rope: d = j*16+lane15; pairs (j, j+2) for j=0,1; fi = d
                int t = rowbase + i * 16 + quad * 4 + r;
                float2 rt0 = tab[t * 32 + lane15];
                float2 rt1 = tab[t * 32 + 16 + lane15];
                float a0 = xx[0], b0 = xx[2], a1 = xx[1], b1 = xx[3];
                xx[0] = a0 * rt0.x - b0 * rt0.y;
                xx[2] = b0 * rt0.x + a0 * rt0.y;
                xx[1] = a1 * rt1.x - b1 * rt1.y;
                xx[3] = b1 * rt1.x + a1 * rt1.y;
#pragma unroll
                for (int j = 0; j < 8; ++j) acc[i][j][r] = xx[j] * sc;
            }
        // row-major write
#pragma unroll
        for (int i = 0; i < 4; ++i)
#pragma unroll
            for (int j = 0; j < 8; ++j) {
                int col = bn + wn * 128 + j * 16 + lane15;
#pragma unroll
                for (int r = 0; r < 4; ++r)
                    qkv[(size_t)(rowbase + i * 16 + quad * 4 + r) * QKV_N + col] = f2bfu(acc[i][j][r]);
            }
        if (!isq) {
            // ---- k: additionally transpose into chunk-tiled kT[h][c][128 d][128 t] ----
            ushort* L = sh;                // slabs [wn][128 d][S]
            int h0 = (bn - 2048) >> 7;     // head of wn=0
            int c0 = bm >> 7;
#pragma unroll
            for (int cq = 0; cq < 2; ++cq) {
                if ((wm >> 1) == cq) {     // waves holding rows cq*128..+127
#pragma unroll
                    for (int i = 0; i < 4; ++i)
#pragma unroll
                        for (int j = 0; j < 8; ++j) {
                            int d_local = j * 16 + lane15;
#pragma unroll
                            for (int r = 0; r < 4; ++r) {
                                int t_local = (wm & 1) * 64 + i * 16 + quad * 4 + r;
                                L[wn * 128 * S + d_local * S + t_local] = f2bfu(acc[i][j][r]);
                            }
                        }
                }
                __syncthreads();
#pragma unroll
                for (int p = 0; p < 16; ++p) {
                    int lin = (p * 512 + threadIdx.x) * 4;
                    int hq2 = lin >> 14;
                    int wi = lin & 16383;
                    int d = wi >> 7, t4 = wi & 127;
                    const ushort* lp = &L[hq2 * 128 * S + d * S + t4];
                    ushort4 u = { lp[0], lp[1], lp[2], lp[3] };
                    *(ushort4*)&kT[((size_t)((h0 + hq2) * 32 + c0 + cq) * 128 + d) * 128 + t4] = u;
                }
                __syncthreads();
            }
        }
        return;
    }

    if (bn < QKV_N) {
        // ---- V tile: transpose 256x256 into vT chunk-tiled slabs [h][c][128 d][128 t] ----
        ushort* L = sh;
        int h0 = (bn - 4096) >> 7;
        int c0 = bm >> 7;
#pragma unroll
        for (int cq = 0; cq < 2; ++cq) {
            if ((wm >> 1) == cq) {
#pragma unroll
                for (int i = 0; i < 4; ++i)
#pragma unroll
                    for (int j = 0; j < 8; ++j) {
                        int d_local = j * 16 + lane15;
#pragma unroll
                        for (int r = 0; r < 4; ++r) {
                            int t_local = (wm & 1) * 64 + i * 16 + quad * 4 + r;
                            L[wn * 128 * S + d_local * S + t_local] = f2bfu(acc[i][j][r]);
                        }
                    }
            }
            __syncthreads();
#pragma unroll
            for (int p = 0; p < 16; ++p) {
                int lin = (p * 512 + threadIdx.x) * 4;
                int hq2 = lin >> 14;
                int wi = lin & 16383;
                int d = wi >> 7, t4 = wi & 127;
                const ushort* lp = &L[hq2 * 128 * S + d * S + t4];
                ushort4 u = { lp[0], lp[1], lp[2], lp[3] };
                *(ushort4*)&vT[((size_t)((h0 + hq2) * 32 + c0 + cq) * 128 + d) * 128 + t4] = u;
            }
            __syncthreads();
        }
        return;
    }

    // ---- gate tile: sigmoid -> gatebuf ----
    int cb = (bn - QKV_N) + wn * 128;
    int rb = bm + wm * 64;
#pragma unroll
    for (int i = 0; i < 4; ++i)
#pragma unroll
        for (int j = 0; j < 8; ++j) {
            int col = cb + j * 16 + lane15;
#pragma unroll
            for (int r = 0; r < 4; ++r) {
                float v = 1.0f / (1.0f + __expf(-acc[i][j][r]));
                gate[(size_t)(rb + i * 16 + quad * 4 + r) * HID_C + col] = f2bfu(v);
            }
        }
}

// ---- dense GEMM: fp32 out. BM=128 x BN=128, 256 thr, 64 KiB LDS (512 blocks, 2 blocks/CU) ----
__global__ __launch_bounds__(256, 2) void gemm_dense(const ushort* __restrict__ A,
                                                     const ushort* __restrict__ Bt,
                                                     float* __restrict__ Cout, int N, int K) {
    __shared__ ushort sh[32768];           // 64 KiB
    // GM=32 x GN=16 tiles; each XCD owns an 8m x 8n region (n-fastest inside)
    int bid = blockIdx.x;
    int x = bid & 7, w = bid >> 3;
    int rm = x >> 1, rn = x & 1;           // 4 x 2 regions
    int wm_i = w >> 3, wn_i = w & 7;       // 8 x 8 blocks inside region
    int bm = (rm * 8 + wm_i) * 128;
    int bn = (rn * 8 + wn_i) * 128;
    f32x4 acc[4][4] = {};
    gemm4_core(A, Bt, K, bm, bn, sh, acc);

    int lane = threadIdx.x & 63, wave = threadIdx.x >> 6;
    int lane15 = lane & 15, quad = lane >> 4;
    int wm = wave >> 1, wn = wave & 1;
    int cb = bn + wn * 64;
    int rb = bm + wm * 64;
#pragma unroll
    for (int i = 0; i < 4; ++i)
#pragma unroll
        for (int j = 0; j < 4; ++j) {
            int col = cb + j * 16 + lane15;
#pragma unroll
            for (int r = 0; r < 4; ++r)
                Cout[(size_t)(rb + i * 16 + quad * 4 + r) * N + col] = acc[i][j][r];
        }
}

// ------- per-chunk partial state (transposed, bf16): PT[c,h][v][d] = sum_j lam^(127-j) v_j[v] k_j[d] -------
__global__ __launch_bounds__(256) void chunk_partial(const ushort* __restrict__ kT,
                                                     const ushort* __restrict__ vT,
                                                     ushort* __restrict__ PT) {
    int c = blockIdx.x, h = blockIdx.y;
    float slope = head_slope(h);
    float lam_inv = __expf(-slope);
    int tid = threadIdx.x, lane = tid & 63, wave = tid >> 6;
    int lane15 = lane & 15, quad = lane >> 4;
    int wv = (wave & 1) * 64, wd = (wave >> 1) * 64;
    // chunk-tiled layout: slab (h,c) is contiguous [128 d][128 t]
    const ushort* vbase = vT + ((size_t)(h * 32 + c) * 128) * 128;
    const ushort* kbase = kT + ((size_t)(h * 32 + c) * 128) * 128;
    f32x4 acc[4][4] = {};
#pragma unroll
    for (int j0 = 0; j0 < 128; j0 += 32) {
        float w8[8];
        w8[0] = __expf(slope * (float)(127 - (j0 + quad * 8)));
#pragma unroll
        for (int kk = 1; kk < 8; ++kk) w8[kk] = w8[kk - 1] * lam_inv;
        bf16x8 afr[4], bfr[4];
#pragma unroll
        for (int i = 0; i < 4; ++i) {
            bf16x8 v = *(const bf16x8*)&vbase[(size_t)(wv + i * 16 + lane15) * 128 + j0 + quad * 8];
#pragma unroll
            for (int kk = 0; kk < 8; ++kk) afr[i][kk] = (__bf16)((float)v[kk] * w8[kk]);
        }
#pragma unroll
        for (int j = 0; j < 4; ++j)
            bfr[j] = *(const bf16x8*)&kbase[(size_t)(wd + j * 16 + lane15) * 128 + j0 + quad * 8];
#pragma unroll
        for (int i = 0; i < 4; ++i)
#pragma unroll
            for (int j = 0; j < 4; ++j)
                acc[i][j] = __builtin_amdgcn_mfma_f32_16x16x32_bf16(afr[i], bfr[j], acc[i][j], 0, 0, 0);
    }
    ushort* out = PT + ((size_t)c * 16 + h) * 16384;
#pragma unroll
    for (int i = 0; i < 4; ++i)
#pragma unroll
        for (int j = 0; j < 4; ++j)
#pragma unroll
            for (int r = 0; r < 4; ++r)
                out[(size_t)(wv + i * 16 + quad * 4 + r) * 128 + wd + j * 16 + lane15] = f2bfu(acc[i][j][r]);
}

// ------- sequential scan over 32 chunks: PT (bf16) -> Spb (bf16 prefix states) + Sfin -------
__global__ __launch_bounds__(128) void scan_states(const ushort* __restrict__ PT,
                                                   const float* __restrict__ S0,
                                                   ushort* __restrict__ Spb,
                                                   float* __restrict__ Sfin) {
    int hv = blockIdx.x;              // h*128 + v
    int d = threadIdx.x;              // k-dim
    int h = hv >> 7, v = hv & 127;
    float lamC = __expf(head_slope(h) * 128.0f);
    float s = S0[(size_t)h * 16384 + d * 128 + v];
#pragma unroll
    for (int c = 0; c < 32; ++c) {
        size_t idx = ((size_t)c * 2048 + hv) * 128 + d;
        Spb[idx] = f2bfu(s);          // state BEFORE chunk c, layout [c][h][v][d]
        s = s * lamC + bfu2f(PT[idx]);
    }
    Sfin[(size_t)h * 16384 + d * 128 + v] = s;
}

// ------- per-chunk output: QK^T (masked/decayed) * V + lam^(t+1) * Q * S_prev -------
__global__ __launch_bounds__(256) void chunk_out(const ushort* __restrict__ qkv,
                                                 const ushort* __restrict__ vT,
                                                 const ushort* __restrict__ Spb,
                                                 ushort* __restrict__ o) {
    int c = blockIdx.x, h = blockIdx.y;
    float slope = head_slope(h);
    __shared__ ushort Ps[128 * 136];   // padded: row stride 272B -> conflict-free b128
    int tid = threadIdx.x, lane = tid & 63, wave = tid >> 6;
    int lane15 = lane & 15, quad = lane >> 4;
    int t0 = c * 128;
    int tt0 = wave, tt1 = 7 - wave;    // owned t-tiles (balanced triangular split)
    const ushort* qbase = qkv + (size_t)t0 * QKV_N + h * 128;
    const ushort* kbase = qbase + 2048;

    bf16x8 qf0[4], qf1[4];
#pragma unroll
    for (int ds = 0; ds < 4; ++ds) {
        qf0[ds] = *(const bf16x8*)&qbase[(size_t)(tt0 * 16 + lane15) * QKV_N + ds * 32 + quad * 8];
        qf1[ds] = *(const bf16x8*)&qbase[(size_t)(tt1 * 16 + lane15) * QKV_N + ds * 32 + quad * 8];
    }
    // ---- phase 1: scores ----
    f32x4 s0a[4] = {};
    f32x4 s1a[8] = {};
#pragma unroll
    for (int st = 0; st < 8; ++st) {
        if (st <= tt1) {
            bf16x8 kf[4];
#pragma unroll
            for (int ds = 0; ds < 4; ++ds)
                kf[ds] = *(const bf16x8*)&kbase[(size_t)(st * 16 + lane15) * QKV_N + ds * 32 + quad * 8];
#pragma unroll
            for (int ds = 0; ds < 4; ++ds)
                s1a[st] = __builtin_amdgcn_mfma_f32_16x16x32_bf16(qf1[ds], kf[ds], s1a[st], 0, 0, 0);
            if (st <= tt0) {
#pragma unroll
                for (int ds = 0; ds < 4; ++ds)
                    s0a[st] = __builtin_amdgcn_mfma_f32_16x16x32_bf16(qf0[ds], kf[ds], s0a[st], 0, 0, 0);
            }
        }
    }
    // ---- park masked/decayed scores (zero strip pads odd 16-blocks to 32) ----
    int stmax0 = tt0 + ((tt0 & 1) ? 0 : 1);
    int stmax1 = tt1 + ((tt1 & 1) ? 0 : 1);
#pragma unroll
    for (int st = 0; st < 8; ++st) {
        if (st <= stmax1) {
#pragma unroll
            for (int r = 0; r < 4; ++r) {
                int t = tt1 * 16 + quad * 4 + r;
                int s = st * 16 + lane15;
                float val = 0.f;
                if (st <= tt1) val = (s <= t) ? s1a[st][r] * __expf(slope * (float)(t - s)) : 0.f;
                Ps[t * 136 + s] = f2bfu(val);
            }
        }
    }
#pragma unroll
    for (int st = 0; st < 5; ++st) {
        if (st <= stmax0) {
#pragma unroll
            for (int r = 0; r < 4; ++r) {
                int t = tt0 * 16 + quad * 4 + r;
                int s = st * 16 + lane15;
                float val = 0.f;
                if (st <= tt0) val = (s <= t) ? s0a[st][r] * __expf(slope * (float)(t - s)) : 0.f;
                Ps[t * 136 + s] = f2bfu(val);
            }
        }
    }
    __syncthreads();
    // ---- phase 2: O = P*V + diag(lam^(t+1)) Q*S_prev ----
    f32x4 oa0[8] = {};
    f32x4 oa1[8] = {};
    float lam0 = __expf(slope * (float)(tt0 * 16 + lane15 + 1));
    float lam1 = __expf(slope * (float)(tt1 * 16 + lane15 + 1));
    bf16x8 qs0[4], qs1[4];
#pragma unroll
    for (int ds = 0; ds < 4; ++ds)
#pragma unroll
        for (int kk = 0; kk < 8; ++kk) {
            qs0[ds][kk] = (__bf16)((float)qf0[ds][kk] * lam0);
            qs1[ds][kk] = (__bf16)((float)qf1[ds][kk] * lam1);
        }
    const ushort* spb = Spb + ((size_t)c * 2048 + h * 128) * 128;
#pragma unroll
    for (int vt = 0; vt < 8; ++vt)
#pragma unroll
        for (int ds = 0; ds < 4; ++ds) {
            bf16x8 bfrag = *(const bf16x8*)&spb[(vt * 16 + lane15) * 128 + ds * 32 + quad * 8];
            oa0[vt] = __builtin_amdgcn_mfma_f32_16x16x32_bf16(qs0[ds], bfrag, oa0[vt], 0, 0, 0);
            oa1[vt] = __builtin_amdgcn_mfma_f32_16x16x32_bf16(qs1[ds], bfrag, oa1[vt], 0, 0, 0);
        }
    // chunk-tiled layout: slab (h,c) contiguous [128 d][128 t]
    const ushort* vbase = vT + ((size_t)(h * 32 + c) * 128) * 128;
    int ns0 = (tt0 + 2) >> 1, ns1 = (tt1 + 2) >> 1;
#pragma unroll
    for (int s32 = 0; s32 < 4; ++s32) {
        if (s32 < ns1) {
            bf16x8 af = *(const bf16x8*)&Ps[(tt1 * 16 + lane15) * 136 + s32 * 32 + quad * 8];
#pragma unroll
            for (int vt = 0; vt < 8; ++vt) {
                bf16x8 bfrag = *(const bf16x8*)&vbase[(size_t)(vt * 16 + lane15) * 128 + s32 * 32 + quad * 8];
                oa1[vt] = __builtin_amdgcn_mfma_f32_16x16x32_bf16(af, bfrag, oa1[vt], 0, 0, 0);
            }
        }
    }
#pragma unroll
    for (int s32 = 0; s32 < 2; ++s32) {
        if (s32 < ns0) {
            bf16x8 af = *(const bf16x8*)&Ps[(tt0 * 16 + lane15) * 136 + s32 * 32 + quad * 8];
#pragma unroll
            for (int vt = 0; vt < 8; ++vt) {
                bf16x8 bfrag = *(const bf16x8*)&vbase[(size_t)(vt * 16 + lane15) * 128 + s32 * 32 + quad * 8];
                oa0[vt] = __builtin_amdgcn_mfma_f32_16x16x32_bf16(af, bfrag, oa0[vt], 0, 0, 0);
            }
        }
    }
    // ---- epilogue (bf16) ----
#pragma unroll
    for (int vt = 0; vt < 8; ++vt)
#pragma unroll
        for (int r = 0; r < 4; ++r) {
            o[(size_t)(t0 + tt0 * 16 + quad * 4 + r) * 2048 + h * 128 + vt * 16 + lane15] = f2bfu(oa0[vt][r]);
            o[(size_t)(t0 + tt1 * 16 + quad * 4 + r) * 2048 + h * 128 + vt * 16 + lane15] = f2bfu(oa1[vt][r]);
        }
}

// ---------------- group RMS-norm * g_norm_w * sigmoid-gate -> bf16 ----------------
__global__ __launch_bounds__(256) void gnorm_gate(const ushort* __restrict__ o,
                                                  const ushort* __restrict__ gate,
                                                  const float* __restrict__ gw,
                                                  ushort* __restrict__ gg) {
    int t = blockIdx.x;
    int tid = threadIdx.x;
    const ushort* op = o + (size_t)t * 2048 + tid * 8;
    bf16x8 xv = *(const bf16x8*)op;
    float x[8];
    float ss = 0.0f;
#pragma unroll
    for (int i = 0; i < 8; ++i) { x[i] = (float)xv[i]; ss += x[i] * x[i]; }
#pragma unroll
    for (int off = 16; off > 0; off >>= 1) ss += __shfl_xor(ss, off);  // 32-thread group = 256 elems
    float r = rsqrtf(ss * (1.0f / 256.0f) + 1e-6f);
    const ushort* gp = gate + (size_t)t * 2048;
#pragma unroll
    for (int i = 0; i < 8; ++i) {
        int j = tid * 8 + i;
        float val = x[i] * r * gw[j] * bfu2f(gp[j]);
        gg[(size_t)t * 2048 + j] = f2bfu(val);
    }
}

extern "C" void kernel_launch(void* const* d_in, const int* in_sizes, int n_in,
                              void* d_out, int out_size, void* d_ws, size_t ws_size,
                              hipStream_t stream) {
    const int* positions   = (const int*)d_in[0];
    const float* hidden    = (const float*)d_in[1];
    const float* S0        = (const float*)d_in[2];
    const float* w_qkv     = (const float*)d_in[3];
    const float* w_g       = (const float*)d_in[4];
    const float* w_dense   = (const float*)d_in[5];
    const float* qw        = (const float*)d_in[6];
    const float* kw        = (const float*)d_in[7];
    const float* gw        = (const float*)d_in[8];

    char* ws = (char*)d_ws;
    ushort* qkv     = (ushort*)ws;                    // bf16 T x 6144            [0, 50331648)
    ushort* wqkv_t  = (ushort*)(ws + 50331648);       // bf16 6144 x 2048 (25.2M) — Bcat rows 0..6143
    ushort* wg_t    = (ushort*)(ws + 75497472);       // bf16 2048 x 2048 (8.4M)  — Bcat rows 6144..8191
    float2* ropet   = (float2*)(ws + 159383552);      // 1 MB — separate region
    ushort* PT      = (ushort*)(ws + 50331648);       // bf16 32x16x128x128 (16.8M) — aliases wqkv_t (dead)
    ushort* wd_t    = (ushort*)(ws + 83886080);       // bf16 2048 x 2048 (8.4M)
    ushort* gatebuf = (ushort*)(ws + 92274688);       // bf16 T x 2048 (16.8M)
    ushort* hid_b   = (ushort*)(ws + 109051904);      // bf16 T x 2048 (16.8M)
    ushort* Spb     = (ushort*)(ws + 109051904);      // bf16 32x16x128x128 (16.8M) — aliases hid_b (dead)
    ushort* kT      = (ushort*)(ws + 125829120);      // bf16 [16][32][128][128] (16.8M) chunk-tiled
    ushort* vT      = (ushort*)(ws + 142606336);      // bf16 [16][32][128][128] (16.8M) chunk-tiled
    ushort* gg      = (ushort*)ws;                    // aliases qkv (dead by gnorm time)  total 160,432,128

    float* out  = (float*)d_out;
    float* Sfin = out + (size_t)T_SEQ * HID_C;
    ushort* obuf = (ushort*)d_out;                    // out-region doubles as bf16 attn scratch

    // one launch: cvt + 3 transposes + rope table (all independent preprocessing)
    prep_all<<<9728, 256, 0, stream>>>(hidden, hid_b, w_qkv, wqkv_t, w_g, wg_t,
                                       w_dense, wd_t, positions, ropet);

    // 256x256 tiles: 512 blocks of 512 threads (waves 4Mx2N -> wave-local norm/rope epilogue)
    gemm_fused<<<dim3(512), 512, 0, stream>>>(hid_b, wqkv_t, qkv, gatebuf, kT, vT,
                                              ropet, qw, kw, HID_C);

    chunk_partial<<<dim3(32, 16), 256, 0, stream>>>(kT, vT, PT);
    scan_states<<<2048, 128, 0, stream>>>(PT, S0, Spb, Sfin);
    chunk_out<<<dim3(32, 16), 256, 0, stream>>>(qkv, vT, Spb, obuf);
    gnorm_gate<<<T_SEQ, 256, 0, stream>>>(obuf, gatebuf, gw, gg);

    // 128x128 tiles: (4096/128)*(2048/128) = 32*16 = 512 blocks of 256 thr, 2 blocks/CU
    gemm_dense<<<dim3(512), 256, 0, stream>>>(gg, wd_t, out, HID_C, HID_C);
}

// Round 13
// 376.778 us; speedup vs baseline: 1.1674x; 1.0324x over previous
//
#include <hip/hip_runtime.h>
#include <hip/hip_bf16.h>

using bf16x8 = __attribute__((ext_vector_type(8))) __bf16;
using f32x4  = __attribute__((ext_vector_type(4))) float;

constexpr int T_SEQ = 4096;
constexpr int HID_C = 2048;
constexpr int NH    = 16;
constexpr int QKV_N = 6144;

__device__ __forceinline__ float head_slope(int h) {
    // slope[h] = -2^{-(h+1)/2} * (1 - 1/31 + 1e-5)
    return -exp2f(-0.5f * (float)(h + 1)) * 0.967751935483871f;
}

__device__ __forceinline__ ushort f2bfu(float f) {
    __hip_bfloat16 h = __float2bfloat16(f);
    return *(ushort*)&h;
}
__device__ __forceinline__ float bfu2f(ushort u) {
    union { unsigned int i; float f; } x; x.i = ((unsigned int)u) << 16; return x.f;
}

// async global -> LDS, 16 bytes per lane; LDS dest = wave-uniform base + lane*16
__device__ __forceinline__ void async16(const ushort* g, ushort* l) {
    __builtin_amdgcn_global_load_lds((const __attribute__((address_space(1))) void*)g,
                                     (__attribute__((address_space(3))) void*)l, 16, 0, 0);
}

template<int N> __device__ __forceinline__ void waitcnt_vm() {
    if constexpr (N == 0)      asm volatile("s_waitcnt vmcnt(0)" ::: "memory");
    else if constexpr (N == 2) asm volatile("s_waitcnt vmcnt(2)" ::: "memory");
    else if constexpr (N == 4) asm volatile("s_waitcnt vmcnt(4)" ::: "memory");
    else if constexpr (N == 6) asm volatile("s_waitcnt vmcnt(6)" ::: "memory");
}

// ============ merged preprocessing: cvt_bf16 + 3x transpose_cvt + rope_tab in ONE launch ============
__device__ __forceinline__ void cvt_body(const float* __restrict__ src, ushort* __restrict__ dst,
                                         int bid, int tid) {
    int i = (bid * 256 + tid) * 8;
    float4 a = *(const float4*)(src + i);
    float4 b = *(const float4*)(src + i + 4);
    ushort4 ua = {f2bfu(a.x), f2bfu(a.y), f2bfu(a.z), f2bfu(a.w)};
    ushort4 ub = {f2bfu(b.x), f2bfu(b.y), f2bfu(b.z), f2bfu(b.w)};
    *(ushort4*)(dst + i) = ua;
    *(ushort4*)(dst + i + 4) = ub;
}

__device__ __forceinline__ void transpose_body(const float* __restrict__ src,
                                               ushort* __restrict__ dst,
                                               int R, int C, int bx, int by, int t,
                                               ushort (*tile)[68]) {
    int tr = by * 64, tc = bx * 64;
    int r0 = t >> 4;
    int c4 = (t & 15) << 2;
#pragma unroll
    for (int p = 0; p < 4; ++p) {
        int row = r0 + p * 16;
        float4 v = *(const float4*)&src[(size_t)(tr + row) * C + tc + c4];
        tile[row][c4 + 0] = f2bfu(v.x);
        tile[row][c4 + 1] = f2bfu(v.y);
        tile[row][c4 + 2] = f2bfu(v.z);
        tile[row][c4 + 3] = f2bfu(v.w);
    }
    __syncthreads();
#pragma unroll
    for (int p = 0; p < 4; ++p) {
        int orow = r0 + p * 16;
        ushort4 u;
        u.x = tile[c4 + 0][orow];
        u.y = tile[c4 + 1][orow];
        u.z = tile[c4 + 2][orow];
        u.w = tile[c4 + 3][orow];
        *(ushort4*)&dst[(size_t)(tc + orow) * R + tr + c4] = u;
    }
}

// grid: [0,4096) cvt | [4096,7168) w_qkv T | [7168,8192) w_g T | [8192,9216) w_dense T | [9216,9728) rope
__global__ __launch_bounds__(256) void prep_all(const float* __restrict__ hidden,
                                                ushort* __restrict__ hid_b,
                                                const float* __restrict__ w_qkv,
                                                ushort* __restrict__ wqkv_t,
                                                const float* __restrict__ w_g,
                                                ushort* __restrict__ wg_t,
                                                const float* __restrict__ w_dense,
                                                ushort* __restrict__ wd_t,
                                                const int* __restrict__ positions,
                                                float2* __restrict__ ropet) {
    __shared__ ushort tile[64][68];
    int b = blockIdx.x, t = threadIdx.x;
    if (b < 4096) {
        cvt_body(hidden, hid_b, b, t);
    } else if (b < 7168) {
        int bb = b - 4096;                       // 96 x 32 tiles
        transpose_body(w_qkv, wqkv_t, HID_C, QKV_N, bb % 96, bb / 96, t, tile);
    } else if (b < 8192) {
        int bb = b - 7168;                       // 32 x 32
        transpose_body(w_g, wg_t, HID_C, HID_C, bb % 32, bb / 32, t, tile);
    } else if (b < 9216) {
        int bb = b - 8192;                       // 32 x 32
        transpose_body(w_dense, wd_t, HID_C, HID_C, bb % 32, bb / 32, t, tile);
    } else {
        int i = (b - 9216) * 256 + t;            // i < T*32
        int tt = i >> 5, fi = i & 31;
        float inv = expf((float)fi * -0.2878231366f);   // ln(10000)/32
        float freq = (float)positions[tt] * inv;
        float sn, cs;
        sincosf(freq, &sn, &cs);
        ropet[i] = make_float2(cs, sn);
    }
}

// ============== 256x256 flat-K-tile MFMA GEMM core, waves 4M x 2N (BK=64, 8 waves, dbuf LDS) ==============
// Per-wave output: 64 rows x 128 cols (ONE FULL HEAD of q/k/v) -> epilogue norm/rope is wave-local.
__device__ __forceinline__ void gemm8w_core(const ushort* __restrict__ Ag,
                                            const ushort* __restrict__ Bg,
                                            int K, int bm, int bn,
                                            ushort* sh, f32x4 (&acc)[4][8]) {
    const int tid  = threadIdx.x;
    const int lane = tid & 63;
    const int wave = tid >> 6;
    const int lane15 = lane & 15, quad = lane >> 4;
    const int wm = wave >> 1, wn = wave & 1;   // 4M x 2N
    const int swz = lane15 & 7;

    ushort* const ldsA0 = sh;              // [256][64] bf16, rows swizzled: phys grp p of row r = logical p^(r&7)
    ushort* const ldsA1 = sh + 16384;
    ushort* const ldsB0 = sh + 32768;      // [256][64]
    ushort* const ldsB1 = sh + 49152;

    // staging: lane l covers row (l>>3) of an 8-row chunk, physical 16B group (l&7),
    // so it must READ logical group (l&7)^(l>>3)  (involution: same xor on the read side)
    const int srow = lane >> 3;
    const int scol = ((lane & 7) ^ srow) << 3;
    const ushort* gA = Ag + (size_t)(bm + srow) * K + scol;
    const ushort* gB = Bg + (size_t)(bn + srow) * K + scol;
    const int ro = wave * 16;              // each wave stages 2x 8-row chunks per half-tile
    const int NT = K >> 6;

#define STAGE8(L, g, k0) do { \
    _Pragma("unroll") for (int h = 0; h < 2; ++h) \
    _Pragma("unroll") for (int q = 0; q < 2; ++q) \
        async16((g) + (size_t)((h) * 128 + ro + q * 8) * K + (k0), (L) + ((h) * 128 + ro + q * 8) * 64); } while (0)

    // prologue: tile0 -> buf0
    STAGE8(ldsA0, gA, 0);
    STAGE8(ldsB0, gB, 0);
    waitcnt_vm<0>();
    asm volatile("s_barrier" ::: "memory");

    for (int t = 0; t < NT; ++t) {
        const ushort* LA = (t & 1) ? ldsA1 : ldsA0;
        const ushort* LB = (t & 1) ? ldsB1 : ldsB0;
        ushort* LAn = (t & 1) ? ldsA0 : ldsA1;
        ushort* LBn = (t & 1) ? ldsB0 : ldsB1;
        // ---- all A-frags + first B-half (compiler inserts counted lgkm waits) ----
        bf16x8 af[4][2];
#pragma unroll
        for (int i = 0; i < 4; ++i)
#pragma unroll
            for (int ks = 0; ks < 2; ++ks)
                af[i][ks] = *(const bf16x8*)&LA[(wm * 64 + i * 16 + lane15) * 64 + (((ks * 4 + quad) ^ swz) << 3)];
        bf16x8 bf0[4][2];
#pragma unroll
        for (int j = 0; j < 4; ++j)
#pragma unroll
            for (int ks = 0; ks < 2; ++ks)
                bf0[j][ks] = *(const bf16x8*)&LB[(wn * 128 + j * 16 + lane15) * 64 + (((ks * 4 + quad) ^ swz) << 3)];
        // ---- stage tile t+1 into the other buffers (WAR-safe) ----
        if (t + 1 < NT) {
            STAGE8(LAn, gA, (t + 1) << 6);
            STAGE8(LBn, gB, (t + 1) << 6);
        }
        __builtin_amdgcn_s_setprio(1);
#pragma unroll
        for (int i = 0; i < 4; ++i)
#pragma unroll
            for (int j = 0; j < 4; ++j)
#pragma unroll
                for (int ks = 0; ks < 2; ++ks)
                    acc[i][j] = __builtin_amdgcn_mfma_f32_16x16x32_bf16(af[i][ks], bf0[j][ks], acc[i][j], 0, 0, 0);
        __builtin_amdgcn_s_setprio(0);
        // ---- second B-half: reads overlap first MFMA cluster ----
        bf16x8 bf1[4][2];
#pragma unroll
        for (int j = 0; j < 4; ++j)
#pragma unroll
            for (int ks = 0; ks < 2; ++ks)
                bf1[j][ks] = *(const bf16x8*)&LB[(wn * 128 + (4 + j) * 16 + lane15) * 64 + (((ks * 4 + quad) ^ swz) << 3)];
        __builtin_amdgcn_s_setprio(1);
#pragma unroll
        for (int i = 0; i < 4; ++i)
#pragma unroll
            for (int j = 0; j < 4; ++j)
#pragma unroll
                for (int ks = 0; ks < 2; ++ks)
                    acc[i][4 + j] = __builtin_amdgcn_mfma_f32_16x16x32_bf16(af[i][ks], bf1[j][ks], acc[i][4 + j], 0, 0, 0);
        __builtin_amdgcn_s_setprio(0);
        // t+1 staging landed long ago (issued ~2500cyc back); drain + handoff
        waitcnt_vm<0>();
        asm volatile("s_barrier" ::: "memory");
    }
#undef STAGE8
}

// ============== 128x128 flat-K-tile core: 4 waves, 64 KiB LDS (for the dense GEMM) ==============
__device__ __forceinline__ void gemm4_core(const ushort* __restrict__ Ag,
                                           const ushort* __restrict__ Bg,
                                           int K, int bm, int bn,
                                           ushort* sh, f32x4 (&acc)[4][4]) {
    const int tid  = threadIdx.x;
    const int lane = tid & 63;
    const int wave = tid >> 6;             // 4 waves: 2M x 2N
    const int lane15 = lane & 15, quad = lane >> 4;
    const int wm = wave >> 1, wn = wave & 1;
    const int swz = lane15 & 7;

    ushort* const ldsA0 = sh;              // [128][64]
    ushort* const ldsA1 = sh + 8192;
    ushort* const ldsB0 = sh + 16384;
    ushort* const ldsB1 = sh + 24576;

    const int srow = lane >> 3;
    const int scol = ((lane & 7) ^ srow) << 3;
    const ushort* gA = Ag + (size_t)(bm + srow) * K + scol;
    const ushort* gB = Bg + (size_t)(bn + srow) * K + scol;
    const int ro = wave * 32;              // each wave stages 4x 8-row chunks (128 rows / 4 waves)
    const int NT = K >> 6;

#define STG(L, g, k0) do { \
    _Pragma("unroll") for (int q = 0; q < 4; ++q) \
        async16((g) + (size_t)(ro + q * 8) * K + (k0), (L) + (ro + q * 8) * 64); } while (0)

    STG(ldsA0, gA, 0);
    STG(ldsB0, gB, 0);
    waitcnt_vm<0>();
    asm volatile("s_barrier" ::: "memory");

    for (int t = 0; t < NT; ++t) {
        const ushort* LA = (t & 1) ? ldsA1 : ldsA0;
        const ushort* LB = (t & 1) ? ldsB1 : ldsB0;
        ushort* LAn = (t & 1) ? ldsA0 : ldsA1;
        ushort* LBn = (t & 1) ? ldsB0 : ldsB1;
        bf16x8 bfr[4][2];
#pragma unroll
        for (int j = 0; j < 4; ++j)
#pragma unroll
            for (int ks = 0; ks < 2; ++ks)
                bfr[j][ks] = *(const bf16x8*)&LB[(wn * 64 + j * 16 + lane15) * 64 + (((ks * 4 + quad) ^ swz) << 3)];
        bf16x8 af[4][2];
#pragma unroll
        for (int i = 0; i < 4; ++i)
#pragma unroll
            for (int ks = 0; ks < 2; ++ks)
                af[i][ks] = *(const bf16x8*)&LA[(wm * 64 + i * 16 + lane15) * 64 + (((ks * 4 + quad) ^ swz) << 3)];
        if (t + 1 < NT) {
            STG(LAn, gA, (t + 1) << 6);
            STG(LBn, gB, (t + 1) << 6);
        }
        __builtin_amdgcn_s_setprio(1);
#pragma unroll
        for (int i = 0; i < 4; ++i)
#pragma unroll
            for (int j = 0; j < 4; ++j)
#pragma unroll
                for (int ks = 0; ks < 2; ++ks)
                    acc[i][j] = __builtin_amdgcn_mfma_f32_16x16x32_bf16(af[i][ks], bfr[j][ks], acc[i][j], 0, 0, 0);
        __builtin_amdgcn_s_setprio(0);
        waitcnt_vm<0>();
        asm volatile("s_barrier" ::: "memory");
    }
#undef STG
}

// ---- fused qkv+gate GEMM + q/k RMSNorm+RoPE + k/v chunk-tiled transpose, all in-epilogue ----
// waves 4Mx2N: each wave owns 64 rows x 1 full head -> norm/rope wave-local (no LDS exchange).
// tiles: bn<2048 q | [2048,4096) k | [4096,6144) v | >=6144 gate.
__global__ __launch_bounds__(512, 2) void gemm_fused(const ushort* __restrict__ A,
                                                     const ushort* __restrict__ Bcat,
                                                     ushort* __restrict__ qkv,
                                                     ushort* __restrict__ gate,
                                                     ushort* __restrict__ kT,
                                                     ushort* __restrict__ vT,
                                                     const float2* __restrict__ tab,
                                                     const float* __restrict__ qw,
                                                     const float* __restrict__ kw, int K) {
    __shared__ ushort sh[65536];           // 128 KiB: GEMM dbuf; epilogue reuses (post-final-barrier)
    // 2D-chunked XCD swizzle: GM=16 x GN=32 tiles; each XCD owns an 8m x 8n region (n-fastest inside)
    int bid = blockIdx.x;
    int x = bid & 7, w = bid >> 3;
    int rm = x >> 2, rn = x & 3;
    int wm_i = w >> 3, wn_i = w & 7;
    int bm = (rm * 8 + wm_i) * 256;
    int bn = (rn * 8 + wn_i) * 256;
    f32x4 acc[4][8] = {};
    gemm8w_core(A, Bcat, K, bm, bn, sh, acc);

    int lane = threadIdx.x & 63, wave = threadIdx.x >> 6;
    int lane15 = lane & 15, quad = lane >> 4;
    int wm = wave >> 1, wn = wave & 1;     // 4M x 2N
    constexpr int S = 132;                 // padded t-stride for transpose slabs

    if (bn < 4096) {
        // ========== q/k tile: wave-local RMSNorm + RoPE ==========
        bool isq = bn < 2048;
        const float* wnorm = isq ? qw : kw;
        float w8a[8];
#pragma unroll
        for (int j = 0; j < 8; ++j) w8a[j] = wnorm[j * 16 + lane15];
        float sc = isq ? 0.08838834764831845f : 1.0f;   // 128^-0.5 on q
        int rowbase = bm + wm * 64;
#pragma unroll
        for (int i = 0; i < 4; ++i)
#pragma unroll
            for (int r = 0; r < 4; ++r) {
                float s2 = 0.f;
#pragma unroll
                for (int j = 0; j < 8; ++j) { float xv = acc[i][j][r]; s2 += xv * xv; }
                s2 += __shfl_xor(s2, 1);
                s2 += __shfl_xor(s2, 2);
                s2 += __shfl_xor(s2, 4);
                s2 += __shfl_xor(s2, 8);
                float rr = rsqrtf(s2 * (1.0f / 128.0f) + 1e-6f);
                float xx[8];
#pragma unroll
                for (int j = 0; j < 8; ++j) xx[j] = acc[i][j][r] * rr * w8a[j];
                // rope: d = j*16+lane15; pairs (j, j+2) for j=0,1; fi = d
                int t = rowbase + i * 16 + quad * 4 + r;
                float2 rt0 = tab[t * 32 + lane15];
                float2 rt1 = tab[t * 32 + 16 + lane15];
                float a0 = xx[0], b0 = xx[2], a1 = xx[1], b1 = xx[3];
                xx[0] = a0 * rt0.x - b0 * rt0.y;
                xx[2] = b0 * rt0.x + a0 * rt0.y;
                xx[1] = a1 * rt1.x - b1 * rt1.y;
                xx[3] = b1 * rt1.x + a1 * rt1.y;
#pragma unroll
                for (int j = 0; j < 8; ++j) acc[i][j][r] = xx[j] * sc;
            }
        // row-major write
#pragma unroll
        for (int i = 0; i < 4; ++i)
#pragma unroll
            for (int j = 0; j < 8; ++j) {
                int col = bn + wn * 128 + j * 16 + lane15;
#pragma unroll
                for (int r = 0; r < 4; ++r)
                    qkv[(size_t)(rowbase + i * 16 + quad * 4 + r) * QKV_N + col] = f2bfu(acc[i][j][r]);
            }
        if (!isq) {
            // ---- k: additionally transpose into chunk-tiled kT[h][c][128 d][128 t] ----
            ushort* L = sh;                // slabs [wn][128 d][S]
            int h0 = (bn - 2048) >> 7;     // head of wn=0
            int c0 = bm >> 7;
#pragma unroll
            for (int cq = 0; cq < 2; ++cq) {
                if ((wm >> 1) == cq) {     // waves holding rows cq*128..+127
#pragma unroll
                    for (int i = 0; i < 4; ++i)
#pragma unroll
                        for (int j = 0; j < 8; ++j) {
                            int d_local = j * 16 + lane15;
#pragma unroll
                            for (int r = 0; r < 4; ++r) {
                                int t_local = (wm & 1) * 64 + i * 16 + quad * 4 + r;
                                L[wn * 128 * S + d_local * S + t_local] = f2bfu(acc[i][j][r]);
                            }
                        }
                }
                __syncthreads();
#pragma unroll
                for (int p = 0; p < 16; ++p) {
                    int lin = (p * 512 + threadIdx.x) * 4;
                    int hq2 = lin >> 14;
                    int wi = lin & 16383;
                    int d = wi >> 7, t4 = wi & 127;
                    const ushort* lp = &L[hq2 * 128 * S + d * S + t4];
                    ushort4 u = { lp[0], lp[1], lp[2], lp[3] };
                    *(ushort4*)&kT[((size_t)((h0 + hq2) * 32 + c0 + cq) * 128 + d) * 128 + t4] = u;
                }
                __syncthreads();
            }
        }
        return;
    }

    if (bn < QKV_N) {
        // ---- V tile: transpose 256x256 into vT chunk-tiled slabs [h][c][128 d][128 t] ----
        ushort* L = sh;
        int h0 = (bn - 4096) >> 7;
        int c0 = bm >> 7;
#pragma unroll
        for (int cq = 0; cq < 2; ++cq) {
            if ((wm >> 1) == cq) {
#pragma unroll
                for (int i = 0; i < 4; ++i)
#pragma unroll
                    for (int j = 0; j < 8; ++j) {
                        int d_local = j * 16 + lane15;
#pragma unroll
                        for (int r = 0; r < 4; ++r) {
                            int t_local = (wm & 1) * 64 + i * 16 + quad * 4 + r;
                            L[wn * 128 * S + d_local * S + t_local] = f2bfu(acc[i][j][r]);
                        }
                    }
            }
            __syncthreads();
#pragma unroll
            for (int p = 0; p < 16; ++p) {
                int lin = (p * 512 + threadIdx.x) * 4;
                int hq2 = lin >> 14;
                int wi = lin & 16383;
                int d = wi >> 7, t4 = wi & 127;
                const ushort* lp = &L[hq2 * 128 * S + d * S + t4];
                ushort4 u = { lp[0], lp[1], lp[2], lp[3] };
                *(ushort4*)&vT[((size_t)((h0 + hq2) * 32 + c0 + cq) * 128 + d) * 128 + t4] = u;
            }
            __syncthreads();
        }
        return;
    }

    // ---- gate tile: sigmoid -> gatebuf ----
    int cb = (bn - QKV_N) + wn * 128;
    int rb = bm + wm * 64;
#pragma unroll
    for (int i = 0; i < 4; ++i)
#pragma unroll
        for (int j = 0; j < 8; ++j) {
            int col = cb + j * 16 + lane15;
#pragma unroll
            for (int r = 0; r < 4; ++r) {
                float v = 1.0f / (1.0f + __expf(-acc[i][j][r]));
                gate[(size_t)(rb + i * 16 + quad * 4 + r) * HID_C + col] = f2bfu(v);
            }
        }
}

// ---- dense GEMM: fp32 out. BM=128 x BN=128, 256 thr, 64 KiB LDS (512 blocks, 2 blocks/CU) ----
__global__ __launch_bounds__(256, 2) void gemm_dense(const ushort* __restrict__ A,
                                                     const ushort* __restrict__ Bt,
                                                     float* __restrict__ Cout, int N, int K) {
    __shared__ ushort sh[32768];           // 64 KiB
    // GM=32 x GN=16 tiles; each XCD owns an 8m x 8n region (n-fastest inside)
    int bid = blockIdx.x;
    int x = bid & 7, w = bid >> 3;
    int rm = x >> 1, rn = x & 1;           // 4 x 2 regions
    int wm_i = w >> 3, wn_i = w & 7;       // 8 x 8 blocks inside region
    int bm = (rm * 8 + wm_i) * 128;
    int bn = (rn * 8 + wn_i) * 128;
    f32x4 acc[4][4] = {};
    gemm4_core(A, Bt, K, bm, bn, sh, acc);

    int lane = threadIdx.x & 63, wave = threadIdx.x >> 6;
    int lane15 = lane & 15, quad = lane >> 4;
    int wm = wave >> 1, wn = wave & 1;
    int cb = bn + wn * 64;
    int rb = bm + wm * 64;
#pragma unroll
    for (int i = 0; i < 4; ++i)
#pragma unroll
        for (int j = 0; j < 4; ++j) {
            int col = cb + j * 16 + lane15;
#pragma unroll
            for (int r = 0; r < 4; ++r)
                Cout[(size_t)(rb + i * 16 + quad * 4 + r) * N + col] = acc[i][j][r];
        }
}

// ------- per-chunk partial state (transposed, bf16): PT[c,h][v][d] = sum_j lam^(127-j) v_j[v] k_j[d] -------
__global__ __launch_bounds__(256) void chunk_partial(const ushort* __restrict__ kT,
                                                     const ushort* __restrict__ vT,
                                                     ushort* __restrict__ PT) {
    int c = blockIdx.x, h = blockIdx.y;
    float slope = head_slope(h);
    float lam_inv = __expf(-slope);
    int tid = threadIdx.x, lane = tid & 63, wave = tid >> 6;
    int lane15 = lane & 15, quad = lane >> 4;
    int wv = (wave & 1) * 64, wd = (wave >> 1) * 64;
    // chunk-tiled layout: slab (h,c) is contiguous [128 d][128 t]
    const ushort* vbase = vT + ((size_t)(h * 32 + c) * 128) * 128;
    const ushort* kbase = kT + ((size_t)(h * 32 + c) * 128) * 128;
    f32x4 acc[4][4] = {};
#pragma unroll
    for (int j0 = 0; j0 < 128; j0 += 32) {
        float w8[8];
        w8[0] = __expf(slope * (float)(127 - (j0 + quad * 8)));
#pragma unroll
        for (int kk = 1; kk < 8; ++kk) w8[kk] = w8[kk - 1] * lam_inv;
        bf16x8 afr[4], bfr[4];
#pragma unroll
        for (int i = 0; i < 4; ++i) {
            bf16x8 v = *(const bf16x8*)&vbase[(size_t)(wv + i * 16 + lane15) * 128 + j0 + quad * 8];
#pragma unroll
            for (int kk = 0; kk < 8; ++kk) afr[i][kk] = (__bf16)((float)v[kk] * w8[kk]);
        }
#pragma unroll
        for (int j = 0; j < 4; ++j)
            bfr[j] = *(const bf16x8*)&kbase[(size_t)(wd + j * 16 + lane15) * 128 + j0 + quad * 8];
#pragma unroll
        for (int i = 0; i < 4; ++i)
#pragma unroll
            for (int j = 0; j < 4; ++j)
                acc[i][j] = __builtin_amdgcn_mfma_f32_16x16x32_bf16(afr[i], bfr[j], acc[i][j], 0, 0, 0);
    }
    ushort* out = PT + ((size_t)c * 16 + h) * 16384;
#pragma unroll
    for (int i = 0; i < 4; ++i)
#pragma unroll
        for (int j = 0; j < 4; ++j)
#pragma unroll
            for (int r = 0; r < 4; ++r)
                out[(size_t)(wv + i * 16 + quad * 4 + r) * 128 + wd + j * 16 + lane15] = f2bfu(acc[i][j][r]);
}

// ------- sequential scan over 32 chunks: PT (bf16) -> Spb (bf16 prefix states) + Sfin -------
__global__ __launch_bounds__(128) void scan_states(const ushort* __restrict__ PT,
                                                   const float* __restrict__ S0,
                                                   ushort* __restrict__ Spb,
                                                   float* __restrict__ Sfin) {
    int hv = blockIdx.x;              // h*128 + v
    int d = threadIdx.x;              // k-dim
    int h = hv >> 7, v = hv & 127;
    float lamC = __expf(head_slope(h) * 128.0f);
    float s = S0[(size_t)h * 16384 + d * 128 + v];
#pragma unroll
    for (int c = 0; c < 32; ++c) {
        size_t idx = ((size_t)c * 2048 + hv) * 128 + d;
        Spb[idx] = f2bfu(s);          // state BEFORE chunk c, layout [c][h][v][d]
        s = s * lamC + bfu2f(PT[idx]);
    }
    Sfin[(size_t)h * 16384 + d * 128 + v] = s;
}

// ------- per-chunk output (2 heads/block) + FUSED group RMS-norm * g_norm_w * sigmoid-gate -------
// grid (32 c, 8 head-pairs), 512 thr. hh = wave>>2 selects head; wave&3 keeps triangular split.
// Group-norm group (256 elems) = exactly this block's 2 heads -> block-local.
__global__ __launch_bounds__(512) void chunk_out(const ushort* __restrict__ qkv,
                                                 const ushort* __restrict__ vT,
                                                 const ushort* __restrict__ Spb,
                                                 const ushort* __restrict__ gate,
                                                 const float* __restrict__ gw,
                                                 ushort* __restrict__ gg) {
    int c = blockIdx.x, hp = blockIdx.y;
    __shared__ ushort Ps[2 * 128 * 136];   // per-head padded score tiles (conflict-free b128)
    __shared__ float ssb[2 * 128];         // per-head per-row sum of squares
    int tid = threadIdx.x, lane = tid & 63, wave = tid >> 6;
    int lane15 = lane & 15, quad = lane >> 4;
    int hh = wave >> 2, h = hp * 2 + hh;
    int wv4 = wave & 3;
    float slope = head_slope(h);
    int t0 = c * 128;
    int tt0 = wv4, tt1 = 7 - wv4;          // owned t-tiles (balanced triangular split)
    ushort* PsH = Ps + hh * 128 * 136;
    const ushort* qbase = qkv + (size_t)t0 * QKV_N + h * 128;
    const ushort* kbase = qbase + 2048;

    bf16x8 qf0[4], qf1[4];
#pragma unroll
    for (int ds = 0; ds < 4; ++ds) {
        qf0[ds] = *(const bf16x8*)&qbase[(size_t)(tt0 * 16 + lane15) * QKV_N + ds * 32 + quad * 8];
        qf1[ds] = *(const bf16x8*)&qbase[(size_t)(tt1 * 16 + lane15) * QKV_N + ds * 32 + quad * 8];
    }
    // ---- phase 1: scores ----
    f32x4 s0a[4] = {};
    f32x4 s1a[8] = {};
#pragma unroll
    for (int st = 0; st < 8; ++st) {
        if (st <= tt1) {
            bf16x8 kf[4];
#pragma unroll
            for (int ds = 0; ds < 4; ++ds)
                kf[ds] = *(const bf16x8*)&kbase[(size_t)(st * 16 + lane15) * QKV_N + ds * 32 + quad * 8];
#pragma unroll
            for (int ds = 0; ds < 4; ++ds)
                s1a[st] = __builtin_amdgcn_mfma_f32_16x16x32_bf16(qf1[ds], kf[ds], s1a[st], 0, 0, 0);
            if (st <= tt0) {
#pragma unroll
                for (int ds = 0; ds < 4; ++ds)
                    s0a[st] = __builtin_amdgcn_mfma_f32_16x16x32_bf16(qf0[ds], kf[ds], s0a[st], 0, 0, 0);
            }
        }
    }
    // ---- park masked/decayed scores (zero strip pads odd 16-blocks to 32) ----
    int stmax0 = tt0 + ((tt0 & 1) ? 0 : 1);
    int stmax1 = tt1 + ((tt1 & 1) ? 0 : 1);
#pragma unroll
    for (int st = 0; st < 8; ++st) {
        if (st <= stmax1) {
#pragma unroll
            for (int r = 0; r < 4; ++r) {
                int t = tt1 * 16 + quad * 4 + r;
                int s = st * 16 + lane15;
                float val = 0.f;
                if (st <= tt1) val = (s <= t) ? s1a[st][r] * __expf(slope * (float)(t - s)) : 0.f;
                PsH[t * 136 + s] = f2bfu(val);
            }
        }
    }
#pragma unroll
    for (int st = 0; st < 5; ++st) {
        if (st <= stmax0) {
#pragma unroll
            for (int r = 0; r < 4; ++r) {
                int t = tt0 * 16 + quad * 4 + r;
                int s = st * 16 + lane15;
                float val = 0.f;
                if (st <= tt0) val = (s <= t) ? s0a[st][r] * __expf(slope * (float)(t - s)) : 0.f;
                PsH[t * 136 + s] = f2bfu(val);
            }
        }
    }
    __syncthreads();
    // ---- phase 2: O = P*V + diag(lam^(t+1)) Q*S_prev ----
    f32x4 oa0[8] = {};
    f32x4 oa1[8] = {};
    float lam0 = __expf(slope * (float)(tt0 * 16 + lane15 + 1));
    float lam1 = __expf(slope * (float)(tt1 * 16 + lane15 + 1));
    bf16x8 qs0[4], qs1[4];
#pragma unroll
    for (int ds = 0; ds < 4; ++ds)
#pragma unroll
        for (int kk = 0; kk < 8; ++kk) {
            qs0[ds][kk] = (__bf16)((float)qf0[ds][kk] * lam0);
            qs1[ds][kk] = (__bf16)((float)qf1[ds][kk] * lam1);
        }
    const ushort* spb = Spb + ((size_t)c * 2048 + h * 128) * 128;
#pragma unroll
    for (int vt = 0; vt < 8; ++vt)
#pragma unroll
        for (int ds = 0; ds < 4; ++ds) {
            bf16x8 bfrag = *(const bf16x8*)&spb[(vt * 16 + lane15) * 128 + ds * 32 + quad * 8];
            oa0[vt] = __builtin_amdgcn_mfma_f32_16x16x32_bf16(qs0[ds], bfrag, oa0[vt], 0, 0, 0);
            oa1[vt] = __builtin_amdgcn_mfma_f32_16x16x32_bf16(qs1[ds], bfrag, oa1[vt], 0, 0, 0);
        }
    // chunk-tiled layout: slab (h,c) contiguous [128 d][128 t]
    const ushort* vbase = vT + ((size_t)(h * 32 + c) * 128) * 128;
    int ns0 = (tt0 + 2) >> 1, ns1 = (tt1 + 2) >> 1;
#pragma unroll
    for (int s32 = 0; s32 < 4; ++s32) {
        if (s32 < ns1) {
            bf16x8 af = *(const bf16x8*)&PsH[(tt1 * 16 + lane15) * 136 + s32 * 32 + quad * 8];
#pragma unroll
            for (int vt = 0; vt < 8; ++vt) {
                bf16x8 bfrag = *(const bf16x8*)&vbase[(size_t)(vt * 16 + lane15) * 128 + s32 * 32 + quad * 8];
                oa1[vt] = __builtin_amdgcn_mfma_f32_16x16x32_bf16(af, bfrag, oa1[vt], 0, 0, 0);
            }
        }
    }
#pragma unroll
    for (int s32 = 0; s32 < 2; ++s32) {
        if (s32 < ns0) {
            bf16x8 af = *(const bf16x8*)&PsH[(tt0 * 16 + lane15) * 136 + s32 * 32 + quad * 8];
#pragma unroll
            for (int vt = 0; vt < 8; ++vt) {
                bf16x8 bfrag = *(const bf16x8*)&vbase[(size_t)(vt * 16 + lane15) * 128 + s32 * 32 + quad * 8];
                oa0[vt] = __builtin_amdgcn_mfma_f32_16x16x32_bf16(af, bfrag, oa0[vt], 0, 0, 0);
            }
        }
    }
    // ---- fused epilogue: group RMS-norm (group = this head-pair) * gw * gate -> gg ----
    // per-row sum of squares over this head's 128 cols (xor 1/2/4/8 stays in lane15 group = same row)
#pragma unroll
    for (int r = 0; r < 4; ++r) {
        float s20 = 0.f, s21 = 0.f;
#pragma unroll
        for (int vt = 0; vt < 8; ++vt) {
            float a = oa0[vt][r], b = oa1[vt][r];
            s20 += a * a; s21 += b * b;
        }
#pragma unroll
        for (int m = 1; m <= 8; m <<= 1) {
            s20 += __shfl_xor(s20, m);
            s21 += __shfl_xor(s21, m);
        }
        if (lane15 == 0) {
            ssb[hh * 128 + tt0 * 16 + quad * 4 + r] = s20;
            ssb[hh * 128 + tt1 * 16 + quad * 4 + r] = s21;
        }
    }
    __syncthreads();
    float gwv[8];
#pragma unroll
    for (int vt = 0; vt < 8; ++vt) gwv[vt] = gw[h * 128 + vt * 16 + lane15];
#pragma unroll
    for (int r = 0; r < 4; ++r) {
        int row0 = tt0 * 16 + quad * 4 + r;
        int row1 = tt1 * 16 + quad * 4 + r;
        float rr0 = rsqrtf((ssb[row0] + ssb[128 + row0]) * (1.0f / 256.0f) + 1e-6f);
        float rr1 = rsqrtf((ssb[row1] + ssb[128 + row1]) * (1.0f / 256.0f) + 1e-6f);
        const ushort* g0 = gate + (size_t)(t0 + row0) * HID_C + h * 128;
        const ushort* g1 = gate + (size_t)(t0 + row1) * HID_C + h * 128;
        ushort* o0 = gg + (size_t)(t0 + row0) * HID_C + h * 128;
        ushort* o1 = gg + (size_t)(t0 + row1) * HID_C + h * 128;
#pragma unroll
        for (int vt = 0; vt < 8; ++vt) {
            int col = vt * 16 + lane15;
            o0[col] = f2bfu(oa0[vt][r] * rr0 * gwv[vt] * bfu2f(g0[col]));
            o1[col] = f2bfu(oa1[vt][r] * rr1 * gwv[vt] * bfu2f(g1[col]));
        }
    }
}

extern "C" void kernel_launch(void* const* d_in, const int* in_sizes, int n_in,
                              void* d_out, int out_size, void* d_ws, size_t ws_size,
                              hipStream_t stream) {
    const int* positions   = (const int*)d_in[0];
    const float* hidden    = (const float*)d_in[1];
    const float* S0        = (const float*)d_in[2];
    const float* w_qkv     = (const float*)d_in[3];
    const float* w_g       = (const float*)d_in[4];
    const float* w_dense   = (const float*)d_in[5];
    const float* qw        = (const float*)d_in[6];
    const float* kw        = (const float*)d_in[7];
    const float* gw        = (const float*)d_in[8];

    char* ws = (char*)d_ws;
    ushort* qkv     = (ushort*)ws;                    // bf16 T x 6144            [0, 50331648)
    ushort* wqkv_t  = (ushort*)(ws + 50331648);       // bf16 6144 x 2048 (25.2M) — Bcat rows 0..6143
    ushort* wg_t    = (ushort*)(ws + 75497472);       // bf16 2048 x 2048 (8.4M)  — Bcat rows 6144..8191
    float2* ropet   = (float2*)(ws + 159383552);      // 1 MB — separate region
    ushort* PT      = (ushort*)(ws + 50331648);       // bf16 32x16x128x128 (16.8M) — aliases wqkv_t (dead)
    ushort* gg      = (ushort*)(ws + 50331648);       // bf16 T x 2048 — reuses PT region (dead after scan)
    ushort* wd_t    = (ushort*)(ws + 83886080);       // bf16 2048 x 2048 (8.4M)
    ushort* gatebuf = (ushort*)(ws + 92274688);       // bf16 T x 2048 (16.8M)
    ushort* hid_b   = (ushort*)(ws + 109051904);      // bf16 T x 2048 (16.8M)
    ushort* Spb     = (ushort*)(ws + 109051904);      // bf16 32x16x128x128 (16.8M) — aliases hid_b (dead)
    ushort* kT      = (ushort*)(ws + 125829120);      // bf16 [16][32][128][128] (16.8M) chunk-tiled
    ushort* vT      = (ushort*)(ws + 142606336);      // bf16 [16][32][128][128] (16.8M) chunk-tiled

    float* out  = (float*)d_out;
    float* Sfin = out + (size_t)T_SEQ * HID_C;

    // one launch: cvt + 3 transposes + rope table (all independent preprocessing)
    prep_all<<<9728, 256, 0, stream>>>(hidden, hid_b, w_qkv, wqkv_t, w_g, wg_t,
                                       w_dense, wd_t, positions, ropet);

    // 256x256 tiles: 512 blocks of 512 threads (waves 4Mx2N -> wave-local norm/rope epilogue)
    gemm_fused<<<dim3(512), 512, 0, stream>>>(hid_b, wqkv_t, qkv, gatebuf, kT, vT,
                                              ropet, qw, kw, HID_C);

    chunk_partial<<<dim3(32, 16), 256, 0, stream>>>(kT, vT, PT);
    scan_states<<<2048, 128, 0, stream>>>(PT, S0, Spb, Sfin);
    // 2 heads/block: fused group-norm + gate -> gg (gnorm_gate kernel eliminated)
    chunk_out<<<dim3(32, 8), 512, 0, stream>>>(qkv, vT, Spb, gatebuf, gw, gg);

    // 128x128 tiles: (4096/128)*(2048/128) = 32*16 = 512 blocks of 256 thr, 2 blocks/CU
    gemm_dense<<<dim3(512), 256, 0, stream>>>(gg, wd_t, out, HID_C, HID_C);
}